// Round 1
// baseline (5646.926 us; speedup 1.0000x reference)
//
#include <hip/hip_runtime.h>
#include <hip/hip_bf16.h>

#define EPS 1e-12f

// Problem constants
#define NIMG   200      // 150 query + 50 support
#define NQIMG  150
#define NSIMG  50
#define BDIM   2
#define NQ     75
#define WAY    5
#define SHOT   5
#define DCH    64
#define H1     84
#define H2     42
#define H3     21
#define HW3    441      // 21*21

// ---------------- conv1: 3->64, BN, ReLU, maxpool 2x2  (84 -> 42) ----------------
__global__ __launch_bounds__(256) void conv1_pool(
    const float* __restrict__ qin, const float* __restrict__ sin_,
    const float* __restrict__ w, const float* __restrict__ scale,
    const float* __restrict__ bias, float* __restrict__ out)
{
    int blk = blockIdx.x;
    int img = blk >> 6;
    int co  = blk & 63;
    const float* x = (img < NQIMG) ? (qin + (size_t)img * 3 * H1 * H1)
                                   : (sin_ + (size_t)(img - NQIMG) * 3 * H1 * H1);
    __shared__ float wsm[27];
    if (threadIdx.x < 27) wsm[threadIdx.x] = w[co * 27 + threadIdx.x];
    __syncthreads();
    float sc = scale[co], bi = bias[co];

    for (int p = threadIdx.x; p < H2 * H2; p += 256) {
        int ph = p / H2, pw = p % H2;
        int y0 = 2 * ph, x0 = 2 * pw;
        float acc[4] = {0.f, 0.f, 0.f, 0.f};
        for (int ci = 0; ci < 3; ci++) {
            const float* xp = x + (size_t)ci * H1 * H1;
            float patch[4][4];
            #pragma unroll
            for (int r = 0; r < 4; r++) {
                int iy = y0 - 1 + r;
                #pragma unroll
                for (int c = 0; c < 4; c++) {
                    int ix = x0 - 1 + c;
                    patch[r][c] = (iy >= 0 && iy < H1 && ix >= 0 && ix < H1)
                                  ? xp[iy * H1 + ix] : 0.f;
                }
            }
            const float* wp = &wsm[ci * 9];
            #pragma unroll
            for (int dy = 0; dy < 2; dy++)
                #pragma unroll
                for (int dx = 0; dx < 2; dx++) {
                    float a = 0.f;
                    #pragma unroll
                    for (int ky = 0; ky < 3; ky++)
                        #pragma unroll
                        for (int kx = 0; kx < 3; kx++)
                            a = fmaf(patch[dy + ky][dx + kx], wp[ky * 3 + kx], a);
                    acc[dy * 2 + dx] += a;
                }
        }
        float v0 = acc[0] * sc + bi, v1 = acc[1] * sc + bi;
        float v2 = acc[2] * sc + bi, v3 = acc[3] * sc + bi;
        float m = fmaxf(fmaxf(v0, v1), fmaxf(v2, v3));
        out[((size_t)img * DCH + co) * (H2 * H2) + p] = fmaxf(m, 0.f);
    }
}

// ---------------- conv2: 64->64, BN, ReLU, maxpool 2x2 (42 -> 21) ----------------
__global__ __launch_bounds__(256) void conv2_pool(
    const float* __restrict__ in, const float* __restrict__ w,
    const float* __restrict__ scale, const float* __restrict__ bias,
    float* __restrict__ out)
{
    int blk = blockIdx.x;
    int img = blk >> 6;
    int co  = blk & 63;
    const float* x = in + (size_t)img * DCH * H2 * H2;
    __shared__ float wsm[DCH * 9];
    for (int i = threadIdx.x; i < DCH * 9; i += 256) wsm[i] = w[co * DCH * 9 + i];
    __syncthreads();
    float sc = scale[co], bi = bias[co];

    for (int p = threadIdx.x; p < H3 * H3; p += 256) {
        int ph = p / H3, pw = p % H3;
        int y0 = 2 * ph, x0 = 2 * pw;
        float acc[4] = {0.f, 0.f, 0.f, 0.f};
        for (int ci = 0; ci < DCH; ci++) {
            const float* xp = x + (size_t)ci * H2 * H2;
            float patch[4][4];
            #pragma unroll
            for (int r = 0; r < 4; r++) {
                int iy = y0 - 1 + r;
                #pragma unroll
                for (int c = 0; c < 4; c++) {
                    int ix = x0 - 1 + c;
                    patch[r][c] = (iy >= 0 && iy < H2 && ix >= 0 && ix < H2)
                                  ? xp[iy * H2 + ix] : 0.f;
                }
            }
            const float* wp = &wsm[ci * 9];
            #pragma unroll
            for (int dy = 0; dy < 2; dy++)
                #pragma unroll
                for (int dx = 0; dx < 2; dx++) {
                    float a = 0.f;
                    #pragma unroll
                    for (int ky = 0; ky < 3; ky++)
                        #pragma unroll
                        for (int kx = 0; kx < 3; kx++)
                            a = fmaf(patch[dy + ky][dx + kx], wp[ky * 3 + kx], a);
                    acc[dy * 2 + dx] += a;
                }
        }
        float v0 = acc[0] * sc + bi, v1 = acc[1] * sc + bi;
        float v2 = acc[2] * sc + bi, v3 = acc[3] * sc + bi;
        float m = fmaxf(fmaxf(v0, v1), fmaxf(v2, v3));
        out[((size_t)img * DCH + co) * HW3 + p] = fmaxf(m, 0.f);
    }
}

// ---------------- conv3/conv4: 64->64, BN, ReLU, no pool (21 -> 21) ----------------
__global__ __launch_bounds__(256) void conv_np(
    const float* __restrict__ in, const float* __restrict__ w,
    const float* __restrict__ scale, const float* __restrict__ bias,
    float* __restrict__ out)
{
    int blk = blockIdx.x;
    int img = blk >> 6;
    int co  = blk & 63;
    const float* x = in + (size_t)img * DCH * HW3;
    __shared__ float wsm[DCH * 9];
    for (int i = threadIdx.x; i < DCH * 9; i += 256) wsm[i] = w[co * DCH * 9 + i];
    __syncthreads();
    float sc = scale[co], bi = bias[co];

    for (int p = threadIdx.x; p < HW3; p += 256) {
        int y = p / H3, x0 = p % H3;
        float acc = 0.f;
        for (int ci = 0; ci < DCH; ci++) {
            const float* xp = x + (size_t)ci * HW3;
            const float* wp = &wsm[ci * 9];
            #pragma unroll
            for (int ky = 0; ky < 3; ky++) {
                int iy = y + ky - 1;
                if (iy < 0 || iy >= H3) continue;
                #pragma unroll
                for (int kx = 0; kx < 3; kx++) {
                    int ix = x0 + kx - 1;
                    if (ix < 0 || ix >= H3) continue;
                    acc = fmaf(xp[iy * H3 + ix], wp[ky * 3 + kx], acc);
                }
            }
        }
        out[((size_t)img * DCH + co) * HW3 + p] = fmaxf(acc * sc + bi, 0.f);
    }
}

// ---------------- query L2-normalize: feat (img,d,hw) -> q_local ----------------
__global__ __launch_bounds__(256) void q_norm(
    const float* __restrict__ feat, float* __restrict__ q_local)
{
    int idx = blockIdx.x * 256 + threadIdx.x;
    if (idx >= NQIMG * HW3) return;
    int img = idx / HW3, hw = idx % HW3;
    const float* f = feat + (size_t)img * DCH * HW3 + hw;
    float v[DCH];
    float ss = 0.f;
    #pragma unroll
    for (int d = 0; d < DCH; d++) {
        v[d] = f[(size_t)d * HW3];
        ss = fmaf(v[d], v[d], ss);
    }
    float inv = 1.f / fmaxf(sqrtf(ss), EPS);
    float* o = q_local + (size_t)img * DCH * HW3 + hw;
    #pragma unroll
    for (int d = 0; d < DCH; d++) o[(size_t)d * HW3] = v[d] * inv;
}

// ---------------- support: mean over shots + L2-normalize ----------------
__global__ __launch_bounds__(256) void s_mean_norm(
    const float* __restrict__ feat, float* __restrict__ s_local)
{
    int idx = blockIdx.x * 256 + threadIdx.x;
    if (idx >= BDIM * WAY * HW3) return;
    int hw = idx % HW3;
    int bc = idx / HW3;          // b*WAY + c
    int b = bc / WAY, c = bc % WAY;
    int img0 = NQIMG + (b * WAY + c) * SHOT;
    float v[DCH];
    float ss = 0.f;
    #pragma unroll
    for (int d = 0; d < DCH; d++) {
        float m = 0.f;
        for (int s = 0; s < SHOT; s++)
            m += feat[((size_t)(img0 + s) * DCH + d) * HW3 + hw];
        m *= (1.f / SHOT);
        v[d] = m;
        ss = fmaf(m, m, ss);
    }
    float inv = 1.f / fmaxf(sqrtf(ss), EPS);
    float* o = s_local + (size_t)bc * DCH * HW3 + hw;
    #pragma unroll
    for (int d = 0; d < DCH; d++) o[(size_t)d * HW3] = v[d] * inv;
}

// ---------------- similarity: per (q_img, way): max_n dot, mean over m ----------------
__global__ __launch_bounds__(256) void sim_kernel(
    const float* __restrict__ q_local, const float* __restrict__ s_local,
    float* __restrict__ out)
{
    int blk = blockIdx.x;           // imgq * WAY + way
    int imgq = blk / WAY, way = blk % WAY;
    int b = imgq / NQ;
    const float* qp = q_local + (size_t)imgq * DCH * HW3;           // [d][m]
    const float* sp = s_local + (size_t)(b * WAY + way) * DCH * HW3; // [d][n]

    __shared__ float slds[DCH][64];
    int tid = threadIdx.x;
    int m1 = tid + 256;
    bool has1 = (m1 < HW3);

    float q0[DCH], q1[DCH];
    #pragma unroll
    for (int d = 0; d < DCH; d++) {
        q0[d] = qp[(size_t)d * HW3 + tid];
        q1[d] = has1 ? qp[(size_t)d * HW3 + m1] : 0.f;
    }

    float best0 = -1e30f, best1 = -1e30f;
    for (int n0 = 0; n0 < HW3; n0 += 64) {
        int nn = (HW3 - n0 < 64) ? (HW3 - n0) : 64;
        __syncthreads();
        for (int i = tid; i < DCH * 64; i += 256) {
            int d = i >> 6, j = i & 63;
            slds[d][j] = (j < nn) ? sp[(size_t)d * HW3 + n0 + j] : 0.f;
        }
        __syncthreads();
        int full = nn & ~3;
        int n = 0;
        for (; n < full; n += 4) {
            float d00 = 0.f, d01 = 0.f, d02 = 0.f, d03 = 0.f;
            float d10 = 0.f, d11 = 0.f, d12 = 0.f, d13 = 0.f;
            #pragma unroll
            for (int d = 0; d < DCH; d++) {
                float4 sv = *reinterpret_cast<const float4*>(&slds[d][n]);
                d00 = fmaf(q0[d], sv.x, d00);
                d01 = fmaf(q0[d], sv.y, d01);
                d02 = fmaf(q0[d], sv.z, d02);
                d03 = fmaf(q0[d], sv.w, d03);
                d10 = fmaf(q1[d], sv.x, d10);
                d11 = fmaf(q1[d], sv.y, d11);
                d12 = fmaf(q1[d], sv.z, d12);
                d13 = fmaf(q1[d], sv.w, d13);
            }
            best0 = fmaxf(best0, fmaxf(fmaxf(d00, d01), fmaxf(d02, d03)));
            best1 = fmaxf(best1, fmaxf(fmaxf(d10, d11), fmaxf(d12, d13)));
        }
        for (; n < nn; n++) {
            float dd0 = 0.f, dd1 = 0.f;
            #pragma unroll
            for (int d = 0; d < DCH; d++) {
                float sv = slds[d][n];
                dd0 = fmaf(q0[d], sv, dd0);
                dd1 = fmaf(q1[d], sv, dd1);
            }
            best0 = fmaxf(best0, dd0);
            best1 = fmaxf(best1, dd1);
        }
    }

    float sum = best0 + (has1 ? best1 : 0.f);
    #pragma unroll
    for (int off = 32; off > 0; off >>= 1)
        sum += __shfl_xor(sum, off, 64);
    __shared__ float red[4];
    int wid = tid >> 6;
    if ((tid & 63) == 0) red[wid] = sum;
    __syncthreads();
    if (tid == 0) {
        float tot = red[0] + red[1] + red[2] + red[3];
        out[(size_t)imgq * WAY + way] = tot / (float)HW3;
    }
}

extern "C" void kernel_launch(void* const* d_in, const int* in_sizes, int n_in,
                              void* d_out, int out_size, void* d_ws, size_t ws_size,
                              hipStream_t stream) {
    const float* query   = (const float*)d_in[0];
    const float* support = (const float*)d_in[1];
    const float* w1 = (const float*)d_in[2];
    const float* w2 = (const float*)d_in[3];
    const float* w3 = (const float*)d_in[4];
    const float* w4 = (const float*)d_in[5];
    const float* s1 = (const float*)d_in[6];
    const float* b1 = (const float*)d_in[7];
    const float* s2 = (const float*)d_in[8];
    const float* b2 = (const float*)d_in[9];
    const float* s3 = (const float*)d_in[10];
    const float* b3 = (const float*)d_in[11];
    const float* s4 = (const float*)d_in[12];
    const float* b4 = (const float*)d_in[13];
    float* out = (float*)d_out;

    char* ws = (char*)d_ws;
    // A: conv1 out (200,64,42,42) f32 = 90,316,800 B
    // B: conv2 out / q_local (200,64,441) f32 = 22,579,200 B
    // C: conv3 out / s_local f32 = 22,579,200 B
    float* A = (float*)ws;
    float* Bb = (float*)(ws + 90316800);
    float* Cb = (float*)(ws + 90316800 + 22579200);

    // encoder
    conv1_pool<<<NIMG * DCH, 256, 0, stream>>>(query, support, w1, s1, b1, A);
    conv2_pool<<<NIMG * DCH, 256, 0, stream>>>(A, w2, s2, b2, Bb);
    conv_np<<<NIMG * DCH, 256, 0, stream>>>(Bb, w3, s3, b3, Cb);
    conv_np<<<NIMG * DCH, 256, 0, stream>>>(Cb, w4, s4, b4, A);   // final feat in A

    // descriptors
    q_norm<<<(NQIMG * HW3 + 255) / 256, 256, 0, stream>>>(A, Bb);        // q_local in B
    s_mean_norm<<<(BDIM * WAY * HW3 + 255) / 256, 256, 0, stream>>>(A, Cb); // s_local in C

    // similarity
    sim_kernel<<<NQIMG * WAY, 256, 0, stream>>>(Bb, Cb, out);
}

// Round 2
// 1813.860 us; speedup vs baseline: 3.1132x; 3.1132x over previous
//
#include <hip/hip_runtime.h>
#include <hip/hip_bf16.h>

#define EPS 1e-12f

// Problem constants
#define NIMG   200      // 150 query + 50 support
#define NQIMG  150
#define NSIMG  50
#define BDIM   2
#define NQ     75
#define WAY    5
#define SHOT   5
#define DCH    64
#define H1     84
#define H2     42
#define H3     21
#define HW2    1764     // 42*42
#define HW3    441      // 21*21

// ---------------- conv1: 3->64, BN, ReLU, maxpool 2x2 (84 -> 42) ----------------
// grid: NIMG * 8 (co-groups of 8), block: 512
__global__ __launch_bounds__(512) void conv1_pool(
    const float* __restrict__ qin, const float* __restrict__ sin_,
    const float* __restrict__ w, const float* __restrict__ scale,
    const float* __restrict__ bias, float* __restrict__ out)
{
    int img = blockIdx.x >> 3;
    int g   = blockIdx.x & 7;         // co group: channels g*8 .. g*8+7
    const float* x = (img < NQIMG) ? (qin + (size_t)img * 3 * H1 * H1)
                                   : (sin_ + (size_t)(img - NQIMG) * 3 * H1 * H1);
    __shared__ __attribute__((aligned(16))) float wsm[8 * 3 * 12];
    int tid = threadIdx.x;
    for (int i = tid; i < 8 * 3 * 9; i += 512) {
        int coci = i / 9, k = i % 9;
        wsm[coci * 12 + k] = w[(size_t)g * 8 * 27 + i];
    }
    __syncthreads();

    for (int p = tid; p < HW2; p += 512) {
        int ph = p / H2, pw = p % H2;
        int y0 = 2 * ph, x0 = 2 * pw;
        float acc[8][4] = {};
        for (int ci = 0; ci < 3; ci++) {
            const float* xp = x + (size_t)ci * H1 * H1;
            float patch[4][4];
            #pragma unroll
            for (int r = 0; r < 4; r++) {
                int iy = y0 - 1 + r;
                bool okr = (iy >= 0 && iy < H1);
                #pragma unroll
                for (int c = 0; c < 4; c++) {
                    int ix = x0 - 1 + c;
                    patch[r][c] = (okr && ix >= 0 && ix < H1) ? xp[iy * H1 + ix] : 0.f;
                }
            }
            #pragma unroll
            for (int co = 0; co < 8; co++) {
                const float* wp = &wsm[(co * 3 + ci) * 12];
                float4 wa = *reinterpret_cast<const float4*>(wp);
                float4 wb = *reinterpret_cast<const float4*>(wp + 4);
                float w8 = wp[8];
                #pragma unroll
                for (int dy = 0; dy < 2; dy++)
                    #pragma unroll
                    for (int dx = 0; dx < 2; dx++) {
                        float a = 0.f;
                        a = fmaf(patch[dy+0][dx+0], wa.x, a);
                        a = fmaf(patch[dy+0][dx+1], wa.y, a);
                        a = fmaf(patch[dy+0][dx+2], wa.z, a);
                        a = fmaf(patch[dy+1][dx+0], wa.w, a);
                        a = fmaf(patch[dy+1][dx+1], wb.x, a);
                        a = fmaf(patch[dy+1][dx+2], wb.y, a);
                        a = fmaf(patch[dy+2][dx+0], wb.z, a);
                        a = fmaf(patch[dy+2][dx+1], wb.w, a);
                        a = fmaf(patch[dy+2][dx+2], w8, a);
                        acc[co][dy*2+dx] += a;
                    }
            }
        }
        #pragma unroll
        for (int co = 0; co < 8; co++) {
            int cog = g * 8 + co;
            float sc = scale[cog], bi = bias[cog];
            float v0 = acc[co][0]*sc+bi, v1 = acc[co][1]*sc+bi;
            float v2 = acc[co][2]*sc+bi, v3 = acc[co][3]*sc+bi;
            float m = fmaxf(fmaxf(v0, v1), fmaxf(v2, v3));
            out[((size_t)img * DCH + cog) * HW2 + p] = fmaxf(m, 0.f);
        }
    }
}

// ---------------- conv2: 64->64, BN, ReLU, maxpool 2x2 (42 -> 21) ----------------
// grid: NIMG * 8, block: 512 (441 active)
__global__ __launch_bounds__(512) void conv2_pool(
    const float* __restrict__ in, const float* __restrict__ w,
    const float* __restrict__ scale, const float* __restrict__ bias,
    float* __restrict__ out)
{
    int img = blockIdx.x >> 3;
    int g   = blockIdx.x & 7;
    const float* x = in + (size_t)img * DCH * HW2;
    __shared__ __attribute__((aligned(16))) float wsm[8 * DCH * 12];
    int tid = threadIdx.x;
    for (int i = tid; i < 8 * DCH * 9; i += 512) {
        int coci = i / 9, k = i % 9;
        wsm[coci * 12 + k] = w[(size_t)g * 8 * DCH * 9 + i];
    }
    __syncthreads();
    if (tid >= HW3) return;

    int ph = tid / H3, pw = tid % H3;
    int y0 = 2 * ph, x0 = 2 * pw;
    float acc[8][4] = {};
    for (int ci = 0; ci < DCH; ci++) {
        const float* xp = x + (size_t)ci * HW2;
        float patch[4][4];
        #pragma unroll
        for (int r = 0; r < 4; r++) {
            int iy = y0 - 1 + r;
            bool okr = (iy >= 0 && iy < H2);
            #pragma unroll
            for (int c = 0; c < 4; c++) {
                int ix = x0 - 1 + c;
                patch[r][c] = (okr && ix >= 0 && ix < H2) ? xp[iy * H2 + ix] : 0.f;
            }
        }
        #pragma unroll
        for (int co = 0; co < 8; co++) {
            const float* wp = &wsm[(co * DCH + ci) * 12];
            float4 wa = *reinterpret_cast<const float4*>(wp);
            float4 wb = *reinterpret_cast<const float4*>(wp + 4);
            float w8 = wp[8];
            #pragma unroll
            for (int dy = 0; dy < 2; dy++)
                #pragma unroll
                for (int dx = 0; dx < 2; dx++) {
                    float a = 0.f;
                    a = fmaf(patch[dy+0][dx+0], wa.x, a);
                    a = fmaf(patch[dy+0][dx+1], wa.y, a);
                    a = fmaf(patch[dy+0][dx+2], wa.z, a);
                    a = fmaf(patch[dy+1][dx+0], wa.w, a);
                    a = fmaf(patch[dy+1][dx+1], wb.x, a);
                    a = fmaf(patch[dy+1][dx+2], wb.y, a);
                    a = fmaf(patch[dy+2][dx+0], wb.z, a);
                    a = fmaf(patch[dy+2][dx+1], wb.w, a);
                    a = fmaf(patch[dy+2][dx+2], w8, a);
                    acc[co][dy*2+dx] += a;
                }
        }
    }
    #pragma unroll
    for (int co = 0; co < 8; co++) {
        int cog = g * 8 + co;
        float sc = scale[cog], bi = bias[cog];
        float v0 = acc[co][0]*sc+bi, v1 = acc[co][1]*sc+bi;
        float v2 = acc[co][2]*sc+bi, v3 = acc[co][3]*sc+bi;
        float m = fmaxf(fmaxf(v0, v1), fmaxf(v2, v3));
        out[((size_t)img * DCH + cog) * HW3 + tid] = fmaxf(m, 0.f);
    }
}

// ---------------- conv3/conv4: 64->64, BN, ReLU, no pool (21x21) ----------------
// grid: NIMG * 8, block: 128 (121 active, 2x2 output tile per thread)
__global__ __launch_bounds__(128) void conv_np(
    const float* __restrict__ in, const float* __restrict__ w,
    const float* __restrict__ scale, const float* __restrict__ bias,
    float* __restrict__ out)
{
    int img = blockIdx.x >> 3;
    int g   = blockIdx.x & 7;
    const float* x = in + (size_t)img * DCH * HW3;
    __shared__ __attribute__((aligned(16))) float wsm[8 * DCH * 12];
    int tid = threadIdx.x;
    for (int i = tid; i < 8 * DCH * 9; i += 128) {
        int coci = i / 9, k = i % 9;
        wsm[coci * 12 + k] = w[(size_t)g * 8 * DCH * 9 + i];
    }
    __syncthreads();
    if (tid >= 121) return;

    int ty = tid / 11, tx = tid % 11;     // 2x2 output tile at (2ty, 2tx)
    int y0 = 2 * ty, x0 = 2 * tx;
    float acc[8][4] = {};
    for (int ci = 0; ci < DCH; ci++) {
        const float* xp = x + (size_t)ci * HW3;
        float patch[4][4];
        #pragma unroll
        for (int r = 0; r < 4; r++) {
            int iy = y0 - 1 + r;
            bool okr = (iy >= 0 && iy < H3);
            #pragma unroll
            for (int c = 0; c < 4; c++) {
                int ix = x0 - 1 + c;
                patch[r][c] = (okr && ix >= 0 && ix < H3) ? xp[iy * H3 + ix] : 0.f;
            }
        }
        #pragma unroll
        for (int co = 0; co < 8; co++) {
            const float* wp = &wsm[(co * DCH + ci) * 12];
            float4 wa = *reinterpret_cast<const float4*>(wp);
            float4 wb = *reinterpret_cast<const float4*>(wp + 4);
            float w8 = wp[8];
            #pragma unroll
            for (int dy = 0; dy < 2; dy++)
                #pragma unroll
                for (int dx = 0; dx < 2; dx++) {
                    float a = 0.f;
                    a = fmaf(patch[dy+0][dx+0], wa.x, a);
                    a = fmaf(patch[dy+0][dx+1], wa.y, a);
                    a = fmaf(patch[dy+0][dx+2], wa.z, a);
                    a = fmaf(patch[dy+1][dx+0], wa.w, a);
                    a = fmaf(patch[dy+1][dx+1], wb.x, a);
                    a = fmaf(patch[dy+1][dx+2], wb.y, a);
                    a = fmaf(patch[dy+2][dx+0], wb.z, a);
                    a = fmaf(patch[dy+2][dx+1], wb.w, a);
                    a = fmaf(patch[dy+2][dx+2], w8, a);
                    acc[co][dy*2+dx] += a;
                }
        }
    }
    #pragma unroll
    for (int co = 0; co < 8; co++) {
        int cog = g * 8 + co;
        float sc = scale[cog], bi = bias[cog];
        #pragma unroll
        for (int dy = 0; dy < 2; dy++)
            #pragma unroll
            for (int dx = 0; dx < 2; dx++) {
                int oy = y0 + dy, ox = x0 + dx;
                if (oy < H3 && ox < H3)
                    out[((size_t)img * DCH + cog) * HW3 + oy * H3 + ox] =
                        fmaxf(acc[co][dy*2+dx] * sc + bi, 0.f);
            }
    }
}

// ---------------- query L2-normalize ----------------
__global__ __launch_bounds__(256) void q_norm(
    const float* __restrict__ feat, float* __restrict__ q_local)
{
    int idx = blockIdx.x * 256 + threadIdx.x;
    if (idx >= NQIMG * HW3) return;
    int img = idx / HW3, hw = idx % HW3;
    const float* f = feat + (size_t)img * DCH * HW3 + hw;
    float v[DCH];
    float ss = 0.f;
    #pragma unroll
    for (int d = 0; d < DCH; d++) {
        v[d] = f[(size_t)d * HW3];
        ss = fmaf(v[d], v[d], ss);
    }
    float inv = 1.f / fmaxf(sqrtf(ss), EPS);
    float* o = q_local + (size_t)img * DCH * HW3 + hw;
    #pragma unroll
    for (int d = 0; d < DCH; d++) o[(size_t)d * HW3] = v[d] * inv;
}

// ---------------- support: mean over shots + L2-normalize ----------------
__global__ __launch_bounds__(256) void s_mean_norm(
    const float* __restrict__ feat, float* __restrict__ s_local)
{
    int idx = blockIdx.x * 256 + threadIdx.x;
    if (idx >= BDIM * WAY * HW3) return;
    int hw = idx % HW3;
    int bc = idx / HW3;
    int img0 = NQIMG + bc * SHOT;
    float v[DCH];
    float ss = 0.f;
    #pragma unroll
    for (int d = 0; d < DCH; d++) {
        float m = 0.f;
        for (int s = 0; s < SHOT; s++)
            m += feat[((size_t)(img0 + s) * DCH + d) * HW3 + hw];
        m *= (1.f / SHOT);
        v[d] = m;
        ss = fmaf(m, m, ss);
    }
    float inv = 1.f / fmaxf(sqrtf(ss), EPS);
    float* o = s_local + (size_t)bc * DCH * HW3 + hw;
    #pragma unroll
    for (int d = 0; d < DCH; d++) o[(size_t)d * HW3] = v[d] * inv;
}

// ---------------- similarity ----------------
__global__ __launch_bounds__(256) void sim_kernel(
    const float* __restrict__ q_local, const float* __restrict__ s_local,
    float* __restrict__ out)
{
    int blk = blockIdx.x;
    int imgq = blk / WAY, way = blk % WAY;
    int b = imgq / NQ;
    const float* qp = q_local + (size_t)imgq * DCH * HW3;
    const float* sp = s_local + (size_t)(b * WAY + way) * DCH * HW3;

    __shared__ float slds[DCH][64];
    int tid = threadIdx.x;
    int m1 = tid + 256;
    bool has1 = (m1 < HW3);

    float q0[DCH], q1[DCH];
    #pragma unroll
    for (int d = 0; d < DCH; d++) {
        q0[d] = qp[(size_t)d * HW3 + tid];
        q1[d] = has1 ? qp[(size_t)d * HW3 + m1] : 0.f;
    }

    float best0 = -1e30f, best1 = -1e30f;
    for (int n0 = 0; n0 < HW3; n0 += 64) {
        int nn = (HW3 - n0 < 64) ? (HW3 - n0) : 64;
        __syncthreads();
        for (int i = tid; i < DCH * 64; i += 256) {
            int d = i >> 6, j = i & 63;
            slds[d][j] = (j < nn) ? sp[(size_t)d * HW3 + n0 + j] : 0.f;
        }
        __syncthreads();
        int full = nn & ~3;
        int n = 0;
        for (; n < full; n += 4) {
            float d00 = 0.f, d01 = 0.f, d02 = 0.f, d03 = 0.f;
            float d10 = 0.f, d11 = 0.f, d12 = 0.f, d13 = 0.f;
            #pragma unroll
            for (int d = 0; d < DCH; d++) {
                float4 sv = *reinterpret_cast<const float4*>(&slds[d][n]);
                d00 = fmaf(q0[d], sv.x, d00);
                d01 = fmaf(q0[d], sv.y, d01);
                d02 = fmaf(q0[d], sv.z, d02);
                d03 = fmaf(q0[d], sv.w, d03);
                d10 = fmaf(q1[d], sv.x, d10);
                d11 = fmaf(q1[d], sv.y, d11);
                d12 = fmaf(q1[d], sv.z, d12);
                d13 = fmaf(q1[d], sv.w, d13);
            }
            best0 = fmaxf(best0, fmaxf(fmaxf(d00, d01), fmaxf(d02, d03)));
            best1 = fmaxf(best1, fmaxf(fmaxf(d10, d11), fmaxf(d12, d13)));
        }
        for (; n < nn; n++) {
            float dd0 = 0.f, dd1 = 0.f;
            #pragma unroll
            for (int d = 0; d < DCH; d++) {
                float sv = slds[d][n];
                dd0 = fmaf(q0[d], sv, dd0);
                dd1 = fmaf(q1[d], sv, dd1);
            }
            best0 = fmaxf(best0, dd0);
            best1 = fmaxf(best1, dd1);
        }
    }

    float sum = best0 + (has1 ? best1 : 0.f);
    #pragma unroll
    for (int off = 32; off > 0; off >>= 1)
        sum += __shfl_xor(sum, off, 64);
    __shared__ float red[4];
    int wid = tid >> 6;
    if ((tid & 63) == 0) red[wid] = sum;
    __syncthreads();
    if (tid == 0) {
        float tot = red[0] + red[1] + red[2] + red[3];
        out[(size_t)imgq * WAY + way] = tot / (float)HW3;
    }
}

extern "C" void kernel_launch(void* const* d_in, const int* in_sizes, int n_in,
                              void* d_out, int out_size, void* d_ws, size_t ws_size,
                              hipStream_t stream) {
    const float* query   = (const float*)d_in[0];
    const float* support = (const float*)d_in[1];
    const float* w1 = (const float*)d_in[2];
    const float* w2 = (const float*)d_in[3];
    const float* w3 = (const float*)d_in[4];
    const float* w4 = (const float*)d_in[5];
    const float* s1 = (const float*)d_in[6];
    const float* b1 = (const float*)d_in[7];
    const float* s2 = (const float*)d_in[8];
    const float* b2 = (const float*)d_in[9];
    const float* s3 = (const float*)d_in[10];
    const float* b3 = (const float*)d_in[11];
    const float* s4 = (const float*)d_in[12];
    const float* b4 = (const float*)d_in[13];
    float* out = (float*)d_out;

    char* ws = (char*)d_ws;
    float* A  = (float*)ws;                                   // conv1 out (200,64,1764)
    float* Bb = (float*)(ws + 90316800);                      // conv2 out / q_local
    float* Cb = (float*)(ws + 90316800 + 22579200);           // conv3 out / s_local

    conv1_pool<<<NIMG * 8, 512, 0, stream>>>(query, support, w1, s1, b1, A);
    conv2_pool<<<NIMG * 8, 512, 0, stream>>>(A, w2, s2, b2, Bb);
    conv_np<<<NIMG * 8, 128, 0, stream>>>(Bb, w3, s3, b3, Cb);
    conv_np<<<NIMG * 8, 128, 0, stream>>>(Cb, w4, s4, b4, A);    // final feat in A

    q_norm<<<(NQIMG * HW3 + 255) / 256, 256, 0, stream>>>(A, Bb);
    s_mean_norm<<<(BDIM * WAY * HW3 + 255) / 256, 256, 0, stream>>>(A, Cb);

    sim_kernel<<<NQIMG * WAY, 256, 0, stream>>>(Bb, Cb, out);
}

// Round 3
// 1317.215 us; speedup vs baseline: 4.2870x; 1.3770x over previous
//
#include <hip/hip_runtime.h>
#include <hip/hip_bf16.h>

#define EPS 1e-12f

// Problem constants
#define NIMG   200      // 150 query + 50 support
#define NQIMG  150
#define NSIMG  50
#define BDIM   2
#define NQ     75
#define WAY    5
#define SHOT   5
#define DCH    64
#define H1     84
#define H2     42
#define H3     21
#define HW2    1764     // 42*42
#define HW3    441      // 21*21

// ---------------- conv1: 3->64, BN, ReLU, maxpool 2x2 (84 -> 42) ----------------
// grid: NIMG * 16 (co-groups of 4), block: 256, VGPR-capped at 256 (no spill)
__global__ __launch_bounds__(256, 2) void conv1_pool(
    const float* __restrict__ qin, const float* __restrict__ sin_,
    const float* __restrict__ w, const float* __restrict__ scale,
    const float* __restrict__ bias, float* __restrict__ out)
{
    int img = blockIdx.x >> 4;
    int g   = blockIdx.x & 15;        // co group: channels g*4 .. g*4+3
    const float* x = (img < NQIMG) ? (qin + (size_t)img * 3 * H1 * H1)
                                   : (sin_ + (size_t)(img - NQIMG) * 3 * H1 * H1);
    __shared__ __attribute__((aligned(16))) float wsm[4 * 3 * 12];
    int tid = threadIdx.x;
    for (int i = tid; i < 4 * 3 * 9; i += 256) {
        int coci = i / 9, k = i % 9;
        wsm[coci * 12 + k] = w[(size_t)g * 4 * 27 + i];
    }
    __syncthreads();

    for (int p = tid; p < HW2; p += 256) {
        int ph = p / H2, pw = p % H2;
        int y0 = 2 * ph, x0 = 2 * pw;
        float acc[4][4] = {};
        #pragma unroll
        for (int ci = 0; ci < 3; ci++) {
            const float* xp = x + (size_t)ci * H1 * H1;
            float patch[4][4];
            #pragma unroll
            for (int r = 0; r < 4; r++) {
                int iy = y0 - 1 + r;
                bool okr = (iy >= 0 && iy < H1);
                #pragma unroll
                for (int c = 0; c < 4; c++) {
                    int ix = x0 - 1 + c;
                    patch[r][c] = (okr && ix >= 0 && ix < H1) ? xp[iy * H1 + ix] : 0.f;
                }
            }
            #pragma unroll
            for (int co = 0; co < 4; co++) {
                const float* wp = &wsm[(co * 3 + ci) * 12];
                float4 wa = *reinterpret_cast<const float4*>(wp);
                float4 wb = *reinterpret_cast<const float4*>(wp + 4);
                float w8 = wp[8];
                #pragma unroll
                for (int dy = 0; dy < 2; dy++)
                    #pragma unroll
                    for (int dx = 0; dx < 2; dx++) {
                        float a = 0.f;
                        a = fmaf(patch[dy+0][dx+0], wa.x, a);
                        a = fmaf(patch[dy+0][dx+1], wa.y, a);
                        a = fmaf(patch[dy+0][dx+2], wa.z, a);
                        a = fmaf(patch[dy+1][dx+0], wa.w, a);
                        a = fmaf(patch[dy+1][dx+1], wb.x, a);
                        a = fmaf(patch[dy+1][dx+2], wb.y, a);
                        a = fmaf(patch[dy+2][dx+0], wb.z, a);
                        a = fmaf(patch[dy+2][dx+1], wb.w, a);
                        a = fmaf(patch[dy+2][dx+2], w8, a);
                        acc[co][dy*2+dx] += a;
                    }
            }
        }
        #pragma unroll
        for (int co = 0; co < 4; co++) {
            int cog = g * 4 + co;
            float sc = scale[cog], bi = bias[cog];
            float v0 = acc[co][0]*sc+bi, v1 = acc[co][1]*sc+bi;
            float v2 = acc[co][2]*sc+bi, v3 = acc[co][3]*sc+bi;
            float m = fmaxf(fmaxf(v0, v1), fmaxf(v2, v3));
            out[((size_t)img * DCH + cog) * HW2 + p] = fmaxf(m, 0.f);
        }
    }
}

// ---------------- conv2: 64->64, BN, ReLU, maxpool 2x2 (42 -> 21) ----------------
// grid: NIMG * 8, block: 512 (441 active)
__global__ __launch_bounds__(512) void conv2_pool(
    const float* __restrict__ in, const float* __restrict__ w,
    const float* __restrict__ scale, const float* __restrict__ bias,
    float* __restrict__ out)
{
    int img = blockIdx.x >> 3;
    int g   = blockIdx.x & 7;
    const float* x = in + (size_t)img * DCH * HW2;
    __shared__ __attribute__((aligned(16))) float wsm[8 * DCH * 12];
    int tid = threadIdx.x;
    for (int i = tid; i < 8 * DCH * 9; i += 512) {
        int coci = i / 9, k = i % 9;
        wsm[coci * 12 + k] = w[(size_t)g * 8 * DCH * 9 + i];
    }
    __syncthreads();
    if (tid >= HW3) return;

    int ph = tid / H3, pw = tid % H3;
    int y0 = 2 * ph, x0 = 2 * pw;
    float acc[8][4] = {};
    for (int ci = 0; ci < DCH; ci++) {
        const float* xp = x + (size_t)ci * HW2;
        float patch[4][4];
        #pragma unroll
        for (int r = 0; r < 4; r++) {
            int iy = y0 - 1 + r;
            bool okr = (iy >= 0 && iy < H2);
            #pragma unroll
            for (int c = 0; c < 4; c++) {
                int ix = x0 - 1 + c;
                patch[r][c] = (okr && ix >= 0 && ix < H2) ? xp[iy * H2 + ix] : 0.f;
            }
        }
        #pragma unroll
        for (int co = 0; co < 8; co++) {
            const float* wp = &wsm[(co * DCH + ci) * 12];
            float4 wa = *reinterpret_cast<const float4*>(wp);
            float4 wb = *reinterpret_cast<const float4*>(wp + 4);
            float w8 = wp[8];
            #pragma unroll
            for (int dy = 0; dy < 2; dy++)
                #pragma unroll
                for (int dx = 0; dx < 2; dx++) {
                    float a = 0.f;
                    a = fmaf(patch[dy+0][dx+0], wa.x, a);
                    a = fmaf(patch[dy+0][dx+1], wa.y, a);
                    a = fmaf(patch[dy+0][dx+2], wa.z, a);
                    a = fmaf(patch[dy+1][dx+0], wa.w, a);
                    a = fmaf(patch[dy+1][dx+1], wb.x, a);
                    a = fmaf(patch[dy+1][dx+2], wb.y, a);
                    a = fmaf(patch[dy+2][dx+0], wb.z, a);
                    a = fmaf(patch[dy+2][dx+1], wb.w, a);
                    a = fmaf(patch[dy+2][dx+2], w8, a);
                    acc[co][dy*2+dx] += a;
                }
        }
    }
    #pragma unroll
    for (int co = 0; co < 8; co++) {
        int cog = g * 8 + co;
        float sc = scale[cog], bi = bias[cog];
        float v0 = acc[co][0]*sc+bi, v1 = acc[co][1]*sc+bi;
        float v2 = acc[co][2]*sc+bi, v3 = acc[co][3]*sc+bi;
        float m = fmaxf(fmaxf(v0, v1), fmaxf(v2, v3));
        out[((size_t)img * DCH + cog) * HW3 + tid] = fmaxf(m, 0.f);
    }
}

// ---------------- conv3/conv4: 64->64, BN, ReLU, no pool (21x21) ----------------
// grid: NIMG * 8, block: 128 (121 active, 2x2 output tile per thread)
__global__ __launch_bounds__(128) void conv_np(
    const float* __restrict__ in, const float* __restrict__ w,
    const float* __restrict__ scale, const float* __restrict__ bias,
    float* __restrict__ out)
{
    int img = blockIdx.x >> 3;
    int g   = blockIdx.x & 7;
    const float* x = in + (size_t)img * DCH * HW3;
    __shared__ __attribute__((aligned(16))) float wsm[8 * DCH * 12];
    int tid = threadIdx.x;
    for (int i = tid; i < 8 * DCH * 9; i += 128) {
        int coci = i / 9, k = i % 9;
        wsm[coci * 12 + k] = w[(size_t)g * 8 * DCH * 9 + i];
    }
    __syncthreads();
    if (tid >= 121) return;

    int ty = tid / 11, tx = tid % 11;     // 2x2 output tile at (2ty, 2tx)
    int y0 = 2 * ty, x0 = 2 * tx;
    float acc[8][4] = {};
    for (int ci = 0; ci < DCH; ci++) {
        const float* xp = x + (size_t)ci * HW3;
        float patch[4][4];
        #pragma unroll
        for (int r = 0; r < 4; r++) {
            int iy = y0 - 1 + r;
            bool okr = (iy >= 0 && iy < H3);
            #pragma unroll
            for (int c = 0; c < 4; c++) {
                int ix = x0 - 1 + c;
                patch[r][c] = (okr && ix >= 0 && ix < H3) ? xp[iy * H3 + ix] : 0.f;
            }
        }
        #pragma unroll
        for (int co = 0; co < 8; co++) {
            const float* wp = &wsm[(co * DCH + ci) * 12];
            float4 wa = *reinterpret_cast<const float4*>(wp);
            float4 wb = *reinterpret_cast<const float4*>(wp + 4);
            float w8 = wp[8];
            #pragma unroll
            for (int dy = 0; dy < 2; dy++)
                #pragma unroll
                for (int dx = 0; dx < 2; dx++) {
                    float a = 0.f;
                    a = fmaf(patch[dy+0][dx+0], wa.x, a);
                    a = fmaf(patch[dy+0][dx+1], wa.y, a);
                    a = fmaf(patch[dy+0][dx+2], wa.z, a);
                    a = fmaf(patch[dy+1][dx+0], wa.w, a);
                    a = fmaf(patch[dy+1][dx+1], wb.x, a);
                    a = fmaf(patch[dy+1][dx+2], wb.y, a);
                    a = fmaf(patch[dy+2][dx+0], wb.z, a);
                    a = fmaf(patch[dy+2][dx+1], wb.w, a);
                    a = fmaf(patch[dy+2][dx+2], w8, a);
                    acc[co][dy*2+dx] += a;
                }
        }
    }
    #pragma unroll
    for (int co = 0; co < 8; co++) {
        int cog = g * 8 + co;
        float sc = scale[cog], bi = bias[cog];
        #pragma unroll
        for (int dy = 0; dy < 2; dy++)
            #pragma unroll
            for (int dx = 0; dx < 2; dx++) {
                int oy = y0 + dy, ox = x0 + dx;
                if (oy < H3 && ox < H3)
                    out[((size_t)img * DCH + cog) * HW3 + oy * H3 + ox] =
                        fmaxf(acc[co][dy*2+dx] * sc + bi, 0.f);
            }
    }
}

// ---------------- query L2-normalize ----------------
__global__ __launch_bounds__(256) void q_norm(
    const float* __restrict__ feat, float* __restrict__ q_local)
{
    int idx = blockIdx.x * 256 + threadIdx.x;
    if (idx >= NQIMG * HW3) return;
    int img = idx / HW3, hw = idx % HW3;
    const float* f = feat + (size_t)img * DCH * HW3 + hw;
    float v[DCH];
    float ss = 0.f;
    #pragma unroll
    for (int d = 0; d < DCH; d++) {
        v[d] = f[(size_t)d * HW3];
        ss = fmaf(v[d], v[d], ss);
    }
    float inv = 1.f / fmaxf(sqrtf(ss), EPS);
    float* o = q_local + (size_t)img * DCH * HW3 + hw;
    #pragma unroll
    for (int d = 0; d < DCH; d++) o[(size_t)d * HW3] = v[d] * inv;
}

// ---------------- support: mean over shots + L2-normalize ----------------
__global__ __launch_bounds__(256) void s_mean_norm(
    const float* __restrict__ feat, float* __restrict__ s_local)
{
    int idx = blockIdx.x * 256 + threadIdx.x;
    if (idx >= BDIM * WAY * HW3) return;
    int hw = idx % HW3;
    int bc = idx / HW3;
    int img0 = NQIMG + bc * SHOT;
    float v[DCH];
    float ss = 0.f;
    #pragma unroll
    for (int d = 0; d < DCH; d++) {
        float m = 0.f;
        for (int s = 0; s < SHOT; s++)
            m += feat[((size_t)(img0 + s) * DCH + d) * HW3 + hw];
        m *= (1.f / SHOT);
        v[d] = m;
        ss = fmaf(m, m, ss);
    }
    float inv = 1.f / fmaxf(sqrtf(ss), EPS);
    float* o = s_local + (size_t)bc * DCH * HW3 + hw;
    #pragma unroll
    for (int d = 0; d < DCH; d++) o[(size_t)d * HW3] = v[d] * inv;
}

// ---------------- similarity ----------------
__global__ __launch_bounds__(256) void sim_kernel(
    const float* __restrict__ q_local, const float* __restrict__ s_local,
    float* __restrict__ out)
{
    int blk = blockIdx.x;
    int imgq = blk / WAY, way = blk % WAY;
    int b = imgq / NQ;
    const float* qp = q_local + (size_t)imgq * DCH * HW3;
    const float* sp = s_local + (size_t)(b * WAY + way) * DCH * HW3;

    __shared__ float slds[DCH][64];
    int tid = threadIdx.x;
    int m1 = tid + 256;
    bool has1 = (m1 < HW3);

    float q0[DCH], q1[DCH];
    #pragma unroll
    for (int d = 0; d < DCH; d++) {
        q0[d] = qp[(size_t)d * HW3 + tid];
        q1[d] = has1 ? qp[(size_t)d * HW3 + m1] : 0.f;
    }

    float best0 = -1e30f, best1 = -1e30f;
    for (int n0 = 0; n0 < HW3; n0 += 64) {
        int nn = (HW3 - n0 < 64) ? (HW3 - n0) : 64;
        __syncthreads();
        for (int i = tid; i < DCH * 64; i += 256) {
            int d = i >> 6, j = i & 63;
            slds[d][j] = (j < nn) ? sp[(size_t)d * HW3 + n0 + j] : 0.f;
        }
        __syncthreads();
        int full = nn & ~3;
        int n = 0;
        for (; n < full; n += 4) {
            float d00 = 0.f, d01 = 0.f, d02 = 0.f, d03 = 0.f;
            float d10 = 0.f, d11 = 0.f, d12 = 0.f, d13 = 0.f;
            #pragma unroll
            for (int d = 0; d < DCH; d++) {
                float4 sv = *reinterpret_cast<const float4*>(&slds[d][n]);
                d00 = fmaf(q0[d], sv.x, d00);
                d01 = fmaf(q0[d], sv.y, d01);
                d02 = fmaf(q0[d], sv.z, d02);
                d03 = fmaf(q0[d], sv.w, d03);
                d10 = fmaf(q1[d], sv.x, d10);
                d11 = fmaf(q1[d], sv.y, d11);
                d12 = fmaf(q1[d], sv.z, d12);
                d13 = fmaf(q1[d], sv.w, d13);
            }
            best0 = fmaxf(best0, fmaxf(fmaxf(d00, d01), fmaxf(d02, d03)));
            best1 = fmaxf(best1, fmaxf(fmaxf(d10, d11), fmaxf(d12, d13)));
        }
        for (; n < nn; n++) {
            float dd0 = 0.f, dd1 = 0.f;
            #pragma unroll
            for (int d = 0; d < DCH; d++) {
                float sv = slds[d][n];
                dd0 = fmaf(q0[d], sv, dd0);
                dd1 = fmaf(q1[d], sv, dd1);
            }
            best0 = fmaxf(best0, dd0);
            best1 = fmaxf(best1, dd1);
        }
    }

    float sum = best0 + (has1 ? best1 : 0.f);
    #pragma unroll
    for (int off = 32; off > 0; off >>= 1)
        sum += __shfl_xor(sum, off, 64);
    __shared__ float red[4];
    int wid = tid >> 6;
    if ((tid & 63) == 0) red[wid] = sum;
    __syncthreads();
    if (tid == 0) {
        float tot = red[0] + red[1] + red[2] + red[3];
        out[(size_t)imgq * WAY + way] = tot / (float)HW3;
    }
}

extern "C" void kernel_launch(void* const* d_in, const int* in_sizes, int n_in,
                              void* d_out, int out_size, void* d_ws, size_t ws_size,
                              hipStream_t stream) {
    const float* query   = (const float*)d_in[0];
    const float* support = (const float*)d_in[1];
    const float* w1 = (const float*)d_in[2];
    const float* w2 = (const float*)d_in[3];
    const float* w3 = (const float*)d_in[4];
    const float* w4 = (const float*)d_in[5];
    const float* s1 = (const float*)d_in[6];
    const float* b1 = (const float*)d_in[7];
    const float* s2 = (const float*)d_in[8];
    const float* b2 = (const float*)d_in[9];
    const float* s3 = (const float*)d_in[10];
    const float* b3 = (const float*)d_in[11];
    const float* s4 = (const float*)d_in[12];
    const float* b4 = (const float*)d_in[13];
    float* out = (float*)d_out;

    char* ws = (char*)d_ws;
    float* A  = (float*)ws;                                   // conv1 out (200,64,1764)
    float* Bb = (float*)(ws + 90316800);                      // conv2 out / q_local
    float* Cb = (float*)(ws + 90316800 + 22579200);           // conv3 out / s_local

    conv1_pool<<<NIMG * 16, 256, 0, stream>>>(query, support, w1, s1, b1, A);
    conv2_pool<<<NIMG * 8, 512, 0, stream>>>(A, w2, s2, b2, Bb);
    conv_np<<<NIMG * 8, 128, 0, stream>>>(Bb, w3, s3, b3, Cb);
    conv_np<<<NIMG * 8, 128, 0, stream>>>(Cb, w4, s4, b4, A);    // final feat in A

    q_norm<<<(NQIMG * HW3 + 255) / 256, 256, 0, stream>>>(A, Bb);
    s_mean_norm<<<(BDIM * WAY * HW3 + 255) / 256, 256, 0, stream>>>(A, Cb);

    sim_kernel<<<NQIMG * WAY, 256, 0, stream>>>(Bb, Cb, out);
}

// Round 4
// 632.038 us; speedup vs baseline: 8.9345x; 2.0841x over previous
//
#include <hip/hip_runtime.h>

#define EPS 1e-12f

// Problem constants
#define NIMG   200      // 150 query + 50 support
#define NQIMG  150
#define BDIM   2
#define NQ     75
#define WAY    5
#define SHOT   5
#define DCH    64
#define H1     84
#define H2     42
#define H3     21
#define HW2    1764     // 42*42
#define HW3    441      // 21*21

typedef __attribute__((ext_vector_type(8))) short bf16x8;
typedef __attribute__((ext_vector_type(4))) float f32x4;

__device__ __forceinline__ unsigned short f2bf(float f) {
    unsigned u = __float_as_uint(f);
    u += 0x7fffu + ((u >> 16) & 1u);
    return (unsigned short)(u >> 16);
}
__device__ __forceinline__ float bf2f(unsigned short h) {
    return __uint_as_float(((unsigned)h) << 16);
}

// ---------------- weight pack: OIHW f32 -> MFMA-fragment-ordered bf16 ----------------
// layout: [s=ky*3+kx][t=kstep][mt=co/16][lane][j]  value = w[co=16mt+(lane&15)][ci=32t+8*(lane>>4)+j][s]
__global__ __launch_bounds__(256) void pack_w(
    const float* __restrict__ w2, const float* __restrict__ w3,
    const float* __restrict__ w4, unsigned short* __restrict__ p2,
    unsigned short* __restrict__ p3, unsigned short* __restrict__ p4)
{
    int idx = blockIdx.x * 256 + threadIdx.x;
    if (idx >= 3 * 36864) return;
    int which = idx / 36864;
    int r = idx % 36864;
    int j = r & 7, lane = (r >> 3) & 63, mt = (r >> 9) & 3, t = (r >> 11) & 1, s = r >> 12;
    int co = (mt << 4) + (lane & 15);
    int ci = (t << 5) + ((lane >> 4) << 3) + j;
    const float* w = (which == 0) ? w2 : (which == 1) ? w3 : w4;
    unsigned short* p = (which == 0) ? p2 : (which == 1) ? p3 : p4;
    p[r] = f2bf(w[(co * 64 + ci) * 9 + s]);
}

// ---------------- conv1: 3->64 fp32 VALU, BN, ReLU, maxpool; out NHWC bf16 ----------------
__global__ __launch_bounds__(256, 2) void conv1_pool(
    const float* __restrict__ qin, const float* __restrict__ sin_,
    const float* __restrict__ w, const float* __restrict__ scale,
    const float* __restrict__ bias, unsigned short* __restrict__ out)
{
    int img = blockIdx.x >> 4;
    int g   = blockIdx.x & 15;        // co group: channels g*4 .. g*4+3
    const float* x = (img < NQIMG) ? (qin + (size_t)img * 3 * H1 * H1)
                                   : (sin_ + (size_t)(img - NQIMG) * 3 * H1 * H1);
    __shared__ __attribute__((aligned(16))) float wsm[4 * 3 * 12];
    int tid = threadIdx.x;
    for (int i = tid; i < 4 * 3 * 9; i += 256) {
        int coci = i / 9, k = i % 9;
        wsm[coci * 12 + k] = w[(size_t)g * 4 * 27 + i];
    }
    __syncthreads();

    float sc[4], bi[4];
    #pragma unroll
    for (int co = 0; co < 4; co++) { sc[co] = scale[g*4+co]; bi[co] = bias[g*4+co]; }

    for (int p = tid; p < HW2; p += 256) {
        int ph = p / H2, pw = p % H2;
        int y0 = 2 * ph, x0 = 2 * pw;
        float acc[4][4] = {};
        #pragma unroll
        for (int ci = 0; ci < 3; ci++) {
            const float* xp = x + (size_t)ci * H1 * H1;
            float patch[4][4];
            #pragma unroll
            for (int r = 0; r < 4; r++) {
                int iy = y0 - 1 + r;
                bool okr = (iy >= 0 && iy < H1);
                #pragma unroll
                for (int c = 0; c < 4; c++) {
                    int ix = x0 - 1 + c;
                    patch[r][c] = (okr && ix >= 0 && ix < H1) ? xp[iy * H1 + ix] : 0.f;
                }
            }
            #pragma unroll
            for (int co = 0; co < 4; co++) {
                const float* wp = &wsm[(co * 3 + ci) * 12];
                float4 wa = *reinterpret_cast<const float4*>(wp);
                float4 wb = *reinterpret_cast<const float4*>(wp + 4);
                float w8 = wp[8];
                #pragma unroll
                for (int dy = 0; dy < 2; dy++)
                    #pragma unroll
                    for (int dx = 0; dx < 2; dx++) {
                        float a = 0.f;
                        a = fmaf(patch[dy+0][dx+0], wa.x, a);
                        a = fmaf(patch[dy+0][dx+1], wa.y, a);
                        a = fmaf(patch[dy+0][dx+2], wa.z, a);
                        a = fmaf(patch[dy+1][dx+0], wa.w, a);
                        a = fmaf(patch[dy+1][dx+1], wb.x, a);
                        a = fmaf(patch[dy+1][dx+2], wb.y, a);
                        a = fmaf(patch[dy+2][dx+0], wb.z, a);
                        a = fmaf(patch[dy+2][dx+1], wb.w, a);
                        a = fmaf(patch[dy+2][dx+2], w8, a);
                        acc[co][dy*2+dx] += a;
                    }
            }
        }
        unsigned short uo[4];
        #pragma unroll
        for (int co = 0; co < 4; co++) {
            float v0 = acc[co][0]*sc[co]+bi[co], v1 = acc[co][1]*sc[co]+bi[co];
            float v2 = acc[co][2]*sc[co]+bi[co], v3 = acc[co][3]*sc[co]+bi[co];
            float m = fmaxf(fmaxf(v0, v1), fmaxf(v2, v3));
            uo[co] = f2bf(fmaxf(m, 0.f));
        }
        uint2 pk;
        pk.x = (unsigned)uo[0] | ((unsigned)uo[1] << 16);
        pk.y = (unsigned)uo[2] | ((unsigned)uo[3] << 16);
        *reinterpret_cast<uint2*>(out + ((size_t)img * HW2 + p) * DCH + (g << 2)) = pk;
    }
}

// ---------------- conv2: 64->64 MFMA, BN, ReLU, maxpool; NHWC bf16 in/out ----------------
// grid NIMG*7, block 256 (4 waves, each one 16-wide n-tile of the 441 outputs)
__global__ __launch_bounds__(256) void conv2_mfma_pool(
    const unsigned short* __restrict__ act,   // [img][1764][64]
    const unsigned short* __restrict__ wp,    // packed fragments
    const float* __restrict__ scale, const float* __restrict__ bias,
    unsigned short* __restrict__ out)         // [img][441][64]
{
    int img = blockIdx.x / 7, tg = blockIdx.x % 7;
    int wv = threadIdx.x >> 6, lane = threadIdx.x & 63;
    int lc = lane & 15, kgrp = lane >> 4;
    int p = (tg * 4 + wv) * 16 + lc;
    bool valid = p < HW3;
    int pc = valid ? p : HW3 - 1;
    int oy = pc / H3, ox = pc % H3;
    const unsigned short* ab = act + (size_t)img * HW2 * DCH;
    const bf16x8* wvv = (const bf16x8*)wp;

    f32x4 acc[4][4];
    #pragma unroll
    for (int i = 0; i < 4; i++)
        #pragma unroll
        for (int j = 0; j < 4; j++)
            acc[i][j] = (f32x4){0.f, 0.f, 0.f, 0.f};

    for (int s = 0; s < 9; s++) {
        int ky = s / 3 - 1, kx = s % 3 - 1;
        #pragma unroll
        for (int t = 0; t < 2; t++) {
            int fbase = ((s * 2 + t) * 4) << 6;
            bf16x8 a0 = wvv[fbase + lane];
            bf16x8 a1 = wvv[fbase + 64 + lane];
            bf16x8 a2 = wvv[fbase + 128 + lane];
            bf16x8 a3 = wvv[fbase + 192 + lane];
            bf16x8 b[4];
            #pragma unroll
            for (int sub = 0; sub < 4; sub++) {
                int y = 2 * oy + (sub >> 1) + ky;
                int x = 2 * ox + (sub & 1) + kx;
                bf16x8 bb = (bf16x8)(short)0;
                if ((unsigned)y < (unsigned)H2 && (unsigned)x < (unsigned)H2)
                    bb = *(const bf16x8*)(ab + (((size_t)(y * H2 + x)) << 6) + (t << 5) + (kgrp << 3));
                b[sub] = bb;
            }
            #pragma unroll
            for (int sub = 0; sub < 4; sub++) {
                acc[0][sub] = __builtin_amdgcn_mfma_f32_16x16x32_bf16(a0, b[sub], acc[0][sub], 0, 0, 0);
                acc[1][sub] = __builtin_amdgcn_mfma_f32_16x16x32_bf16(a1, b[sub], acc[1][sub], 0, 0, 0);
                acc[2][sub] = __builtin_amdgcn_mfma_f32_16x16x32_bf16(a2, b[sub], acc[2][sub], 0, 0, 0);
                acc[3][sub] = __builtin_amdgcn_mfma_f32_16x16x32_bf16(a3, b[sub], acc[3][sub], 0, 0, 0);
            }
        }
    }

    if (!valid) return;
    #pragma unroll
    for (int mt = 0; mt < 4; mt++) {
        int co0 = (mt << 4) + (kgrp << 2);
        float4 sc = *reinterpret_cast<const float4*>(scale + co0);
        float4 bi = *reinterpret_cast<const float4*>(bias + co0);
        unsigned short uo[4];
        #pragma unroll
        for (int r = 0; r < 4; r++) {
            float scr = (&sc.x)[r], bir = (&bi.x)[r];
            float v0 = acc[mt][0][r] * scr + bir;
            float v1 = acc[mt][1][r] * scr + bir;
            float v2 = acc[mt][2][r] * scr + bir;
            float v3 = acc[mt][3][r] * scr + bir;
            float m = fmaxf(fmaxf(v0, v1), fmaxf(v2, v3));
            uo[r] = f2bf(fmaxf(m, 0.f));
        }
        uint2 pk;
        pk.x = (unsigned)uo[0] | ((unsigned)uo[1] << 16);
        pk.y = (unsigned)uo[2] | ((unsigned)uo[3] << 16);
        *reinterpret_cast<uint2*>(out + ((size_t)img * HW3 + p) * DCH + co0) = pk;
    }
}

// ---------------- conv3/4: 64->64 MFMA, BN, ReLU, no pool; NHWC bf16 ----------------
// grid NIMG*7, block 128 (2 waves, each 2 n-tiles)
__global__ __launch_bounds__(128) void conv_mfma_np(
    const unsigned short* __restrict__ act,   // [img][441][64]
    const unsigned short* __restrict__ wp,
    const float* __restrict__ scale, const float* __restrict__ bias,
    unsigned short* __restrict__ out)         // [img][441][64]
{
    int img = blockIdx.x / 7, tg = blockIdx.x % 7;
    int wv = threadIdx.x >> 6, lane = threadIdx.x & 63;
    int lc = lane & 15, kgrp = lane >> 4;
    int p0 = (tg * 4 + wv * 2) * 16 + lc;
    int p1 = p0 + 16;
    bool v0 = p0 < HW3, v1 = p1 < HW3;
    int pc0 = v0 ? p0 : HW3 - 1, pc1 = v1 ? p1 : HW3 - 1;
    int oy0 = pc0 / H3, ox0 = pc0 % H3;
    int oy1 = pc1 / H3, ox1 = pc1 % H3;
    const unsigned short* ab = act + (size_t)img * HW3 * DCH;
    const bf16x8* wvv = (const bf16x8*)wp;

    f32x4 acc[4][2];
    #pragma unroll
    for (int i = 0; i < 4; i++) {
        acc[i][0] = (f32x4){0.f, 0.f, 0.f, 0.f};
        acc[i][1] = (f32x4){0.f, 0.f, 0.f, 0.f};
    }

    for (int s = 0; s < 9; s++) {
        int ky = s / 3 - 1, kx = s % 3 - 1;
        #pragma unroll
        for (int t = 0; t < 2; t++) {
            int fbase = ((s * 2 + t) * 4) << 6;
            bf16x8 a0 = wvv[fbase + lane];
            bf16x8 a1 = wvv[fbase + 64 + lane];
            bf16x8 a2 = wvv[fbase + 128 + lane];
            bf16x8 a3 = wvv[fbase + 192 + lane];
            int y0 = oy0 + ky, x0 = ox0 + kx;
            int y1 = oy1 + ky, x1 = ox1 + kx;
            bf16x8 b0 = (bf16x8)(short)0, b1 = (bf16x8)(short)0;
            if ((unsigned)y0 < (unsigned)H3 && (unsigned)x0 < (unsigned)H3)
                b0 = *(const bf16x8*)(ab + (((size_t)(y0 * H3 + x0)) << 6) + (t << 5) + (kgrp << 3));
            if ((unsigned)y1 < (unsigned)H3 && (unsigned)x1 < (unsigned)H3)
                b1 = *(const bf16x8*)(ab + (((size_t)(y1 * H3 + x1)) << 6) + (t << 5) + (kgrp << 3));
            acc[0][0] = __builtin_amdgcn_mfma_f32_16x16x32_bf16(a0, b0, acc[0][0], 0, 0, 0);
            acc[1][0] = __builtin_amdgcn_mfma_f32_16x16x32_bf16(a1, b0, acc[1][0], 0, 0, 0);
            acc[2][0] = __builtin_amdgcn_mfma_f32_16x16x32_bf16(a2, b0, acc[2][0], 0, 0, 0);
            acc[3][0] = __builtin_amdgcn_mfma_f32_16x16x32_bf16(a3, b0, acc[3][0], 0, 0, 0);
            acc[0][1] = __builtin_amdgcn_mfma_f32_16x16x32_bf16(a0, b1, acc[0][1], 0, 0, 0);
            acc[1][1] = __builtin_amdgcn_mfma_f32_16x16x32_bf16(a1, b1, acc[1][1], 0, 0, 0);
            acc[2][1] = __builtin_amdgcn_mfma_f32_16x16x32_bf16(a2, b1, acc[2][1], 0, 0, 0);
            acc[3][1] = __builtin_amdgcn_mfma_f32_16x16x32_bf16(a3, b1, acc[3][1], 0, 0, 0);
        }
    }

    #pragma unroll
    for (int mt = 0; mt < 4; mt++) {
        int co0 = (mt << 4) + (kgrp << 2);
        float4 sc = *reinterpret_cast<const float4*>(scale + co0);
        float4 bi = *reinterpret_cast<const float4*>(bias + co0);
        #pragma unroll
        for (int nt = 0; nt < 2; nt++) {
            bool vld = nt == 0 ? v0 : v1;
            if (!vld) continue;
            int pp = nt == 0 ? p0 : p1;
            unsigned short uo[4];
            #pragma unroll
            for (int r = 0; r < 4; r++) {
                float v = acc[mt][nt][r] * (&sc.x)[r] + (&bi.x)[r];
                uo[r] = f2bf(fmaxf(v, 0.f));
            }
            uint2 pk;
            pk.x = (unsigned)uo[0] | ((unsigned)uo[1] << 16);
            pk.y = (unsigned)uo[2] | ((unsigned)uo[3] << 16);
            *reinterpret_cast<uint2*>(out + ((size_t)img * HW3 + pp) * DCH + co0) = pk;
        }
    }
}

// ---------------- query L2-normalize: NHWC bf16 -> [img][d][441] f32 ----------------
__global__ __launch_bounds__(256) void q_norm(
    const unsigned short* __restrict__ feat, float* __restrict__ q_local)
{
    int idx = blockIdx.x * 256 + threadIdx.x;
    if (idx >= NQIMG * HW3) return;
    int img = idx / HW3, hw = idx % HW3;
    const bf16x8* f = (const bf16x8*)(feat + (size_t)idx * DCH);
    float v[DCH];
    float ss = 0.f;
    #pragma unroll
    for (int g = 0; g < 8; g++) {
        bf16x8 x = f[g];
        #pragma unroll
        for (int j = 0; j < 8; j++) {
            float vv = bf2f((unsigned short)x[j]);
            v[g * 8 + j] = vv;
            ss = fmaf(vv, vv, ss);
        }
    }
    float inv = 1.f / fmaxf(sqrtf(ss), EPS);
    float* o = q_local + (size_t)img * DCH * HW3 + hw;
    #pragma unroll
    for (int d = 0; d < DCH; d++) o[(size_t)d * HW3] = v[d] * inv;
}

// ---------------- support: mean over shots + L2-normalize ----------------
__global__ __launch_bounds__(256) void s_mean_norm(
    const unsigned short* __restrict__ feat, float* __restrict__ s_local)
{
    int idx = blockIdx.x * 256 + threadIdx.x;
    if (idx >= BDIM * WAY * HW3) return;
    int hw = idx % HW3;
    int bc = idx / HW3;
    int img0 = NQIMG + bc * SHOT;
    float v[DCH];
    #pragma unroll
    for (int d = 0; d < DCH; d++) v[d] = 0.f;
    for (int sh = 0; sh < SHOT; sh++) {
        const bf16x8* f = (const bf16x8*)(feat + ((size_t)(img0 + sh) * HW3 + hw) * DCH);
        #pragma unroll
        for (int g = 0; g < 8; g++) {
            bf16x8 x = f[g];
            #pragma unroll
            for (int j = 0; j < 8; j++)
                v[g * 8 + j] += bf2f((unsigned short)x[j]);
        }
    }
    float ss = 0.f;
    #pragma unroll
    for (int d = 0; d < DCH; d++) {
        v[d] *= (1.f / SHOT);
        ss = fmaf(v[d], v[d], ss);
    }
    float inv = 1.f / fmaxf(sqrtf(ss), EPS);
    float* o = s_local + (size_t)bc * DCH * HW3 + hw;
    #pragma unroll
    for (int d = 0; d < DCH; d++) o[(size_t)d * HW3] = v[d] * inv;
}

// ---------------- similarity (fp32, unchanged) ----------------
__global__ __launch_bounds__(256) void sim_kernel(
    const float* __restrict__ q_local, const float* __restrict__ s_local,
    float* __restrict__ out)
{
    int blk = blockIdx.x;
    int imgq = blk / WAY, way = blk % WAY;
    int b = imgq / NQ;
    const float* qp = q_local + (size_t)imgq * DCH * HW3;
    const float* sp = s_local + (size_t)(b * WAY + way) * DCH * HW3;

    __shared__ float slds[DCH][64];
    int tid = threadIdx.x;
    int m1 = tid + 256;
    bool has1 = (m1 < HW3);

    float q0[DCH], q1[DCH];
    #pragma unroll
    for (int d = 0; d < DCH; d++) {
        q0[d] = qp[(size_t)d * HW3 + tid];
        q1[d] = has1 ? qp[(size_t)d * HW3 + m1] : 0.f;
    }

    float best0 = -1e30f, best1 = -1e30f;
    for (int n0 = 0; n0 < HW3; n0 += 64) {
        int nn = (HW3 - n0 < 64) ? (HW3 - n0) : 64;
        __syncthreads();
        for (int i = tid; i < DCH * 64; i += 256) {
            int d = i >> 6, j = i & 63;
            slds[d][j] = (j < nn) ? sp[(size_t)d * HW3 + n0 + j] : 0.f;
        }
        __syncthreads();
        int full = nn & ~3;
        int n = 0;
        for (; n < full; n += 4) {
            float d00 = 0.f, d01 = 0.f, d02 = 0.f, d03 = 0.f;
            float d10 = 0.f, d11 = 0.f, d12 = 0.f, d13 = 0.f;
            #pragma unroll
            for (int d = 0; d < DCH; d++) {
                float4 sv = *reinterpret_cast<const float4*>(&slds[d][n]);
                d00 = fmaf(q0[d], sv.x, d00);
                d01 = fmaf(q0[d], sv.y, d01);
                d02 = fmaf(q0[d], sv.z, d02);
                d03 = fmaf(q0[d], sv.w, d03);
                d10 = fmaf(q1[d], sv.x, d10);
                d11 = fmaf(q1[d], sv.y, d11);
                d12 = fmaf(q1[d], sv.z, d12);
                d13 = fmaf(q1[d], sv.w, d13);
            }
            best0 = fmaxf(best0, fmaxf(fmaxf(d00, d01), fmaxf(d02, d03)));
            best1 = fmaxf(best1, fmaxf(fmaxf(d10, d11), fmaxf(d12, d13)));
        }
        for (; n < nn; n++) {
            float dd0 = 0.f, dd1 = 0.f;
            #pragma unroll
            for (int d = 0; d < DCH; d++) {
                float sv = slds[d][n];
                dd0 = fmaf(q0[d], sv, dd0);
                dd1 = fmaf(q1[d], sv, dd1);
            }
            best0 = fmaxf(best0, dd0);
            best1 = fmaxf(best1, dd1);
        }
    }

    float sum = best0 + (has1 ? best1 : 0.f);
    #pragma unroll
    for (int off = 32; off > 0; off >>= 1)
        sum += __shfl_xor(sum, off, 64);
    __shared__ float red[4];
    int wid = tid >> 6;
    if ((tid & 63) == 0) red[wid] = sum;
    __syncthreads();
    if (tid == 0) {
        float tot = red[0] + red[1] + red[2] + red[3];
        out[(size_t)imgq * WAY + way] = tot / (float)HW3;
    }
}

extern "C" void kernel_launch(void* const* d_in, const int* in_sizes, int n_in,
                              void* d_out, int out_size, void* d_ws, size_t ws_size,
                              hipStream_t stream) {
    const float* query   = (const float*)d_in[0];
    const float* support = (const float*)d_in[1];
    const float* w1 = (const float*)d_in[2];
    const float* w2 = (const float*)d_in[3];
    const float* w3 = (const float*)d_in[4];
    const float* w4 = (const float*)d_in[5];
    const float* s1 = (const float*)d_in[6];
    const float* b1 = (const float*)d_in[7];
    const float* s2 = (const float*)d_in[8];
    const float* b2 = (const float*)d_in[9];
    const float* s3 = (const float*)d_in[10];
    const float* b3 = (const float*)d_in[11];
    const float* s4 = (const float*)d_in[12];
    const float* b4 = (const float*)d_in[13];
    float* out = (float*)d_out;

    char* ws = (char*)d_ws;
    unsigned short* A1  = (unsigned short*)(ws);              // 200*1764*64 bf16 = 45,158,400 B
    unsigned short* A2  = (unsigned short*)(ws + 45158400);   // 200*441*64 bf16 = 11,289,600 B
    unsigned short* A3  = (unsigned short*)(ws + 56448000);
    unsigned short* A4  = (unsigned short*)(ws + 67737600);
    float*          QL  = (float*)(ws + 79027200);            // 150*64*441 f32 = 16,934,400 B
    float*          SL  = (float*)(ws + 95961600);            // 10*64*441 f32 = 1,128,960 B
    unsigned short* WP2 = (unsigned short*)(ws + 97090560);   // 36864 bf16 = 73,728 B
    unsigned short* WP3 = (unsigned short*)(ws + 97164288);
    unsigned short* WP4 = (unsigned short*)(ws + 97238016);

    pack_w<<<(3 * 36864 + 255) / 256, 256, 0, stream>>>(w2, w3, w4, WP2, WP3, WP4);
    conv1_pool<<<NIMG * 16, 256, 0, stream>>>(query, support, w1, s1, b1, A1);
    conv2_mfma_pool<<<NIMG * 7, 256, 0, stream>>>(A1, WP2, s2, b2, A2);
    conv_mfma_np<<<NIMG * 7, 128, 0, stream>>>(A2, WP3, s3, b3, A3);
    conv_mfma_np<<<NIMG * 7, 128, 0, stream>>>(A3, WP4, s4, b4, A4);

    q_norm<<<(NQIMG * HW3 + 255) / 256, 256, 0, stream>>>(A4, QL);
    s_mean_norm<<<(BDIM * WAY * HW3 + 255) / 256, 256, 0, stream>>>(A4, SL);

    sim_kernel<<<NQIMG * WAY, 256, 0, stream>>>(QL, SL, out);
}

// Round 5
// 329.882 us; speedup vs baseline: 17.1180x; 1.9159x over previous
//
#include <hip/hip_runtime.h>

#define EPS 1e-12f

// Problem constants
#define NIMG   200      // 150 query + 50 support
#define NQIMG  150
#define BDIM   2
#define NQ     75
#define WAY    5
#define SHOT   5
#define DCH    64
#define H1     84
#define H2     42
#define H3     21
#define HW2    1764     // 42*42
#define HW3    441      // 21*21

typedef __attribute__((ext_vector_type(8))) short bf16x8;
typedef __attribute__((ext_vector_type(4))) float f32x4;

__device__ __forceinline__ unsigned short f2bf(float f) {
    unsigned u = __float_as_uint(f);
    u += 0x7fffu + ((u >> 16) & 1u);
    return (unsigned short)(u >> 16);
}
__device__ __forceinline__ float bf2f(unsigned short h) {
    return __uint_as_float(((unsigned)h) << 16);
}

// ---------------- weight pack: OIHW f32 -> MFMA-fragment-ordered bf16 ----------------
// layout: [s=ky*3+kx][t=kstep][mt=co/16][lane][j]  value = w[co=16mt+(lane&15)][ci=32t+8*(lane>>4)+j][s]
__global__ __launch_bounds__(256) void pack_w(
    const float* __restrict__ w2, const float* __restrict__ w3,
    const float* __restrict__ w4, unsigned short* __restrict__ p2,
    unsigned short* __restrict__ p3, unsigned short* __restrict__ p4)
{
    int idx = blockIdx.x * 256 + threadIdx.x;
    if (idx >= 3 * 36864) return;
    int which = idx / 36864;
    int r = idx % 36864;
    int j = r & 7, lane = (r >> 3) & 63, mt = (r >> 9) & 3, t = (r >> 11) & 1, s = r >> 12;
    int co = (mt << 4) + (lane & 15);
    int ci = (t << 5) + ((lane >> 4) << 3) + j;
    const float* w = (which == 0) ? w2 : (which == 1) ? w3 : w4;
    unsigned short* p = (which == 0) ? p2 : (which == 1) ? p3 : p4;
    p[r] = f2bf(w[(co * 64 + ci) * 9 + s]);
}

// ---------------- conv1: 3->64 fp32 VALU, BN, ReLU, maxpool; out NHWC bf16 ----------------
__global__ __launch_bounds__(256, 2) void conv1_pool(
    const float* __restrict__ qin, const float* __restrict__ sin_,
    const float* __restrict__ w, const float* __restrict__ scale,
    const float* __restrict__ bias, unsigned short* __restrict__ out)
{
    int img = blockIdx.x >> 4;
    int g   = blockIdx.x & 15;        // co group: channels g*4 .. g*4+3
    const float* x = (img < NQIMG) ? (qin + (size_t)img * 3 * H1 * H1)
                                   : (sin_ + (size_t)(img - NQIMG) * 3 * H1 * H1);
    __shared__ __attribute__((aligned(16))) float wsm[4 * 3 * 12];
    int tid = threadIdx.x;
    for (int i = tid; i < 4 * 3 * 9; i += 256) {
        int coci = i / 9, k = i % 9;
        wsm[coci * 12 + k] = w[(size_t)g * 4 * 27 + i];
    }
    __syncthreads();

    float sc[4], bi[4];
    #pragma unroll
    for (int co = 0; co < 4; co++) { sc[co] = scale[g*4+co]; bi[co] = bias[g*4+co]; }

    for (int p = tid; p < HW2; p += 256) {
        int ph = p / H2, pw = p % H2;
        int y0 = 2 * ph, x0 = 2 * pw;
        float acc[4][4] = {};
        #pragma unroll
        for (int ci = 0; ci < 3; ci++) {
            const float* xp = x + (size_t)ci * H1 * H1;
            float patch[4][4];
            #pragma unroll
            for (int r = 0; r < 4; r++) {
                int iy = y0 - 1 + r;
                bool okr = (iy >= 0 && iy < H1);
                #pragma unroll
                for (int c = 0; c < 4; c++) {
                    int ix = x0 - 1 + c;
                    patch[r][c] = (okr && ix >= 0 && ix < H1) ? xp[iy * H1 + ix] : 0.f;
                }
            }
            #pragma unroll
            for (int co = 0; co < 4; co++) {
                const float* wp = &wsm[(co * 3 + ci) * 12];
                float4 wa = *reinterpret_cast<const float4*>(wp);
                float4 wb = *reinterpret_cast<const float4*>(wp + 4);
                float w8 = wp[8];
                #pragma unroll
                for (int dy = 0; dy < 2; dy++)
                    #pragma unroll
                    for (int dx = 0; dx < 2; dx++) {
                        float a = 0.f;
                        a = fmaf(patch[dy+0][dx+0], wa.x, a);
                        a = fmaf(patch[dy+0][dx+1], wa.y, a);
                        a = fmaf(patch[dy+0][dx+2], wa.z, a);
                        a = fmaf(patch[dy+1][dx+0], wa.w, a);
                        a = fmaf(patch[dy+1][dx+1], wb.x, a);
                        a = fmaf(patch[dy+1][dx+2], wb.y, a);
                        a = fmaf(patch[dy+2][dx+0], wb.z, a);
                        a = fmaf(patch[dy+2][dx+1], wb.w, a);
                        a = fmaf(patch[dy+2][dx+2], w8, a);
                        acc[co][dy*2+dx] += a;
                    }
            }
        }
        unsigned short uo[4];
        #pragma unroll
        for (int co = 0; co < 4; co++) {
            float v0 = acc[co][0]*sc[co]+bi[co], v1 = acc[co][1]*sc[co]+bi[co];
            float v2 = acc[co][2]*sc[co]+bi[co], v3 = acc[co][3]*sc[co]+bi[co];
            float m = fmaxf(fmaxf(v0, v1), fmaxf(v2, v3));
            uo[co] = f2bf(fmaxf(m, 0.f));
        }
        uint2 pk;
        pk.x = (unsigned)uo[0] | ((unsigned)uo[1] << 16);
        pk.y = (unsigned)uo[2] | ((unsigned)uo[3] << 16);
        *reinterpret_cast<uint2*>(out + ((size_t)img * HW2 + p) * DCH + (g << 2)) = pk;
    }
}

// ---------------- conv2: 64->64 MFMA, BN, ReLU, maxpool; NHWC bf16 in/out ----------------
__global__ __launch_bounds__(256) void conv2_mfma_pool(
    const unsigned short* __restrict__ act,   // [img][1764][64]
    const unsigned short* __restrict__ wp,    // packed fragments
    const float* __restrict__ scale, const float* __restrict__ bias,
    unsigned short* __restrict__ out)         // [img][441][64]
{
    int img = blockIdx.x / 7, tg = blockIdx.x % 7;
    int wv = threadIdx.x >> 6, lane = threadIdx.x & 63;
    int lc = lane & 15, kgrp = lane >> 4;
    int p = (tg * 4 + wv) * 16 + lc;
    bool valid = p < HW3;
    int pc = valid ? p : HW3 - 1;
    int oy = pc / H3, ox = pc % H3;
    const unsigned short* ab = act + (size_t)img * HW2 * DCH;
    const bf16x8* wvv = (const bf16x8*)wp;

    f32x4 acc[4][4];
    #pragma unroll
    for (int i = 0; i < 4; i++)
        #pragma unroll
        for (int j = 0; j < 4; j++)
            acc[i][j] = (f32x4){0.f, 0.f, 0.f, 0.f};

    for (int s = 0; s < 9; s++) {
        int ky = s / 3 - 1, kx = s % 3 - 1;
        #pragma unroll
        for (int t = 0; t < 2; t++) {
            int fbase = ((s * 2 + t) * 4) << 6;
            bf16x8 a0 = wvv[fbase + lane];
            bf16x8 a1 = wvv[fbase + 64 + lane];
            bf16x8 a2 = wvv[fbase + 128 + lane];
            bf16x8 a3 = wvv[fbase + 192 + lane];
            bf16x8 b[4];
            #pragma unroll
            for (int sub = 0; sub < 4; sub++) {
                int y = 2 * oy + (sub >> 1) + ky;
                int x = 2 * ox + (sub & 1) + kx;
                bf16x8 bb = (bf16x8)(short)0;
                if ((unsigned)y < (unsigned)H2 && (unsigned)x < (unsigned)H2)
                    bb = *(const bf16x8*)(ab + (((size_t)(y * H2 + x)) << 6) + (t << 5) + (kgrp << 3));
                b[sub] = bb;
            }
            #pragma unroll
            for (int sub = 0; sub < 4; sub++) {
                acc[0][sub] = __builtin_amdgcn_mfma_f32_16x16x32_bf16(a0, b[sub], acc[0][sub], 0, 0, 0);
                acc[1][sub] = __builtin_amdgcn_mfma_f32_16x16x32_bf16(a1, b[sub], acc[1][sub], 0, 0, 0);
                acc[2][sub] = __builtin_amdgcn_mfma_f32_16x16x32_bf16(a2, b[sub], acc[2][sub], 0, 0, 0);
                acc[3][sub] = __builtin_amdgcn_mfma_f32_16x16x32_bf16(a3, b[sub], acc[3][sub], 0, 0, 0);
            }
        }
    }

    if (!valid) return;
    #pragma unroll
    for (int mt = 0; mt < 4; mt++) {
        int co0 = (mt << 4) + (kgrp << 2);
        float4 sc = *reinterpret_cast<const float4*>(scale + co0);
        float4 bi = *reinterpret_cast<const float4*>(bias + co0);
        unsigned short uo[4];
        #pragma unroll
        for (int r = 0; r < 4; r++) {
            float scr = (&sc.x)[r], bir = (&bi.x)[r];
            float v0 = acc[mt][0][r] * scr + bir;
            float v1 = acc[mt][1][r] * scr + bir;
            float v2 = acc[mt][2][r] * scr + bir;
            float v3 = acc[mt][3][r] * scr + bir;
            float m = fmaxf(fmaxf(v0, v1), fmaxf(v2, v3));
            uo[r] = f2bf(fmaxf(m, 0.f));
        }
        uint2 pk;
        pk.x = (unsigned)uo[0] | ((unsigned)uo[1] << 16);
        pk.y = (unsigned)uo[2] | ((unsigned)uo[3] << 16);
        *reinterpret_cast<uint2*>(out + ((size_t)img * HW3 + p) * DCH + co0) = pk;
    }
}

// ---------------- conv3/4: 64->64 MFMA, BN, ReLU, no pool; NHWC bf16 ----------------
__global__ __launch_bounds__(128) void conv_mfma_np(
    const unsigned short* __restrict__ act,   // [img][441][64]
    const unsigned short* __restrict__ wp,
    const float* __restrict__ scale, const float* __restrict__ bias,
    unsigned short* __restrict__ out)         // [img][441][64]
{
    int img = blockIdx.x / 7, tg = blockIdx.x % 7;
    int wv = threadIdx.x >> 6, lane = threadIdx.x & 63;
    int lc = lane & 15, kgrp = lane >> 4;
    int p0 = (tg * 4 + wv * 2) * 16 + lc;
    int p1 = p0 + 16;
    bool v0 = p0 < HW3, v1 = p1 < HW3;
    int pc0 = v0 ? p0 : HW3 - 1, pc1 = v1 ? p1 : HW3 - 1;
    int oy0 = pc0 / H3, ox0 = pc0 % H3;
    int oy1 = pc1 / H3, ox1 = pc1 % H3;
    const unsigned short* ab = act + (size_t)img * HW3 * DCH;
    const bf16x8* wvv = (const bf16x8*)wp;

    f32x4 acc[4][2];
    #pragma unroll
    for (int i = 0; i < 4; i++) {
        acc[i][0] = (f32x4){0.f, 0.f, 0.f, 0.f};
        acc[i][1] = (f32x4){0.f, 0.f, 0.f, 0.f};
    }

    for (int s = 0; s < 9; s++) {
        int ky = s / 3 - 1, kx = s % 3 - 1;
        #pragma unroll
        for (int t = 0; t < 2; t++) {
            int fbase = ((s * 2 + t) * 4) << 6;
            bf16x8 a0 = wvv[fbase + lane];
            bf16x8 a1 = wvv[fbase + 64 + lane];
            bf16x8 a2 = wvv[fbase + 128 + lane];
            bf16x8 a3 = wvv[fbase + 192 + lane];
            int y0 = oy0 + ky, x0 = ox0 + kx;
            int y1 = oy1 + ky, x1 = ox1 + kx;
            bf16x8 b0 = (bf16x8)(short)0, b1 = (bf16x8)(short)0;
            if ((unsigned)y0 < (unsigned)H3 && (unsigned)x0 < (unsigned)H3)
                b0 = *(const bf16x8*)(ab + (((size_t)(y0 * H3 + x0)) << 6) + (t << 5) + (kgrp << 3));
            if ((unsigned)y1 < (unsigned)H3 && (unsigned)x1 < (unsigned)H3)
                b1 = *(const bf16x8*)(ab + (((size_t)(y1 * H3 + x1)) << 6) + (t << 5) + (kgrp << 3));
            acc[0][0] = __builtin_amdgcn_mfma_f32_16x16x32_bf16(a0, b0, acc[0][0], 0, 0, 0);
            acc[1][0] = __builtin_amdgcn_mfma_f32_16x16x32_bf16(a1, b0, acc[1][0], 0, 0, 0);
            acc[2][0] = __builtin_amdgcn_mfma_f32_16x16x32_bf16(a2, b0, acc[2][0], 0, 0, 0);
            acc[3][0] = __builtin_amdgcn_mfma_f32_16x16x32_bf16(a3, b0, acc[3][0], 0, 0, 0);
            acc[0][1] = __builtin_amdgcn_mfma_f32_16x16x32_bf16(a0, b1, acc[0][1], 0, 0, 0);
            acc[1][1] = __builtin_amdgcn_mfma_f32_16x16x32_bf16(a1, b1, acc[1][1], 0, 0, 0);
            acc[2][1] = __builtin_amdgcn_mfma_f32_16x16x32_bf16(a2, b1, acc[2][1], 0, 0, 0);
            acc[3][1] = __builtin_amdgcn_mfma_f32_16x16x32_bf16(a3, b1, acc[3][1], 0, 0, 0);
        }
    }

    #pragma unroll
    for (int mt = 0; mt < 4; mt++) {
        int co0 = (mt << 4) + (kgrp << 2);
        float4 sc = *reinterpret_cast<const float4*>(scale + co0);
        float4 bi = *reinterpret_cast<const float4*>(bias + co0);
        #pragma unroll
        for (int nt = 0; nt < 2; nt++) {
            bool vld = nt == 0 ? v0 : v1;
            if (!vld) continue;
            int pp = nt == 0 ? p0 : p1;
            unsigned short uo[4];
            #pragma unroll
            for (int r = 0; r < 4; r++) {
                float v = acc[mt][nt][r] * (&sc.x)[r] + (&bi.x)[r];
                uo[r] = f2bf(fmaxf(v, 0.f));
            }
            uint2 pk;
            pk.x = (unsigned)uo[0] | ((unsigned)uo[1] << 16);
            pk.y = (unsigned)uo[2] | ((unsigned)uo[3] << 16);
            *reinterpret_cast<uint2*>(out + ((size_t)img * HW3 + pp) * DCH + co0) = pk;
        }
    }
}

// ---------------- query L2-normalize: NHWC bf16 -> [img][hw][64] bf16 ----------------
__global__ __launch_bounds__(256) void q_norm(
    const unsigned short* __restrict__ feat, unsigned short* __restrict__ q_local)
{
    int idx = blockIdx.x * 256 + threadIdx.x;
    if (idx >= NQIMG * HW3) return;
    const bf16x8* f = (const bf16x8*)(feat + (size_t)idx * DCH);
    float v[DCH];
    float ss = 0.f;
    #pragma unroll
    for (int g = 0; g < 8; g++) {
        bf16x8 x = f[g];
        #pragma unroll
        for (int j = 0; j < 8; j++) {
            float vv = bf2f((unsigned short)x[j]);
            v[g * 8 + j] = vv;
            ss = fmaf(vv, vv, ss);
        }
    }
    float inv = 1.f / fmaxf(sqrtf(ss), EPS);
    bf16x8* o = (bf16x8*)(q_local + (size_t)idx * DCH);
    #pragma unroll
    for (int g = 0; g < 8; g++) {
        bf16x8 pk;
        #pragma unroll
        for (int j = 0; j < 8; j++) pk[j] = (short)f2bf(v[g * 8 + j] * inv);
        o[g] = pk;
    }
}

// ---------------- support: mean over shots + L2-normalize -> [bc][hw][64] bf16 ----------------
__global__ __launch_bounds__(256) void s_mean_norm(
    const unsigned short* __restrict__ feat, unsigned short* __restrict__ s_local)
{
    int idx = blockIdx.x * 256 + threadIdx.x;
    if (idx >= BDIM * WAY * HW3) return;
    int hw = idx % HW3;
    int bc = idx / HW3;
    int img0 = NQIMG + bc * SHOT;
    float v[DCH];
    #pragma unroll
    for (int d = 0; d < DCH; d++) v[d] = 0.f;
    for (int sh = 0; sh < SHOT; sh++) {
        const bf16x8* f = (const bf16x8*)(feat + ((size_t)(img0 + sh) * HW3 + hw) * DCH);
        #pragma unroll
        for (int g = 0; g < 8; g++) {
            bf16x8 x = f[g];
            #pragma unroll
            for (int j = 0; j < 8; j++)
                v[g * 8 + j] += bf2f((unsigned short)x[j]);
        }
    }
    float ss = 0.f;
    #pragma unroll
    for (int d = 0; d < DCH; d++) {
        v[d] *= (1.f / SHOT);
        ss = fmaf(v[d], v[d], ss);
    }
    float inv = 1.f / fmaxf(sqrtf(ss), EPS);
    bf16x8* o = (bf16x8*)(s_local + (size_t)idx * DCH);
    #pragma unroll
    for (int g = 0; g < 8; g++) {
        bf16x8 pk;
        #pragma unroll
        for (int j = 0; j < 8; j++) pk[j] = (short)f2bf(v[g * 8 + j] * inv);
        o[g] = pk;
    }
}

// ---------------- similarity via MFMA ----------------
// grid: 750 (imgq*WAY+way), block 256 (4 waves). Each wave owns 7 m-tiles,
// holds their q fragments in registers; s staged in LDS (row pad 72 shorts
// -> 2-way-free bank pattern); 2 LDS reads amortized over 14 MFMAs per n-tile.
#define SLDW 72
__global__ __launch_bounds__(256) void sim_mfma(
    const unsigned short* __restrict__ qloc,  // [150][441][64] bf16
    const unsigned short* __restrict__ sloc,  // [10][441][64] bf16
    float* __restrict__ out)
{
    int blk = blockIdx.x;
    int imgq = blk / WAY, way = blk % WAY;
    int b = imgq / NQ;
    const unsigned short* qp = qloc + (size_t)imgq * HW3 * DCH;
    const unsigned short* sp = sloc + (size_t)(b * WAY + way) * HW3 * DCH;

    __shared__ unsigned short slds[448 * SLDW];
    int tid = threadIdx.x;
    for (int i = tid; i < 448 * 8; i += 256) {
        int row = i >> 3, ch = (i & 7) << 3;
        bf16x8 v = (bf16x8)(short)0;
        if (row < HW3) v = *(const bf16x8*)(sp + (size_t)row * DCH + ch);
        *(bf16x8*)(&slds[row * SLDW + ch]) = v;
    }
    __syncthreads();

    int wv = tid >> 6, lane = tid & 63;
    int lc = lane & 15, kg = lane >> 4;
    int mt0 = wv * 7;

    // q fragments for this wave's 7 m-tiles (rows m0+lc, k-chunks kg*8 / +32)
    bf16x8 qa0[7], qa1[7];
    #pragma unroll
    for (int i = 0; i < 7; i++) {
        const unsigned short* qrow = qp + (size_t)((mt0 + i) * 16 + lc) * DCH + (kg << 3);
        qa0[i] = *(const bf16x8*)(qrow);
        qa1[i] = *(const bf16x8*)(qrow + 32);
    }
    f32x4 rmax[7];
    #pragma unroll
    for (int i = 0; i < 7; i++)
        rmax[i] = (f32x4){-1e30f, -1e30f, -1e30f, -1e30f};

    for (int nt = 0; nt < 27; nt++) {
        const unsigned short* srow = &slds[(nt * 16 + lc) * SLDW + (kg << 3)];
        bf16x8 sb0 = *(const bf16x8*)(srow);
        bf16x8 sb1 = *(const bf16x8*)(srow + 32);
        #pragma unroll
        for (int i = 0; i < 7; i++) {
            f32x4 acc = (f32x4){0.f, 0.f, 0.f, 0.f};
            acc = __builtin_amdgcn_mfma_f32_16x16x32_bf16(qa0[i], sb0, acc, 0, 0, 0);
            acc = __builtin_amdgcn_mfma_f32_16x16x32_bf16(qa1[i], sb1, acc, 0, 0, 0);
            rmax[i][0] = fmaxf(rmax[i][0], acc[0]);
            rmax[i][1] = fmaxf(rmax[i][1], acc[1]);
            rmax[i][2] = fmaxf(rmax[i][2], acc[2]);
            rmax[i][3] = fmaxf(rmax[i][3], acc[3]);
        }
    }
    {   // last n-tile (cols 432..447): mask invalid cols
        const unsigned short* srow = &slds[(432 + lc) * SLDW + (kg << 3)];
        bf16x8 sb0 = *(const bf16x8*)(srow);
        bf16x8 sb1 = *(const bf16x8*)(srow + 32);
        bool nval = (432 + lc) < HW3;
        #pragma unroll
        for (int i = 0; i < 7; i++) {
            f32x4 acc = (f32x4){0.f, 0.f, 0.f, 0.f};
            acc = __builtin_amdgcn_mfma_f32_16x16x32_bf16(qa0[i], sb0, acc, 0, 0, 0);
            acc = __builtin_amdgcn_mfma_f32_16x16x32_bf16(qa1[i], sb1, acc, 0, 0, 0);
            #pragma unroll
            for (int r = 0; r < 4; r++)
                rmax[i][r] = fmaxf(rmax[i][r], nval ? acc[r] : -1e30f);
        }
    }

    // per-row max across the 16 n-cols (lanes lc=0..15), then masked mean sum
    float msum = 0.f;
    #pragma unroll
    for (int i = 0; i < 7; i++) {
        #pragma unroll
        for (int r = 0; r < 4; r++) {
            float v = rmax[i][r];
            v = fmaxf(v, __shfl_xor(v, 1, 64));
            v = fmaxf(v, __shfl_xor(v, 2, 64));
            v = fmaxf(v, __shfl_xor(v, 4, 64));
            v = fmaxf(v, __shfl_xor(v, 8, 64));
            int m = (mt0 + i) * 16 + (kg << 2) + r;
            if (lc == 0 && m < HW3) msum += v;
        }
    }
    #pragma unroll
    for (int off = 32; off > 0; off >>= 1)
        msum += __shfl_xor(msum, off, 64);
    __shared__ float red[4];
    if (lane == 0) red[wv] = msum;
    __syncthreads();
    if (tid == 0)
        out[(size_t)imgq * WAY + way] = (red[0] + red[1] + red[2] + red[3]) * (1.f / HW3);
}

extern "C" void kernel_launch(void* const* d_in, const int* in_sizes, int n_in,
                              void* d_out, int out_size, void* d_ws, size_t ws_size,
                              hipStream_t stream) {
    const float* query   = (const float*)d_in[0];
    const float* support = (const float*)d_in[1];
    const float* w1 = (const float*)d_in[2];
    const float* w2 = (const float*)d_in[3];
    const float* w3 = (const float*)d_in[4];
    const float* w4 = (const float*)d_in[5];
    const float* s1 = (const float*)d_in[6];
    const float* b1 = (const float*)d_in[7];
    const float* s2 = (const float*)d_in[8];
    const float* b2 = (const float*)d_in[9];
    const float* s3 = (const float*)d_in[10];
    const float* b3 = (const float*)d_in[11];
    const float* s4 = (const float*)d_in[12];
    const float* b4 = (const float*)d_in[13];
    float* out = (float*)d_out;

    char* ws = (char*)d_ws;
    unsigned short* A1  = (unsigned short*)(ws);              // 200*1764*64 bf16 = 45,158,400 B
    unsigned short* A2  = (unsigned short*)(ws + 45158400);   // 200*441*64 bf16 = 11,289,600 B
    unsigned short* A3  = (unsigned short*)(ws + 56448000);
    unsigned short* A4  = (unsigned short*)(ws + 67737600);
    unsigned short* QL  = (unsigned short*)(ws + 79027200);   // 150*441*64 bf16 = 8,467,200 B
    unsigned short* SL  = (unsigned short*)(ws + 87495296);   // 10*441*64 bf16 = 564,480 B (896B slack before)
    unsigned short* WP2 = (unsigned short*)(ws + 88059776);   // 36864 bf16 = 73,728 B
    unsigned short* WP3 = (unsigned short*)(ws + 88133504);
    unsigned short* WP4 = (unsigned short*)(ws + 88207232);

    pack_w<<<(3 * 36864 + 255) / 256, 256, 0, stream>>>(w2, w3, w4, WP2, WP3, WP4);
    conv1_pool<<<NIMG * 16, 256, 0, stream>>>(query, support, w1, s1, b1, A1);
    conv2_mfma_pool<<<NIMG * 7, 256, 0, stream>>>(A1, WP2, s2, b2, A2);
    conv_mfma_np<<<NIMG * 7, 128, 0, stream>>>(A2, WP3, s3, b3, A3);
    conv_mfma_np<<<NIMG * 7, 128, 0, stream>>>(A3, WP4, s4, b4, A4);

    q_norm<<<(NQIMG * HW3 + 255) / 256, 256, 0, stream>>>(A4, QL);
    s_mean_norm<<<(BDIM * WAY * HW3 + 255) / 256, 256, 0, stream>>>(A4, SL);

    sim_mfma<<<NQIMG * WAY, 256, 0, stream>>>(QL, SL, out);
}

// Round 6
// 227.578 us; speedup vs baseline: 24.8131x; 1.4495x over previous
//
#include <hip/hip_runtime.h>

#define EPS 1e-12f

// Problem constants
#define NIMG   200      // 150 query + 50 support
#define NQIMG  150
#define BDIM   2
#define NQ     75
#define WAY    5
#define SHOT   5
#define DCH    64
#define H1     84
#define H2     42
#define H3     21
#define HW2    1764     // 42*42
#define HW3    441      // 21*21
#define PH     86       // padded 84+2
#define PSZ    7396     // 86*86

typedef __attribute__((ext_vector_type(8))) short bf16x8;
typedef __attribute__((ext_vector_type(4))) float f32x4;

__device__ __forceinline__ unsigned short f2bf(float f) {
    unsigned u = __float_as_uint(f);
    u += 0x7fffu + ((u >> 16) & 1u);
    return (unsigned short)(u >> 16);
}
__device__ __forceinline__ float bf2f(unsigned short h) {
    return __uint_as_float(((unsigned)h) << 16);
}

// ---------------- input zero-pad: f32 NCHW 84x84 -> bf16 [img][3][86][86] ----------------
__global__ __launch_bounds__(256) void pad_in(
    const float* __restrict__ qin, const float* __restrict__ sin_,
    unsigned short* __restrict__ pad)
{
    int idx = blockIdx.x * 256 + threadIdx.x;
    if (idx >= NIMG * 3 * PSZ) return;
    int img = idx / (3 * PSZ);
    int rem = idx % (3 * PSZ);
    int ci = rem / PSZ, p = rem % PSZ;
    int iy = p / PH, ix = p % PH;
    float v = 0.f;
    if (iy >= 1 && iy <= H1 && ix >= 1 && ix <= H1) {
        const float* src = (img < NQIMG) ? (qin + (size_t)img * 3 * H1 * H1)
                                         : (sin_ + (size_t)(img - NQIMG) * 3 * H1 * H1);
        v = src[(size_t)ci * H1 * H1 + (iy - 1) * H1 + (ix - 1)];
    }
    pad[idx] = f2bf(v);
}

// ---------------- w1 pack: (64,3,3,3) f32 -> MFMA A-fragments, K=27 pad 32 ----------------
// [mt][lane][j]: co = mt*16+(lane&15), k = (lane>>4)*8+j; k=ci*9+s
__global__ __launch_bounds__(256) void pack_w1(
    const float* __restrict__ w1, unsigned short* __restrict__ p1)
{
    int idx = blockIdx.x * 256 + threadIdx.x;
    if (idx >= 2048) return;
    int j = idx & 7, lane = (idx >> 3) & 63, mt = idx >> 9;
    int co = (mt << 4) + (lane & 15);
    int k = ((lane >> 4) << 3) + j;
    float v = 0.f;
    if (k < 27) {
        int ci = k / 9, s = k % 9;
        v = w1[(co * 3 + ci) * 9 + s];
    }
    p1[idx] = f2bf(v);
}

// ---------------- weight pack: OIHW f32 -> MFMA-fragment-ordered bf16 (w2/w3/w4) ----------------
__global__ __launch_bounds__(256) void pack_w(
    const float* __restrict__ w2, const float* __restrict__ w3,
    const float* __restrict__ w4, unsigned short* __restrict__ p2,
    unsigned short* __restrict__ p3, unsigned short* __restrict__ p4)
{
    int idx = blockIdx.x * 256 + threadIdx.x;
    if (idx >= 3 * 36864) return;
    int which = idx / 36864;
    int r = idx % 36864;
    int j = r & 7, lane = (r >> 3) & 63, mt = (r >> 9) & 3, t = (r >> 11) & 1, s = r >> 12;
    int co = (mt << 4) + (lane & 15);
    int ci = (t << 5) + ((lane >> 4) << 3) + j;
    const float* w = (which == 0) ? w2 : (which == 1) ? w3 : w4;
    unsigned short* p = (which == 0) ? p2 : (which == 1) ? p3 : p4;
    p[r] = f2bf(w[(co * 64 + ci) * 9 + s]);
}

// ---------------- conv1: 3->64 MFMA (im2col K=27->32), BN, ReLU, maxpool; out NHWC bf16 ----------------
// grid: 200*8, block 256 (4 waves). Per wave-iter: 16 conv px = 4 pooled px,
// all 64 co via 4 MFMAs; pool via shfl_xor within 4-lane sub groups.
__global__ __launch_bounds__(256) void conv1_mfma(
    const unsigned short* __restrict__ pad,   // [img][3][86][86] bf16
    const unsigned short* __restrict__ wp1,   // packed A fragments
    const float* __restrict__ scale, const float* __restrict__ bias,
    unsigned short* __restrict__ out)         // [img][1764][64] bf16
{
    int img = blockIdx.x >> 3;
    int seg = blockIdx.x & 7;
    int tid = threadIdx.x;
    int wv = tid >> 6, lane = tid & 63;
    int lc = lane & 15, kg = lane >> 4;

    const bf16x8* wvv = (const bf16x8*)wp1;
    bf16x8 a0 = wvv[lane];
    bf16x8 a1 = wvv[64 + lane];
    bf16x8 a2 = wvv[128 + lane];
    bf16x8 a3 = wvv[192 + lane];

    // per-lane im2col offsets (constant over the loop)
    int off[8];
    bool kval[8];
    #pragma unroll
    for (int j = 0; j < 8; j++) {
        int k = (kg << 3) + j;
        kval[j] = k < 27;
        int kk = kval[j] ? k : 0;
        int ci = kk / 9, s = kk % 9;
        off[j] = ci * PSZ + (s / 3) * PH + (s % 3);
    }

    float4 sc4[4], bi4[4];
    #pragma unroll
    for (int mt = 0; mt < 4; mt++) {
        sc4[mt] = *reinterpret_cast<const float4*>(scale + (mt << 4) + (kg << 2));
        bi4[mt] = *reinterpret_cast<const float4*>(bias + (mt << 4) + (kg << 2));
    }

    const unsigned short* bimg = pad + (size_t)img * 3 * PSZ;
    int sub = lc & 3;
    int sy = sub >> 1, sx = sub & 1;

    for (int ppb = seg * 16; ppb < HW2; ppb += 128) {
        int pp = ppb + wv * 4 + (lc >> 2);
        int pc = pp < HW2 ? pp : HW2 - 1;
        int py = pc / H2, px = pc % H2;
        int y = 2 * py + sy, x = 2 * px + sx;   // conv coords; padded patch starts (y,x)
        int base = y * PH + x;

        bf16x8 bb;
        #pragma unroll
        for (int j = 0; j < 8; j++) {
            unsigned short v = bimg[base + off[j]];
            bb[j] = kval[j] ? (short)v : (short)0;
        }

        f32x4 acc0 = (f32x4){0.f, 0.f, 0.f, 0.f};
        f32x4 acc1 = acc0, acc2 = acc0, acc3 = acc0;
        acc0 = __builtin_amdgcn_mfma_f32_16x16x32_bf16(a0, bb, acc0, 0, 0, 0);
        acc1 = __builtin_amdgcn_mfma_f32_16x16x32_bf16(a1, bb, acc1, 0, 0, 0);
        acc2 = __builtin_amdgcn_mfma_f32_16x16x32_bf16(a2, bb, acc2, 0, 0, 0);
        acc3 = __builtin_amdgcn_mfma_f32_16x16x32_bf16(a3, bb, acc3, 0, 0, 0);

        // BN -> pool (max over 4 sub lanes) -> ReLU -> write
        bool wr = ((lc & 3) == 0) && (pp < HW2);
        #pragma unroll
        for (int mt = 0; mt < 4; mt++) {
            f32x4 acc = (mt == 0) ? acc0 : (mt == 1) ? acc1 : (mt == 2) ? acc2 : acc3;
            unsigned short uo[4];
            #pragma unroll
            for (int r = 0; r < 4; r++) {
                float v = acc[r] * (&sc4[mt].x)[r] + (&bi4[mt].x)[r];
                v = fmaxf(v, __shfl_xor(v, 1, 64));
                v = fmaxf(v, __shfl_xor(v, 2, 64));
                uo[r] = f2bf(fmaxf(v, 0.f));
            }
            if (wr) {
                uint2 pk;
                pk.x = (unsigned)uo[0] | ((unsigned)uo[1] << 16);
                pk.y = (unsigned)uo[2] | ((unsigned)uo[3] << 16);
                *reinterpret_cast<uint2*>(out + ((size_t)img * HW2 + pp) * DCH + (mt << 4) + (kg << 2)) = pk;
            }
        }
    }
}

// ---------------- conv2: 64->64 MFMA, BN, ReLU, maxpool; NHWC bf16 in/out ----------------
__global__ __launch_bounds__(256) void conv2_mfma_pool(
    const unsigned short* __restrict__ act,   // [img][1764][64]
    const unsigned short* __restrict__ wp,    // packed fragments
    const float* __restrict__ scale, const float* __restrict__ bias,
    unsigned short* __restrict__ out)         // [img][441][64]
{
    int img = blockIdx.x / 7, tg = blockIdx.x % 7;
    int wv = threadIdx.x >> 6, lane = threadIdx.x & 63;
    int lc = lane & 15, kgrp = lane >> 4;
    int p = (tg * 4 + wv) * 16 + lc;
    bool valid = p < HW3;
    int pc = valid ? p : HW3 - 1;
    int oy = pc / H3, ox = pc % H3;
    const unsigned short* ab = act + (size_t)img * HW2 * DCH;
    const bf16x8* wvv = (const bf16x8*)wp;

    f32x4 acc[4][4];
    #pragma unroll
    for (int i = 0; i < 4; i++)
        #pragma unroll
        for (int j = 0; j < 4; j++)
            acc[i][j] = (f32x4){0.f, 0.f, 0.f, 0.f};

    for (int s = 0; s < 9; s++) {
        int ky = s / 3 - 1, kx = s % 3 - 1;
        #pragma unroll
        for (int t = 0; t < 2; t++) {
            int fbase = ((s * 2 + t) * 4) << 6;
            bf16x8 a0 = wvv[fbase + lane];
            bf16x8 a1 = wvv[fbase + 64 + lane];
            bf16x8 a2 = wvv[fbase + 128 + lane];
            bf16x8 a3 = wvv[fbase + 192 + lane];
            bf16x8 b[4];
            #pragma unroll
            for (int sub = 0; sub < 4; sub++) {
                int y = 2 * oy + (sub >> 1) + ky;
                int x = 2 * ox + (sub & 1) + kx;
                bf16x8 bb = (bf16x8)(short)0;
                if ((unsigned)y < (unsigned)H2 && (unsigned)x < (unsigned)H2)
                    bb = *(const bf16x8*)(ab + (((size_t)(y * H2 + x)) << 6) + (t << 5) + (kgrp << 3));
                b[sub] = bb;
            }
            #pragma unroll
            for (int sub = 0; sub < 4; sub++) {
                acc[0][sub] = __builtin_amdgcn_mfma_f32_16x16x32_bf16(a0, b[sub], acc[0][sub], 0, 0, 0);
                acc[1][sub] = __builtin_amdgcn_mfma_f32_16x16x32_bf16(a1, b[sub], acc[1][sub], 0, 0, 0);
                acc[2][sub] = __builtin_amdgcn_mfma_f32_16x16x32_bf16(a2, b[sub], acc[2][sub], 0, 0, 0);
                acc[3][sub] = __builtin_amdgcn_mfma_f32_16x16x32_bf16(a3, b[sub], acc[3][sub], 0, 0, 0);
            }
        }
    }

    if (!valid) return;
    #pragma unroll
    for (int mt = 0; mt < 4; mt++) {
        int co0 = (mt << 4) + (kgrp << 2);
        float4 sc = *reinterpret_cast<const float4*>(scale + co0);
        float4 bi = *reinterpret_cast<const float4*>(bias + co0);
        unsigned short uo[4];
        #pragma unroll
        for (int r = 0; r < 4; r++) {
            float scr = (&sc.x)[r], bir = (&bi.x)[r];
            float v0 = acc[mt][0][r] * scr + bir;
            float v1 = acc[mt][1][r] * scr + bir;
            float v2 = acc[mt][2][r] * scr + bir;
            float v3 = acc[mt][3][r] * scr + bir;
            float m = fmaxf(fmaxf(v0, v1), fmaxf(v2, v3));
            uo[r] = f2bf(fmaxf(m, 0.f));
        }
        uint2 pk;
        pk.x = (unsigned)uo[0] | ((unsigned)uo[1] << 16);
        pk.y = (unsigned)uo[2] | ((unsigned)uo[3] << 16);
        *reinterpret_cast<uint2*>(out + ((size_t)img * HW3 + p) * DCH + co0) = pk;
    }
}

// ---------------- conv3/4: 64->64 MFMA, BN, ReLU, no pool; NHWC bf16 ----------------
__global__ __launch_bounds__(128) void conv_mfma_np(
    const unsigned short* __restrict__ act,   // [img][441][64]
    const unsigned short* __restrict__ wp,
    const float* __restrict__ scale, const float* __restrict__ bias,
    unsigned short* __restrict__ out)         // [img][441][64]
{
    int img = blockIdx.x / 7, tg = blockIdx.x % 7;
    int wv = threadIdx.x >> 6, lane = threadIdx.x & 63;
    int lc = lane & 15, kgrp = lane >> 4;
    int p0 = (tg * 4 + wv * 2) * 16 + lc;
    int p1 = p0 + 16;
    bool v0 = p0 < HW3, v1 = p1 < HW3;
    int pc0 = v0 ? p0 : HW3 - 1, pc1 = v1 ? p1 : HW3 - 1;
    int oy0 = pc0 / H3, ox0 = pc0 % H3;
    int oy1 = pc1 / H3, ox1 = pc1 % H3;
    const unsigned short* ab = act + (size_t)img * HW3 * DCH;
    const bf16x8* wvv = (const bf16x8*)wp;

    f32x4 acc[4][2];
    #pragma unroll
    for (int i = 0; i < 4; i++) {
        acc[i][0] = (f32x4){0.f, 0.f, 0.f, 0.f};
        acc[i][1] = (f32x4){0.f, 0.f, 0.f, 0.f};
    }

    for (int s = 0; s < 9; s++) {
        int ky = s / 3 - 1, kx = s % 3 - 1;
        #pragma unroll
        for (int t = 0; t < 2; t++) {
            int fbase = ((s * 2 + t) * 4) << 6;
            bf16x8 a0 = wvv[fbase + lane];
            bf16x8 a1 = wvv[fbase + 64 + lane];
            bf16x8 a2 = wvv[fbase + 128 + lane];
            bf16x8 a3 = wvv[fbase + 192 + lane];
            int y0 = oy0 + ky, x0 = ox0 + kx;
            int y1 = oy1 + ky, x1 = ox1 + kx;
            bf16x8 b0 = (bf16x8)(short)0, b1 = (bf16x8)(short)0;
            if ((unsigned)y0 < (unsigned)H3 && (unsigned)x0 < (unsigned)H3)
                b0 = *(const bf16x8*)(ab + (((size_t)(y0 * H3 + x0)) << 6) + (t << 5) + (kgrp << 3));
            if ((unsigned)y1 < (unsigned)H3 && (unsigned)x1 < (unsigned)H3)
                b1 = *(const bf16x8*)(ab + (((size_t)(y1 * H3 + x1)) << 6) + (t << 5) + (kgrp << 3));
            acc[0][0] = __builtin_amdgcn_mfma_f32_16x16x32_bf16(a0, b0, acc[0][0], 0, 0, 0);
            acc[1][0] = __builtin_amdgcn_mfma_f32_16x16x32_bf16(a1, b0, acc[1][0], 0, 0, 0);
            acc[2][0] = __builtin_amdgcn_mfma_f32_16x16x32_bf16(a2, b0, acc[2][0], 0, 0, 0);
            acc[3][0] = __builtin_amdgcn_mfma_f32_16x16x32_bf16(a3, b0, acc[3][0], 0, 0, 0);
            acc[0][1] = __builtin_amdgcn_mfma_f32_16x16x32_bf16(a0, b1, acc[0][1], 0, 0, 0);
            acc[1][1] = __builtin_amdgcn_mfma_f32_16x16x32_bf16(a1, b1, acc[1][1], 0, 0, 0);
            acc[2][1] = __builtin_amdgcn_mfma_f32_16x16x32_bf16(a2, b1, acc[2][1], 0, 0, 0);
            acc[3][1] = __builtin_amdgcn_mfma_f32_16x16x32_bf16(a3, b1, acc[3][1], 0, 0, 0);
        }
    }

    #pragma unroll
    for (int mt = 0; mt < 4; mt++) {
        int co0 = (mt << 4) + (kgrp << 2);
        float4 sc = *reinterpret_cast<const float4*>(scale + co0);
        float4 bi = *reinterpret_cast<const float4*>(bias + co0);
        #pragma unroll
        for (int nt = 0; nt < 2; nt++) {
            bool vld = nt == 0 ? v0 : v1;
            if (!vld) continue;
            int pp = nt == 0 ? p0 : p1;
            unsigned short uo[4];
            #pragma unroll
            for (int r = 0; r < 4; r++) {
                float v = acc[mt][nt][r] * (&sc.x)[r] + (&bi.x)[r];
                uo[r] = f2bf(fmaxf(v, 0.f));
            }
            uint2 pk;
            pk.x = (unsigned)uo[0] | ((unsigned)uo[1] << 16);
            pk.y = (unsigned)uo[2] | ((unsigned)uo[3] << 16);
            *reinterpret_cast<uint2*>(out + ((size_t)img * HW3 + pp) * DCH + co0) = pk;
        }
    }
}

// ---------------- query L2-normalize: NHWC bf16 -> [img][hw][64] bf16 ----------------
__global__ __launch_bounds__(256) void q_norm(
    const unsigned short* __restrict__ feat, unsigned short* __restrict__ q_local)
{
    int idx = blockIdx.x * 256 + threadIdx.x;
    if (idx >= NQIMG * HW3) return;
    const bf16x8* f = (const bf16x8*)(feat + (size_t)idx * DCH);
    float v[DCH];
    float ss = 0.f;
    #pragma unroll
    for (int g = 0; g < 8; g++) {
        bf16x8 x = f[g];
        #pragma unroll
        for (int j = 0; j < 8; j++) {
            float vv = bf2f((unsigned short)x[j]);
            v[g * 8 + j] = vv;
            ss = fmaf(vv, vv, ss);
        }
    }
    float inv = 1.f / fmaxf(sqrtf(ss), EPS);
    bf16x8* o = (bf16x8*)(q_local + (size_t)idx * DCH);
    #pragma unroll
    for (int g = 0; g < 8; g++) {
        bf16x8 pk;
        #pragma unroll
        for (int j = 0; j < 8; j++) pk[j] = (short)f2bf(v[g * 8 + j] * inv);
        o[g] = pk;
    }
}

// ---------------- support: mean over shots + L2-normalize -> [bc][hw][64] bf16 ----------------
__global__ __launch_bounds__(256) void s_mean_norm(
    const unsigned short* __restrict__ feat, unsigned short* __restrict__ s_local)
{
    int idx = blockIdx.x * 256 + threadIdx.x;
    if (idx >= BDIM * WAY * HW3) return;
    int hw = idx % HW3;
    int bc = idx / HW3;
    int img0 = NQIMG + bc * SHOT;
    float v[DCH];
    #pragma unroll
    for (int d = 0; d < DCH; d++) v[d] = 0.f;
    for (int sh = 0; sh < SHOT; sh++) {
        const bf16x8* f = (const bf16x8*)(feat + ((size_t)(img0 + sh) * HW3 + hw) * DCH);
        #pragma unroll
        for (int g = 0; g < 8; g++) {
            bf16x8 x = f[g];
            #pragma unroll
            for (int j = 0; j < 8; j++)
                v[g * 8 + j] += bf2f((unsigned short)x[j]);
        }
    }
    float ss = 0.f;
    #pragma unroll
    for (int d = 0; d < DCH; d++) {
        v[d] *= (1.f / SHOT);
        ss = fmaf(v[d], v[d], ss);
    }
    float inv = 1.f / fmaxf(sqrtf(ss), EPS);
    bf16x8* o = (bf16x8*)(s_local + (size_t)idx * DCH);
    #pragma unroll
    for (int g = 0; g < 8; g++) {
        bf16x8 pk;
        #pragma unroll
        for (int j = 0; j < 8; j++) pk[j] = (short)f2bf(v[g * 8 + j] * inv);
        o[g] = pk;
    }
}

// ---------------- similarity via MFMA ----------------
#define SLDW 72
__global__ __launch_bounds__(256) void sim_mfma(
    const unsigned short* __restrict__ qloc,  // [150][441][64] bf16
    const unsigned short* __restrict__ sloc,  // [10][441][64] bf16
    float* __restrict__ out)
{
    int blk = blockIdx.x;
    int imgq = blk / WAY, way = blk % WAY;
    int b = imgq / NQ;
    const unsigned short* qp = qloc + (size_t)imgq * HW3 * DCH;
    const unsigned short* sp = sloc + (size_t)(b * WAY + way) * HW3 * DCH;

    __shared__ unsigned short slds[448 * SLDW];
    int tid = threadIdx.x;
    for (int i = tid; i < 448 * 8; i += 256) {
        int row = i >> 3, ch = (i & 7) << 3;
        bf16x8 v = (bf16x8)(short)0;
        if (row < HW3) v = *(const bf16x8*)(sp + (size_t)row * DCH + ch);
        *(bf16x8*)(&slds[row * SLDW + ch]) = v;
    }
    __syncthreads();

    int wv = tid >> 6, lane = tid & 63;
    int lc = lane & 15, kg = lane >> 4;
    int mt0 = wv * 7;

    bf16x8 qa0[7], qa1[7];
    #pragma unroll
    for (int i = 0; i < 7; i++) {
        const unsigned short* qrow = qp + (size_t)((mt0 + i) * 16 + lc) * DCH + (kg << 3);
        qa0[i] = *(const bf16x8*)(qrow);
        qa1[i] = *(const bf16x8*)(qrow + 32);
    }
    f32x4 rmax[7];
    #pragma unroll
    for (int i = 0; i < 7; i++)
        rmax[i] = (f32x4){-1e30f, -1e30f, -1e30f, -1e30f};

    for (int nt = 0; nt < 27; nt++) {
        const unsigned short* srow = &slds[(nt * 16 + lc) * SLDW + (kg << 3)];
        bf16x8 sb0 = *(const bf16x8*)(srow);
        bf16x8 sb1 = *(const bf16x8*)(srow + 32);
        #pragma unroll
        for (int i = 0; i < 7; i++) {
            f32x4 acc = (f32x4){0.f, 0.f, 0.f, 0.f};
            acc = __builtin_amdgcn_mfma_f32_16x16x32_bf16(qa0[i], sb0, acc, 0, 0, 0);
            acc = __builtin_amdgcn_mfma_f32_16x16x32_bf16(qa1[i], sb1, acc, 0, 0, 0);
            rmax[i][0] = fmaxf(rmax[i][0], acc[0]);
            rmax[i][1] = fmaxf(rmax[i][1], acc[1]);
            rmax[i][2] = fmaxf(rmax[i][2], acc[2]);
            rmax[i][3] = fmaxf(rmax[i][3], acc[3]);
        }
    }
    {   // last n-tile (cols 432..447): mask invalid cols
        const unsigned short* srow = &slds[(432 + lc) * SLDW + (kg << 3)];
        bf16x8 sb0 = *(const bf16x8*)(srow);
        bf16x8 sb1 = *(const bf16x8*)(srow + 32);
        bool nval = (432 + lc) < HW3;
        #pragma unroll
        for (int i = 0; i < 7; i++) {
            f32x4 acc = (f32x4){0.f, 0.f, 0.f, 0.f};
            acc = __builtin_amdgcn_mfma_f32_16x16x32_bf16(qa0[i], sb0, acc, 0, 0, 0);
            acc = __builtin_amdgcn_mfma_f32_16x16x32_bf16(qa1[i], sb1, acc, 0, 0, 0);
            #pragma unroll
            for (int r = 0; r < 4; r++)
                rmax[i][r] = fmaxf(rmax[i][r], nval ? acc[r] : -1e30f);
        }
    }

    float msum = 0.f;
    #pragma unroll
    for (int i = 0; i < 7; i++) {
        #pragma unroll
        for (int r = 0; r < 4; r++) {
            float v = rmax[i][r];
            v = fmaxf(v, __shfl_xor(v, 1, 64));
            v = fmaxf(v, __shfl_xor(v, 2, 64));
            v = fmaxf(v, __shfl_xor(v, 4, 64));
            v = fmaxf(v, __shfl_xor(v, 8, 64));
            int m = (mt0 + i) * 16 + (kg << 2) + r;
            if (lc == 0 && m < HW3) msum += v;
        }
    }
    #pragma unroll
    for (int off = 32; off > 0; off >>= 1)
        msum += __shfl_xor(msum, off, 64);
    __shared__ float red[4];
    if (lane == 0) red[wv] = msum;
    __syncthreads();
    if (tid == 0)
        out[(size_t)imgq * WAY + way] = (red[0] + red[1] + red[2] + red[3]) * (1.f / HW3);
}

extern "C" void kernel_launch(void* const* d_in, const int* in_sizes, int n_in,
                              void* d_out, int out_size, void* d_ws, size_t ws_size,
                              hipStream_t stream) {
    const float* query   = (const float*)d_in[0];
    const float* support = (const float*)d_in[1];
    const float* w1 = (const float*)d_in[2];
    const float* w2 = (const float*)d_in[3];
    const float* w3 = (const float*)d_in[4];
    const float* w4 = (const float*)d_in[5];
    const float* s1 = (const float*)d_in[6];
    const float* b1 = (const float*)d_in[7];
    const float* s2 = (const float*)d_in[8];
    const float* b2 = (const float*)d_in[9];
    const float* s3 = (const float*)d_in[10];
    const float* b3 = (const float*)d_in[11];
    const float* s4 = (const float*)d_in[12];
    const float* b4 = (const float*)d_in[13];
    float* out = (float*)d_out;

    char* ws = (char*)d_ws;
    unsigned short* A1  = (unsigned short*)(ws);              // 200*1764*64 bf16 = 45,158,400 B
    unsigned short* A2  = (unsigned short*)(ws + 45158400);   // 200*441*64 bf16 = 11,289,600 B
    unsigned short* A3  = (unsigned short*)(ws + 56448000);
    unsigned short* A4  = (unsigned short*)(ws + 67737600);
    unsigned short* QL  = (unsigned short*)(ws + 79027200);   // 150*441*64 bf16 = 8,467,200 B
    unsigned short* SL  = (unsigned short*)(ws + 87495296);   // 10*441*64 bf16 = 564,480 B
    unsigned short* WP2 = (unsigned short*)(ws + 88059776);   // 36864 bf16 = 73,728 B
    unsigned short* WP3 = (unsigned short*)(ws + 88133504);
    unsigned short* WP4 = (unsigned short*)(ws + 88207232);
    unsigned short* WP1 = (unsigned short*)(ws + 88280960);   // 2048 bf16 = 4,096 B
    unsigned short* PAD = (unsigned short*)(ws + 88285056);   // 200*3*7396 bf16 = 8,875,200 B

    pad_in<<<(NIMG * 3 * PSZ + 255) / 256, 256, 0, stream>>>(query, support, PAD);
    pack_w1<<<8, 256, 0, stream>>>(w1, WP1);
    pack_w<<<(3 * 36864 + 255) / 256, 256, 0, stream>>>(w2, w3, w4, WP2, WP3, WP4);

    conv1_mfma<<<NIMG * 8, 256, 0, stream>>>(PAD, WP1, s1, b1, A1);
    conv2_mfma_pool<<<NIMG * 7, 256, 0, stream>>>(A1, WP2, s2, b2, A2);
    conv_mfma_np<<<NIMG * 7, 128, 0, stream>>>(A2, WP3, s3, b3, A3);
    conv_mfma_np<<<NIMG * 7, 128, 0, stream>>>(A3, WP4, s4, b4, A4);

    q_norm<<<(NQIMG * HW3 + 255) / 256, 256, 0, stream>>>(A4, QL);
    s_mean_norm<<<(BDIM * WAY * HW3 + 255) / 256, 256, 0, stream>>>(A4, SL);

    sim_mfma<<<NQIMG * WAY, 256, 0, stream>>>(QL, SL, out);
}

// Round 7
// 185.930 us; speedup vs baseline: 30.3712x; 1.2240x over previous
//
#include <hip/hip_runtime.h>

#define EPS 1e-12f

// Problem constants
#define NIMG   200      // 150 query + 50 support
#define NQIMG  150
#define BDIM   2
#define NQ     75
#define WAY    5
#define SHOT   5
#define DCH    64
#define H1     84
#define H2     42
#define H3     21
#define HW2    1764     // 42*42
#define HW3    441      // 21*21
#define PH     86       // padded 84+2
#define PSZ    7396     // 86*86

typedef __attribute__((ext_vector_type(8))) short bf16x8;
typedef __attribute__((ext_vector_type(4))) float f32x4;

__device__ __forceinline__ unsigned short f2bf(float f) {
    unsigned u = __float_as_uint(f);
    u += 0x7fffu + ((u >> 16) & 1u);
    return (unsigned short)(u >> 16);
}
__device__ __forceinline__ float bf2f(unsigned short h) {
    return __uint_as_float(((unsigned)h) << 16);
}
// LDS pixel-line swizzle: 128B line per pixel, 8 x 16B chunks; chunk ^= (pix>>1)&7
// (<=2-way bank alias for both stride-1 and stride-2 pixel reads)
__device__ __forceinline__ int swz(int pix, int c) {
    return pix * 128 + ((c ^ ((pix >> 1) & 7)) << 4);
}

// ---------------- input zero-pad: f32 NCHW 84x84 -> bf16 [img][3][86][86] ----------------
__global__ __launch_bounds__(256) void pad_in(
    const float* __restrict__ qin, const float* __restrict__ sin_,
    unsigned short* __restrict__ pad)
{
    int idx = blockIdx.x * 256 + threadIdx.x;
    if (idx >= NIMG * 3 * PSZ) return;
    int img = idx / (3 * PSZ);
    int rem = idx % (3 * PSZ);
    int ci = rem / PSZ, p = rem % PSZ;
    int iy = p / PH, ix = p % PH;
    float v = 0.f;
    if (iy >= 1 && iy <= H1 && ix >= 1 && ix <= H1) {
        const float* src = (img < NQIMG) ? (qin + (size_t)img * 3 * H1 * H1)
                                         : (sin_ + (size_t)(img - NQIMG) * 3 * H1 * H1);
        v = src[(size_t)ci * H1 * H1 + (iy - 1) * H1 + (ix - 1)];
    }
    pad[idx] = f2bf(v);
}

// ---------------- w1 pack: (64,3,3,3) f32 -> MFMA A-fragments, K=27 pad 32 ----------------
__global__ __launch_bounds__(256) void pack_w1(
    const float* __restrict__ w1, unsigned short* __restrict__ p1)
{
    int idx = blockIdx.x * 256 + threadIdx.x;
    if (idx >= 2048) return;
    int j = idx & 7, lane = (idx >> 3) & 63, mt = idx >> 9;
    int co = (mt << 4) + (lane & 15);
    int k = ((lane >> 4) << 3) + j;
    float v = 0.f;
    if (k < 27) {
        int ci = k / 9, s = k % 9;
        v = w1[(co * 3 + ci) * 9 + s];
    }
    p1[idx] = f2bf(v);
}

// ---------------- weight pack: OIHW f32 -> MFMA-fragment-ordered bf16 (w2/w3/w4) ----------------
__global__ __launch_bounds__(256) void pack_w(
    const float* __restrict__ w2, const float* __restrict__ w3,
    const float* __restrict__ w4, unsigned short* __restrict__ p2,
    unsigned short* __restrict__ p3, unsigned short* __restrict__ p4)
{
    int idx = blockIdx.x * 256 + threadIdx.x;
    if (idx >= 3 * 36864) return;
    int which = idx / 36864;
    int r = idx % 36864;
    int j = r & 7, lane = (r >> 3) & 63, mt = (r >> 9) & 3, t = (r >> 11) & 1, s = r >> 12;
    int co = (mt << 4) + (lane & 15);
    int ci = (t << 5) + ((lane >> 4) << 3) + j;
    const float* w = (which == 0) ? w2 : (which == 1) ? w3 : w4;
    unsigned short* p = (which == 0) ? p2 : (which == 1) ? p3 : p4;
    p[r] = f2bf(w[(co * 64 + ci) * 9 + s]);
}

// ---------------- conv1: 3->64 MFMA (im2col K=27->32), BN, ReLU, maxpool ----------------
__global__ __launch_bounds__(256) void conv1_mfma(
    const unsigned short* __restrict__ pad,   // [img][3][86][86] bf16
    const unsigned short* __restrict__ wp1,   // packed A fragments
    const float* __restrict__ scale, const float* __restrict__ bias,
    unsigned short* __restrict__ out)         // [img][1764][64] bf16
{
    int img = blockIdx.x >> 3;
    int seg = blockIdx.x & 7;
    int tid = threadIdx.x;
    int wv = tid >> 6, lane = tid & 63;
    int lc = lane & 15, kg = lane >> 4;

    const bf16x8* wvv = (const bf16x8*)wp1;
    bf16x8 a0 = wvv[lane];
    bf16x8 a1 = wvv[64 + lane];
    bf16x8 a2 = wvv[128 + lane];
    bf16x8 a3 = wvv[192 + lane];

    int off[8];
    bool kval[8];
    #pragma unroll
    for (int j = 0; j < 8; j++) {
        int k = (kg << 3) + j;
        kval[j] = k < 27;
        int kk = kval[j] ? k : 0;
        int ci = kk / 9, s = kk % 9;
        off[j] = ci * PSZ + (s / 3) * PH + (s % 3);
    }

    float4 sc4[4], bi4[4];
    #pragma unroll
    for (int mt = 0; mt < 4; mt++) {
        sc4[mt] = *reinterpret_cast<const float4*>(scale + (mt << 4) + (kg << 2));
        bi4[mt] = *reinterpret_cast<const float4*>(bias + (mt << 4) + (kg << 2));
    }

    const unsigned short* bimg = pad + (size_t)img * 3 * PSZ;
    int sub = lc & 3;
    int sy = sub >> 1, sx = sub & 1;

    for (int ppb = seg * 16; ppb < HW2; ppb += 128) {
        int pp = ppb + wv * 4 + (lc >> 2);
        int pc = pp < HW2 ? pp : HW2 - 1;
        int py = pc / H2, px = pc % H2;
        int y = 2 * py + sy, x = 2 * px + sx;
        int base = y * PH + x;

        bf16x8 bb;
        #pragma unroll
        for (int j = 0; j < 8; j++) {
            unsigned short v = bimg[base + off[j]];
            bb[j] = kval[j] ? (short)v : (short)0;
        }

        f32x4 acc0 = (f32x4){0.f, 0.f, 0.f, 0.f};
        f32x4 acc1 = acc0, acc2 = acc0, acc3 = acc0;
        acc0 = __builtin_amdgcn_mfma_f32_16x16x32_bf16(a0, bb, acc0, 0, 0, 0);
        acc1 = __builtin_amdgcn_mfma_f32_16x16x32_bf16(a1, bb, acc1, 0, 0, 0);
        acc2 = __builtin_amdgcn_mfma_f32_16x16x32_bf16(a2, bb, acc2, 0, 0, 0);
        acc3 = __builtin_amdgcn_mfma_f32_16x16x32_bf16(a3, bb, acc3, 0, 0, 0);

        bool wr = ((lc & 3) == 0) && (pp < HW2);
        #pragma unroll
        for (int mt = 0; mt < 4; mt++) {
            f32x4 acc = (mt == 0) ? acc0 : (mt == 1) ? acc1 : (mt == 2) ? acc2 : acc3;
            unsigned short uo[4];
            #pragma unroll
            for (int r = 0; r < 4; r++) {
                float v = acc[r] * (&sc4[mt].x)[r] + (&bi4[mt].x)[r];
                v = fmaxf(v, __shfl_xor(v, 1, 64));
                v = fmaxf(v, __shfl_xor(v, 2, 64));
                uo[r] = f2bf(fmaxf(v, 0.f));
            }
            if (wr) {
                uint2 pk;
                pk.x = (unsigned)uo[0] | ((unsigned)uo[1] << 16);
                pk.y = (unsigned)uo[2] | ((unsigned)uo[3] << 16);
                *reinterpret_cast<uint2*>(out + ((size_t)img * HW2 + pp) * DCH + (mt << 4) + (kg << 2)) = pk;
            }
        }
    }
}

// ---------------- conv2: 64->64 MFMA + LDS strip staging, BN, ReLU, maxpool ----------------
// grid NIMG*7 (strips of 3 pooled rows), block 256. LDS: 8 rows x 44 px x 128B (swizzled).
__global__ __launch_bounds__(256) void conv2_mfma_pool(
    const unsigned short* __restrict__ act,   // [img][1764][64]
    const unsigned short* __restrict__ wp,    // packed fragments
    const float* __restrict__ scale, const float* __restrict__ bias,
    unsigned short* __restrict__ out)         // [img][441][64]
{
    int img = blockIdx.x / 7, tg = blockIdx.x % 7;
    int tid = threadIdx.x;
    __shared__ unsigned short lds[8 * 44 * DCH];   // 45,056 B

    // stage input rows [6*tg-1 .. 6*tg+6], x in [-1..42], zeros outside
    const unsigned short* ab = act + (size_t)img * HW2 * DCH;
    int ybase = 6 * tg - 1;
    #pragma unroll
    for (int it = 0; it < 11; it++) {
        int idx = it * 256 + tid;          // 0..2815
        int pix = idx >> 3, c = idx & 7;
        int r = pix / 44, xx = pix % 44;
        int y = ybase + r, x = xx - 1;
        bf16x8 v = (bf16x8)(short)0;
        if ((unsigned)y < (unsigned)H2 && (unsigned)x < (unsigned)H2)
            v = *(const bf16x8*)(ab + ((size_t)(y * H2 + x)) * DCH + (c << 3));
        *(bf16x8*)((char*)lds + swz(pix, c)) = v;
    }
    __syncthreads();

    int wv = tid >> 6, lane = tid & 63;
    int lc = lane & 15, kg = lane >> 4;
    int p_local = wv * 16 + lc;            // 0..63, 63 valid
    bool valid = p_local < 63;
    int pl = valid ? p_local : 62;
    int pyl = pl / 21, pxl = pl % 21;
    int pixc[4];
    #pragma unroll
    for (int sub = 0; sub < 4; sub++)
        pixc[sub] = (2 * pyl + (sub >> 1) + 1) * 44 + (2 * pxl + (sub & 1) + 1);

    const bf16x8* wvv = (const bf16x8*)wp;
    f32x4 acc[4][4];
    #pragma unroll
    for (int i = 0; i < 4; i++)
        #pragma unroll
        for (int j = 0; j < 4; j++)
            acc[i][j] = (f32x4){0.f, 0.f, 0.f, 0.f};

    for (int s = 0; s < 9; s++) {
        int offs = (s / 3 - 1) * 44 + (s % 3 - 1);
        #pragma unroll
        for (int t = 0; t < 2; t++) {
            int fbase = ((s * 2 + t) * 4) << 6;
            bf16x8 a0 = wvv[fbase + lane];
            bf16x8 a1 = wvv[fbase + 64 + lane];
            bf16x8 a2 = wvv[fbase + 128 + lane];
            bf16x8 a3 = wvv[fbase + 192 + lane];
            int c = (t << 2) + kg;
            bf16x8 b[4];
            #pragma unroll
            for (int sub = 0; sub < 4; sub++) {
                int pix = pixc[sub] + offs;
                b[sub] = *(const bf16x8*)((const char*)lds + swz(pix, c));
            }
            #pragma unroll
            for (int sub = 0; sub < 4; sub++) {
                acc[0][sub] = __builtin_amdgcn_mfma_f32_16x16x32_bf16(a0, b[sub], acc[0][sub], 0, 0, 0);
                acc[1][sub] = __builtin_amdgcn_mfma_f32_16x16x32_bf16(a1, b[sub], acc[1][sub], 0, 0, 0);
                acc[2][sub] = __builtin_amdgcn_mfma_f32_16x16x32_bf16(a2, b[sub], acc[2][sub], 0, 0, 0);
                acc[3][sub] = __builtin_amdgcn_mfma_f32_16x16x32_bf16(a3, b[sub], acc[3][sub], 0, 0, 0);
            }
        }
    }

    if (!valid) return;
    int p = tg * 63 + p_local;
    #pragma unroll
    for (int mt = 0; mt < 4; mt++) {
        int co0 = (mt << 4) + (kg << 2);
        float4 sc = *reinterpret_cast<const float4*>(scale + co0);
        float4 bi = *reinterpret_cast<const float4*>(bias + co0);
        unsigned short uo[4];
        #pragma unroll
        for (int r = 0; r < 4; r++) {
            float scr = (&sc.x)[r], bir = (&bi.x)[r];
            float v0 = acc[mt][0][r] * scr + bir;
            float v1 = acc[mt][1][r] * scr + bir;
            float v2 = acc[mt][2][r] * scr + bir;
            float v3 = acc[mt][3][r] * scr + bir;
            float m = fmaxf(fmaxf(v0, v1), fmaxf(v2, v3));
            uo[r] = f2bf(fmaxf(m, 0.f));
        }
        uint2 pk;
        pk.x = (unsigned)uo[0] | ((unsigned)uo[1] << 16);
        pk.y = (unsigned)uo[2] | ((unsigned)uo[3] << 16);
        *reinterpret_cast<uint2*>(out + ((size_t)img * HW3 + p) * DCH + co0) = pk;
    }
}

// ---------------- conv3/4: 64->64 MFMA, whole image in LDS, BN, ReLU ----------------
// grid NIMG, block 256 (4 waves x 7 n-tiles). LDS: 23x23 px x 128B (swizzled) = 67.7 KB.
__global__ __launch_bounds__(256) void conv34_mfma(
    const unsigned short* __restrict__ act,   // [img][441][64]
    const unsigned short* __restrict__ wp,
    const float* __restrict__ scale, const float* __restrict__ bias,
    unsigned short* __restrict__ out)         // [img][441][64]
{
    int img = blockIdx.x;
    int tid = threadIdx.x;
    __shared__ unsigned short lds[529 * DCH];   // 67,712 B

    const unsigned short* ab = act + (size_t)img * HW3 * DCH;
    #pragma unroll
    for (int it = 0; it < 17; it++) {
        int idx = it * 256 + tid;
        if (idx < 529 * 8) {
            int pix = idx >> 3, c = idx & 7;
            int r = pix / 23, xx = pix % 23;
            int y = r - 1, x = xx - 1;
            bf16x8 v = (bf16x8)(short)0;
            if ((unsigned)y < (unsigned)H3 && (unsigned)x < (unsigned)H3)
                v = *(const bf16x8*)(ab + ((size_t)(y * H3 + x)) * DCH + (c << 3));
            *(bf16x8*)((char*)lds + swz(pix, c)) = v;
        }
    }
    __syncthreads();

    int wv = tid >> 6, lane = tid & 63;
    int lc = lane & 15, kg = lane >> 4;
    int pixBase[7];
    bool pv[7];
    #pragma unroll
    for (int i = 0; i < 7; i++) {
        int p = (wv * 7 + i) * 16 + lc;
        pv[i] = p < HW3;
        int pc = pv[i] ? p : HW3 - 1;
        pixBase[i] = (pc / 21) * 23 + (pc % 21);
    }

    const bf16x8* wvv = (const bf16x8*)wp;
    f32x4 acc[7][4];
    #pragma unroll
    for (int i = 0; i < 7; i++)
        #pragma unroll
        for (int m = 0; m < 4; m++)
            acc[i][m] = (f32x4){0.f, 0.f, 0.f, 0.f};

    for (int s = 0; s < 9; s++) {
        int offs = (s / 3) * 23 + (s % 3);   // pix = base + (ky+1)*23 + (kx+1)
        #pragma unroll
        for (int t = 0; t < 2; t++) {
            int fbase = ((s * 2 + t) * 4) << 6;
            bf16x8 a0 = wvv[fbase + lane];
            bf16x8 a1 = wvv[fbase + 64 + lane];
            bf16x8 a2 = wvv[fbase + 128 + lane];
            bf16x8 a3 = wvv[fbase + 192 + lane];
            int c = (t << 2) + kg;
            #pragma unroll
            for (int i = 0; i < 7; i++) {
                int pix = pixBase[i] + offs;
                bf16x8 bb = *(const bf16x8*)((const char*)lds + swz(pix, c));
                acc[i][0] = __builtin_amdgcn_mfma_f32_16x16x32_bf16(a0, bb, acc[i][0], 0, 0, 0);
                acc[i][1] = __builtin_amdgcn_mfma_f32_16x16x32_bf16(a1, bb, acc[i][1], 0, 0, 0);
                acc[i][2] = __builtin_amdgcn_mfma_f32_16x16x32_bf16(a2, bb, acc[i][2], 0, 0, 0);
                acc[i][3] = __builtin_amdgcn_mfma_f32_16x16x32_bf16(a3, bb, acc[i][3], 0, 0, 0);
            }
        }
    }

    #pragma unroll
    for (int mt = 0; mt < 4; mt++) {
        int co0 = (mt << 4) + (kg << 2);
        float4 sc = *reinterpret_cast<const float4*>(scale + co0);
        float4 bi = *reinterpret_cast<const float4*>(bias + co0);
        #pragma unroll
        for (int i = 0; i < 7; i++) {
            if (!pv[i]) continue;
            int p = (wv * 7 + i) * 16 + lc;
            unsigned short uo[4];
            #pragma unroll
            for (int r = 0; r < 4; r++) {
                float v = acc[i][mt][r] * (&sc.x)[r] + (&bi.x)[r];
                uo[r] = f2bf(fmaxf(v, 0.f));
            }
            uint2 pk;
            pk.x = (unsigned)uo[0] | ((unsigned)uo[1] << 16);
            pk.y = (unsigned)uo[2] | ((unsigned)uo[3] << 16);
            *reinterpret_cast<uint2*>(out + ((size_t)img * HW3 + p) * DCH + co0) = pk;
        }
    }
}

// ---------------- query L2-normalize: NHWC bf16 -> [img][hw][64] bf16 ----------------
__global__ __launch_bounds__(256) void q_norm(
    const unsigned short* __restrict__ feat, unsigned short* __restrict__ q_local)
{
    int idx = blockIdx.x * 256 + threadIdx.x;
    if (idx >= NQIMG * HW3) return;
    const bf16x8* f = (const bf16x8*)(feat + (size_t)idx * DCH);
    float v[DCH];
    float ss = 0.f;
    #pragma unroll
    for (int g = 0; g < 8; g++) {
        bf16x8 x = f[g];
        #pragma unroll
        for (int j = 0; j < 8; j++) {
            float vv = bf2f((unsigned short)x[j]);
            v[g * 8 + j] = vv;
            ss = fmaf(vv, vv, ss);
        }
    }
    float inv = 1.f / fmaxf(sqrtf(ss), EPS);
    bf16x8* o = (bf16x8*)(q_local + (size_t)idx * DCH);
    #pragma unroll
    for (int g = 0; g < 8; g++) {
        bf16x8 pk;
        #pragma unroll
        for (int j = 0; j < 8; j++) pk[j] = (short)f2bf(v[g * 8 + j] * inv);
        o[g] = pk;
    }
}

// ---------------- support: mean over shots + L2-normalize -> [bc][hw][64] bf16 ----------------
__global__ __launch_bounds__(256) void s_mean_norm(
    const unsigned short* __restrict__ feat, unsigned short* __restrict__ s_local)
{
    int idx = blockIdx.x * 256 + threadIdx.x;
    if (idx >= BDIM * WAY * HW3) return;
    int hw = idx % HW3;
    int bc = idx / HW3;
    int img0 = NQIMG + bc * SHOT;
    float v[DCH];
    #pragma unroll
    for (int d = 0; d < DCH; d++) v[d] = 0.f;
    for (int sh = 0; sh < SHOT; sh++) {
        const bf16x8* f = (const bf16x8*)(feat + ((size_t)(img0 + sh) * HW3 + hw) * DCH);
        #pragma unroll
        for (int g = 0; g < 8; g++) {
            bf16x8 x = f[g];
            #pragma unroll
            for (int j = 0; j < 8; j++)
                v[g * 8 + j] += bf2f((unsigned short)x[j]);
        }
    }
    float ss = 0.f;
    #pragma unroll
    for (int d = 0; d < DCH; d++) {
        v[d] *= (1.f / SHOT);
        ss = fmaf(v[d], v[d], ss);
    }
    float inv = 1.f / fmaxf(sqrtf(ss), EPS);
    bf16x8* o = (bf16x8*)(s_local + (size_t)idx * DCH);
    #pragma unroll
    for (int g = 0; g < 8; g++) {
        bf16x8 pk;
        #pragma unroll
        for (int j = 0; j < 8; j++) pk[j] = (short)f2bf(v[g * 8 + j] * inv);
        o[g] = pk;
    }
}

// ---------------- similarity via MFMA ----------------
#define SLDW 72
__global__ __launch_bounds__(256) void sim_mfma(
    const unsigned short* __restrict__ qloc,  // [150][441][64] bf16
    const unsigned short* __restrict__ sloc,  // [10][441][64] bf16
    float* __restrict__ out)
{
    int blk = blockIdx.x;
    int imgq = blk / WAY, way = blk % WAY;
    int b = imgq / NQ;
    const unsigned short* qp = qloc + (size_t)imgq * HW3 * DCH;
    const unsigned short* sp = sloc + (size_t)(b * WAY + way) * HW3 * DCH;

    __shared__ unsigned short slds[448 * SLDW];
    int tid = threadIdx.x;
    for (int i = tid; i < 448 * 8; i += 256) {
        int row = i >> 3, ch = (i & 7) << 3;
        bf16x8 v = (bf16x8)(short)0;
        if (row < HW3) v = *(const bf16x8*)(sp + (size_t)row * DCH + ch);
        *(bf16x8*)(&slds[row * SLDW + ch]) = v;
    }
    __syncthreads();

    int wv = tid >> 6, lane = tid & 63;
    int lc = lane & 15, kg = lane >> 4;
    int mt0 = wv * 7;

    bf16x8 qa0[7], qa1[7];
    #pragma unroll
    for (int i = 0; i < 7; i++) {
        const unsigned short* qrow = qp + (size_t)((mt0 + i) * 16 + lc) * DCH + (kg << 3);
        qa0[i] = *(const bf16x8*)(qrow);
        qa1[i] = *(const bf16x8*)(qrow + 32);
    }
    f32x4 rmax[7];
    #pragma unroll
    for (int i = 0; i < 7; i++)
        rmax[i] = (f32x4){-1e30f, -1e30f, -1e30f, -1e30f};

    for (int nt = 0; nt < 27; nt++) {
        const unsigned short* srow = &slds[(nt * 16 + lc) * SLDW + (kg << 3)];
        bf16x8 sb0 = *(const bf16x8*)(srow);
        bf16x8 sb1 = *(const bf16x8*)(srow + 32);
        #pragma unroll
        for (int i = 0; i < 7; i++) {
            f32x4 acc = (f32x4){0.f, 0.f, 0.f, 0.f};
            acc = __builtin_amdgcn_mfma_f32_16x16x32_bf16(qa0[i], sb0, acc, 0, 0, 0);
            acc = __builtin_amdgcn_mfma_f32_16x16x32_bf16(qa1[i], sb1, acc, 0, 0, 0);
            rmax[i][0] = fmaxf(rmax[i][0], acc[0]);
            rmax[i][1] = fmaxf(rmax[i][1], acc[1]);
            rmax[i][2] = fmaxf(rmax[i][2], acc[2]);
            rmax[i][3] = fmaxf(rmax[i][3], acc[3]);
        }
    }
    {   // last n-tile (cols 432..447): mask invalid cols
        const unsigned short* srow = &slds[(432 + lc) * SLDW + (kg << 3)];
        bf16x8 sb0 = *(const bf16x8*)(srow);
        bf16x8 sb1 = *(const bf16x8*)(srow + 32);
        bool nval = (432 + lc) < HW3;
        #pragma unroll
        for (int i = 0; i < 7; i++) {
            f32x4 acc = (f32x4){0.f, 0.f, 0.f, 0.f};
            acc = __builtin_amdgcn_mfma_f32_16x16x32_bf16(qa0[i], sb0, acc, 0, 0, 0);
            acc = __builtin_amdgcn_mfma_f32_16x16x32_bf16(qa1[i], sb1, acc, 0, 0, 0);
            #pragma unroll
            for (int r = 0; r < 4; r++)
                rmax[i][r] = fmaxf(rmax[i][r], nval ? acc[r] : -1e30f);
        }
    }

    float msum = 0.f;
    #pragma unroll
    for (int i = 0; i < 7; i++) {
        #pragma unroll
        for (int r = 0; r < 4; r++) {
            float v = rmax[i][r];
            v = fmaxf(v, __shfl_xor(v, 1, 64));
            v = fmaxf(v, __shfl_xor(v, 2, 64));
            v = fmaxf(v, __shfl_xor(v, 4, 64));
            v = fmaxf(v, __shfl_xor(v, 8, 64));
            int m = (mt0 + i) * 16 + (kg << 2) + r;
            if (lc == 0 && m < HW3) msum += v;
        }
    }
    #pragma unroll
    for (int off = 32; off > 0; off >>= 1)
        msum += __shfl_xor(msum, off, 64);
    __shared__ float red[4];
    if (lane == 0) red[wv] = msum;
    __syncthreads();
    if (tid == 0)
        out[(size_t)imgq * WAY + way] = (red[0] + red[1] + red[2] + red[3]) * (1.f / HW3);
}

extern "C" void kernel_launch(void* const* d_in, const int* in_sizes, int n_in,
                              void* d_out, int out_size, void* d_ws, size_t ws_size,
                              hipStream_t stream) {
    const float* query   = (const float*)d_in[0];
    const float* support = (const float*)d_in[1];
    const float* w1 = (const float*)d_in[2];
    const float* w2 = (const float*)d_in[3];
    const float* w3 = (const float*)d_in[4];
    const float* w4 = (const float*)d_in[5];
    const float* s1 = (const float*)d_in[6];
    const float* b1 = (const float*)d_in[7];
    const float* s2 = (const float*)d_in[8];
    const float* b2 = (const float*)d_in[9];
    const float* s3 = (const float*)d_in[10];
    const float* b3 = (const float*)d_in[11];
    const float* s4 = (const float*)d_in[12];
    const float* b4 = (const float*)d_in[13];
    float* out = (float*)d_out;

    char* ws = (char*)d_ws;
    unsigned short* A1  = (unsigned short*)(ws);              // 200*1764*64 bf16 = 45,158,400 B
    unsigned short* A2  = (unsigned short*)(ws + 45158400);   // 200*441*64 bf16 = 11,289,600 B
    unsigned short* A3  = (unsigned short*)(ws + 56448000);
    unsigned short* A4  = (unsigned short*)(ws + 67737600);
    unsigned short* QL  = (unsigned short*)(ws + 79027200);   // 150*441*64 bf16 = 8,467,200 B
    unsigned short* SL  = (unsigned short*)(ws + 87495296);   // 10*441*64 bf16 = 564,480 B
    unsigned short* WP2 = (unsigned short*)(ws + 88059776);   // 36864 bf16 = 73,728 B
    unsigned short* WP3 = (unsigned short*)(ws + 88133504);
    unsigned short* WP4 = (unsigned short*)(ws + 88207232);
    unsigned short* WP1 = (unsigned short*)(ws + 88280960);   // 2048 bf16 = 4,096 B
    unsigned short* PAD = (unsigned short*)(ws + 88285056);   // 200*3*7396 bf16 = 8,875,200 B

    pad_in<<<(NIMG * 3 * PSZ + 255) / 256, 256, 0, stream>>>(query, support, PAD);
    pack_w1<<<8, 256, 0, stream>>>(w1, WP1);
    pack_w<<<(3 * 36864 + 255) / 256, 256, 0, stream>>>(w2, w3, w4, WP2, WP3, WP4);

    conv1_mfma<<<NIMG * 8, 256, 0, stream>>>(PAD, WP1, s1, b1, A1);
    conv2_mfma_pool<<<NIMG * 7, 256, 0, stream>>>(A1, WP2, s2, b2, A2);
    conv34_mfma<<<NIMG, 256, 0, stream>>>(A2, WP3, s3, b3, A3);
    conv34_mfma<<<NIMG, 256, 0, stream>>>(A3, WP4, s4, b4, A4);

    q_norm<<<(NQIMG * HW3 + 255) / 256, 256, 0, stream>>>(A4, QL);
    s_mean_norm<<<(BDIM * WAY * HW3 + 255) / 256, 256, 0, stream>>>(A4, SL);

    sim_mfma<<<NQIMG * WAY, 256, 0, stream>>>(QL, SL, out);
}

// Round 8
// 174.164 us; speedup vs baseline: 32.4231x; 1.0676x over previous
//
#include <hip/hip_runtime.h>

#define EPS 1e-12f

// Problem constants
#define NIMG   200      // 150 query + 50 support
#define NQIMG  150
#define BDIM   2
#define NQ     75
#define WAY    5
#define SHOT   5
#define DCH    64
#define H1     84
#define H2     42
#define H3     21
#define HW2    1764     // 42*42
#define HW3    441      // 21*21
#define PH     86       // padded 84+2
#define PSZ    7396     // 86*86

typedef __attribute__((ext_vector_type(8))) short bf16x8;
typedef __attribute__((ext_vector_type(4))) float f32x4;

__device__ __forceinline__ unsigned short f2bf(float f) {
    unsigned u = __float_as_uint(f);
    u += 0x7fffu + ((u >> 16) & 1u);
    return (unsigned short)(u >> 16);
}
__device__ __forceinline__ float bf2f(unsigned short h) {
    return __uint_as_float(((unsigned)h) << 16);
}
// LDS pixel-line swizzle: 128B line per pixel, 8 x 16B chunks; chunk ^= (pix>>1)&7
__device__ __forceinline__ int swz(int pix, int c) {
    return pix * 128 + ((c ^ ((pix >> 1) & 7)) << 4);
}

// ---------------- input zero-pad: f32 NCHW 84x84 -> bf16 [img][3][86][86] ----------------
__global__ __launch_bounds__(256) void pad_in(
    const float* __restrict__ qin, const float* __restrict__ sin_,
    unsigned short* __restrict__ pad)
{
    int idx = blockIdx.x * 256 + threadIdx.x;
    if (idx >= NIMG * 3 * PSZ) return;
    int img = idx / (3 * PSZ);
    int rem = idx % (3 * PSZ);
    int ci = rem / PSZ, p = rem % PSZ;
    int iy = p / PH, ix = p % PH;
    float v = 0.f;
    if (iy >= 1 && iy <= H1 && ix >= 1 && ix <= H1) {
        const float* src = (img < NQIMG) ? (qin + (size_t)img * 3 * H1 * H1)
                                         : (sin_ + (size_t)(img - NQIMG) * 3 * H1 * H1);
        v = src[(size_t)ci * H1 * H1 + (iy - 1) * H1 + (ix - 1)];
    }
    pad[idx] = f2bf(v);
}

// ---------------- w1 pack: (64,3,3,3) f32 * scale -> MFMA A-fragments, K=27 pad 32 ----------------
__global__ __launch_bounds__(256) void pack_w1(
    const float* __restrict__ w1, const float* __restrict__ s1,
    unsigned short* __restrict__ p1)
{
    int idx = blockIdx.x * 256 + threadIdx.x;
    if (idx >= 2048) return;
    int j = idx & 7, lane = (idx >> 3) & 63, mt = idx >> 9;
    int co = (mt << 4) + (lane & 15);
    int k = ((lane >> 4) << 3) + j;
    float v = 0.f;
    if (k < 27) {
        int ci = k / 9, s = k % 9;
        v = w1[(co * 3 + ci) * 9 + s] * s1[co];
    }
    p1[idx] = f2bf(v);
}

// ---------------- weight pack: OIHW f32 * scale -> MFMA-fragment-ordered bf16 ----------------
__global__ __launch_bounds__(256) void pack_w(
    const float* __restrict__ w2, const float* __restrict__ s2,
    const float* __restrict__ w3, const float* __restrict__ s3,
    const float* __restrict__ w4, const float* __restrict__ s4,
    unsigned short* __restrict__ p2, unsigned short* __restrict__ p3,
    unsigned short* __restrict__ p4)
{
    int idx = blockIdx.x * 256 + threadIdx.x;
    if (idx >= 3 * 36864) return;
    int which = idx / 36864;
    int r = idx % 36864;
    int j = r & 7, lane = (r >> 3) & 63, mt = (r >> 9) & 3, t = (r >> 11) & 1, s = r >> 12;
    int co = (mt << 4) + (lane & 15);
    int ci = (t << 5) + ((lane >> 4) << 3) + j;
    const float* w = (which == 0) ? w2 : (which == 1) ? w3 : w4;
    const float* sc = (which == 0) ? s2 : (which == 1) ? s3 : s4;
    unsigned short* p = (which == 0) ? p2 : (which == 1) ? p3 : p4;
    p[r] = f2bf(w[(co * 64 + ci) * 9 + s] * sc[co]);
}

// ---------------- conv1: 3->64 MFMA im2col K=27->32, bias-init, pool by reg-max ----------------
// grid NIMG*7, block 256. Per wave-iter: 16 pooled px, 4 sub B-fragments (32 gathers
// issued up-front), 16 MFMAs, pooling = register max across subs, all lanes write.
__global__ __launch_bounds__(256) void conv1_mfma(
    const unsigned short* __restrict__ pad,   // [img][3][86][86] bf16
    const unsigned short* __restrict__ wp1,   // packed A fragments (scale folded)
    const float* __restrict__ bias,
    unsigned short* __restrict__ out)         // [img][1764][64] bf16 (pooled 42x42)
{
    int img = blockIdx.x / 7;
    int seg = blockIdx.x % 7;
    int tid = threadIdx.x;
    int wv = tid >> 6, lane = tid & 63;
    int lc = lane & 15, kg = lane >> 4;

    const bf16x8* wvv = (const bf16x8*)wp1;
    bf16x8 a0 = wvv[lane];
    bf16x8 a1 = wvv[64 + lane];
    bf16x8 a2 = wvv[128 + lane];
    bf16x8 a3 = wvv[192 + lane];

    int off[8];
    #pragma unroll
    for (int j = 0; j < 8; j++) {
        int k = (kg << 3) + j;
        int kk = k < 27 ? k : 0;          // k>=27: A is zero, B value irrelevant (finite)
        int ci = kk / 9, s = kk % 9;
        off[j] = ci * PSZ + (s / 3) * PH + (s % 3);
    }

    f32x4 bini[4];
    #pragma unroll
    for (int mt = 0; mt < 4; mt++) {
        float4 bq = *reinterpret_cast<const float4*>(bias + (mt << 4) + (kg << 2));
        bini[mt] = (f32x4){bq.x, bq.y, bq.z, bq.w};
    }

    const unsigned short* bimg = pad + (size_t)img * 3 * PSZ;

    #pragma unroll
    for (int it = 0; it < 4; it++) {
        int p = seg * 256 + it * 64 + wv * 16 + lc;    // pooled px
        bool valid = p < HW2;
        int pc = valid ? p : HW2 - 1;
        int py = pc / H2, px = pc % H2;

        bf16x8 b[4];
        #pragma unroll
        for (int sub = 0; sub < 4; sub++) {
            int base = (2 * py + (sub >> 1)) * PH + 2 * px + (sub & 1);
            #pragma unroll
            for (int j = 0; j < 8; j++)
                b[sub][j] = (short)bimg[base + off[j]];
        }

        f32x4 acc[4][4];
        #pragma unroll
        for (int mt = 0; mt < 4; mt++)
            #pragma unroll
            for (int sub = 0; sub < 4; sub++)
                acc[mt][sub] = bini[mt];
        #pragma unroll
        for (int sub = 0; sub < 4; sub++) {
            acc[0][sub] = __builtin_amdgcn_mfma_f32_16x16x32_bf16(a0, b[sub], acc[0][sub], 0, 0, 0);
            acc[1][sub] = __builtin_amdgcn_mfma_f32_16x16x32_bf16(a1, b[sub], acc[1][sub], 0, 0, 0);
            acc[2][sub] = __builtin_amdgcn_mfma_f32_16x16x32_bf16(a2, b[sub], acc[2][sub], 0, 0, 0);
            acc[3][sub] = __builtin_amdgcn_mfma_f32_16x16x32_bf16(a3, b[sub], acc[3][sub], 0, 0, 0);
        }

        #pragma unroll
        for (int mt = 0; mt < 4; mt++) {
            unsigned short uo[4];
            #pragma unroll
            for (int r = 0; r < 4; r++) {
                float m = fmaxf(fmaxf(acc[mt][0][r], acc[mt][1][r]),
                                fmaxf(acc[mt][2][r], acc[mt][3][r]));
                uo[r] = f2bf(fmaxf(m, 0.f));
            }
            if (valid) {
                uint2 pk;
                pk.x = (unsigned)uo[0] | ((unsigned)uo[1] << 16);
                pk.y = (unsigned)uo[2] | ((unsigned)uo[3] << 16);
                *reinterpret_cast<uint2*>(out + ((size_t)img * HW2 + p) * DCH + (mt << 4) + (kg << 2)) = pk;
            }
        }
    }
}

// ---------------- conv2: 64->64 MFMA + LDS strip staging, bias-init, pool, ReLU ----------------
__global__ __launch_bounds__(256) void conv2_mfma_pool(
    const unsigned short* __restrict__ act,   // [img][1764][64]
    const unsigned short* __restrict__ wp,    // packed fragments (scale folded)
    const float* __restrict__ bias,
    unsigned short* __restrict__ out)         // [img][441][64]
{
    int img = blockIdx.x / 7, tg = blockIdx.x % 7;
    int tid = threadIdx.x;
    __shared__ unsigned short lds[8 * 44 * DCH];   // 45,056 B

    const unsigned short* ab = act + (size_t)img * HW2 * DCH;
    int ybase = 6 * tg - 1;
    #pragma unroll
    for (int it = 0; it < 11; it++) {
        int idx = it * 256 + tid;
        int pix = idx >> 3, c = idx & 7;
        int r = pix / 44, xx = pix % 44;
        int y = ybase + r, x = xx - 1;
        bf16x8 v = (bf16x8)(short)0;
        if ((unsigned)y < (unsigned)H2 && (unsigned)x < (unsigned)H2)
            v = *(const bf16x8*)(ab + ((size_t)(y * H2 + x)) * DCH + (c << 3));
        *(bf16x8*)((char*)lds + swz(pix, c)) = v;
    }
    __syncthreads();

    int wv = tid >> 6, lane = tid & 63;
    int lc = lane & 15, kg = lane >> 4;
    int p_local = wv * 16 + lc;
    bool valid = p_local < 63;
    int pl = valid ? p_local : 62;
    int pyl = pl / 21, pxl = pl % 21;
    int pixc[4];
    #pragma unroll
    for (int sub = 0; sub < 4; sub++)
        pixc[sub] = (2 * pyl + (sub >> 1) + 1) * 44 + (2 * pxl + (sub & 1) + 1);

    f32x4 bini[4];
    #pragma unroll
    for (int mt = 0; mt < 4; mt++) {
        float4 bq = *reinterpret_cast<const float4*>(bias + (mt << 4) + (kg << 2));
        bini[mt] = (f32x4){bq.x, bq.y, bq.z, bq.w};
    }

    const bf16x8* wvv = (const bf16x8*)wp;
    f32x4 acc[4][4];
    #pragma unroll
    for (int i = 0; i < 4; i++)
        #pragma unroll
        for (int j = 0; j < 4; j++)
            acc[i][j] = bini[i];

    for (int s = 0; s < 9; s++) {
        int offs = (s / 3 - 1) * 44 + (s % 3 - 1);
        #pragma unroll
        for (int t = 0; t < 2; t++) {
            int fbase = ((s * 2 + t) * 4) << 6;
            bf16x8 a0 = wvv[fbase + lane];
            bf16x8 a1 = wvv[fbase + 64 + lane];
            bf16x8 a2 = wvv[fbase + 128 + lane];
            bf16x8 a3 = wvv[fbase + 192 + lane];
            int c = (t << 2) + kg;
            bf16x8 b[4];
            #pragma unroll
            for (int sub = 0; sub < 4; sub++) {
                int pix = pixc[sub] + offs;
                b[sub] = *(const bf16x8*)((const char*)lds + swz(pix, c));
            }
            #pragma unroll
            for (int sub = 0; sub < 4; sub++) {
                acc[0][sub] = __builtin_amdgcn_mfma_f32_16x16x32_bf16(a0, b[sub], acc[0][sub], 0, 0, 0);
                acc[1][sub] = __builtin_amdgcn_mfma_f32_16x16x32_bf16(a1, b[sub], acc[1][sub], 0, 0, 0);
                acc[2][sub] = __builtin_amdgcn_mfma_f32_16x16x32_bf16(a2, b[sub], acc[2][sub], 0, 0, 0);
                acc[3][sub] = __builtin_amdgcn_mfma_f32_16x16x32_bf16(a3, b[sub], acc[3][sub], 0, 0, 0);
            }
        }
    }

    if (!valid) return;
    int p = tg * 63 + p_local;
    #pragma unroll
    for (int mt = 0; mt < 4; mt++) {
        unsigned short uo[4];
        #pragma unroll
        for (int r = 0; r < 4; r++) {
            float m = fmaxf(fmaxf(acc[mt][0][r], acc[mt][1][r]),
                            fmaxf(acc[mt][2][r], acc[mt][3][r]));
            uo[r] = f2bf(fmaxf(m, 0.f));
        }
        uint2 pk;
        pk.x = (unsigned)uo[0] | ((unsigned)uo[1] << 16);
        pk.y = (unsigned)uo[2] | ((unsigned)uo[3] << 16);
        *reinterpret_cast<uint2*>(out + ((size_t)img * HW3 + p) * DCH + (mt << 4) + (kg << 2)) = pk;
    }
}

// ---------------- conv3/4: 64->64 MFMA, whole image in LDS, bias-init, ReLU ----------------
__global__ __launch_bounds__(256) void conv34_mfma(
    const unsigned short* __restrict__ act,   // [img][441][64]
    const unsigned short* __restrict__ wp,
    const float* __restrict__ bias,
    unsigned short* __restrict__ out)         // [img][441][64]
{
    int img = blockIdx.x;
    int tid = threadIdx.x;
    __shared__ unsigned short lds[529 * DCH];   // 67,712 B

    const unsigned short* ab = act + (size_t)img * HW3 * DCH;
    #pragma unroll
    for (int it = 0; it < 17; it++) {
        int idx = it * 256 + tid;
        if (idx < 529 * 8) {
            int pix = idx >> 3, c = idx & 7;
            int r = pix / 23, xx = pix % 23;
            int y = r - 1, x = xx - 1;
            bf16x8 v = (bf16x8)(short)0;
            if ((unsigned)y < (unsigned)H3 && (unsigned)x < (unsigned)H3)
                v = *(const bf16x8*)(ab + ((size_t)(y * H3 + x)) * DCH + (c << 3));
            *(bf16x8*)((char*)lds + swz(pix, c)) = v;
        }
    }
    __syncthreads();

    int wv = tid >> 6, lane = tid & 63;
    int lc = lane & 15, kg = lane >> 4;
    int pixBase[7];
    bool pv[7];
    #pragma unroll
    for (int i = 0; i < 7; i++) {
        int p = (wv * 7 + i) * 16 + lc;
        pv[i] = p < HW3;
        int pc = pv[i] ? p : HW3 - 1;
        pixBase[i] = (pc / 21) * 23 + (pc % 21);
    }

    f32x4 bini[4];
    #pragma unroll
    for (int mt = 0; mt < 4; mt++) {
        float4 bq = *reinterpret_cast<const float4*>(bias + (mt << 4) + (kg << 2));
        bini[mt] = (f32x4){bq.x, bq.y, bq.z, bq.w};
    }

    const bf16x8* wvv = (const bf16x8*)wp;
    f32x4 acc[7][4];
    #pragma unroll
    for (int i = 0; i < 7; i++)
        #pragma unroll
        for (int m = 0; m < 4; m++)
            acc[i][m] = bini[m];

    for (int s = 0; s < 9; s++) {
        int offs = (s / 3) * 23 + (s % 3);
        #pragma unroll
        for (int t = 0; t < 2; t++) {
            int fbase = ((s * 2 + t) * 4) << 6;
            bf16x8 a0 = wvv[fbase + lane];
            bf16x8 a1 = wvv[fbase + 64 + lane];
            bf16x8 a2 = wvv[fbase + 128 + lane];
            bf16x8 a3 = wvv[fbase + 192 + lane];
            int c = (t << 2) + kg;
            #pragma unroll
            for (int i = 0; i < 7; i++) {
                int pix = pixBase[i] + offs;
                bf16x8 bb = *(const bf16x8*)((const char*)lds + swz(pix, c));
                acc[i][0] = __builtin_amdgcn_mfma_f32_16x16x32_bf16(a0, bb, acc[i][0], 0, 0, 0);
                acc[i][1] = __builtin_amdgcn_mfma_f32_16x16x32_bf16(a1, bb, acc[i][1], 0, 0, 0);
                acc[i][2] = __builtin_amdgcn_mfma_f32_16x16x32_bf16(a2, bb, acc[i][2], 0, 0, 0);
                acc[i][3] = __builtin_amdgcn_mfma_f32_16x16x32_bf16(a3, bb, acc[i][3], 0, 0, 0);
            }
        }
    }

    #pragma unroll
    for (int mt = 0; mt < 4; mt++) {
        #pragma unroll
        for (int i = 0; i < 7; i++) {
            if (!pv[i]) continue;
            int p = (wv * 7 + i) * 16 + lc;
            unsigned short uo[4];
            #pragma unroll
            for (int r = 0; r < 4; r++)
                uo[r] = f2bf(fmaxf(acc[i][mt][r], 0.f));
            uint2 pk;
            pk.x = (unsigned)uo[0] | ((unsigned)uo[1] << 16);
            pk.y = (unsigned)uo[2] | ((unsigned)uo[3] << 16);
            *reinterpret_cast<uint2*>(out + ((size_t)img * HW3 + p) * DCH + (mt << 4) + (kg << 2)) = pk;
        }
    }
}

// ---------------- query L2-normalize: NHWC bf16 -> [img][hw][64] bf16 ----------------
__global__ __launch_bounds__(256) void q_norm(
    const unsigned short* __restrict__ feat, unsigned short* __restrict__ q_local)
{
    int idx = blockIdx.x * 256 + threadIdx.x;
    if (idx >= NQIMG * HW3) return;
    const bf16x8* f = (const bf16x8*)(feat + (size_t)idx * DCH);
    float v[DCH];
    float ss = 0.f;
    #pragma unroll
    for (int g = 0; g < 8; g++) {
        bf16x8 x = f[g];
        #pragma unroll
        for (int j = 0; j < 8; j++) {
            float vv = bf2f((unsigned short)x[j]);
            v[g * 8 + j] = vv;
            ss = fmaf(vv, vv, ss);
        }
    }
    float inv = 1.f / fmaxf(sqrtf(ss), EPS);
    bf16x8* o = (bf16x8*)(q_local + (size_t)idx * DCH);
    #pragma unroll
    for (int g = 0; g < 8; g++) {
        bf16x8 pk;
        #pragma unroll
        for (int j = 0; j < 8; j++) pk[j] = (short)f2bf(v[g * 8 + j] * inv);
        o[g] = pk;
    }
}

// ---------------- support: mean over shots + L2-normalize -> [bc][hw][64] bf16 ----------------
__global__ __launch_bounds__(256) void s_mean_norm(
    const unsigned short* __restrict__ feat, unsigned short* __restrict__ s_local)
{
    int idx = blockIdx.x * 256 + threadIdx.x;
    if (idx >= BDIM * WAY * HW3) return;
    int hw = idx % HW3;
    int bc = idx / HW3;
    int img0 = NQIMG + bc * SHOT;
    float v[DCH];
    #pragma unroll
    for (int d = 0; d < DCH; d++) v[d] = 0.f;
    for (int sh = 0; sh < SHOT; sh++) {
        const bf16x8* f = (const bf16x8*)(feat + ((size_t)(img0 + sh) * HW3 + hw) * DCH);
        #pragma unroll
        for (int g = 0; g < 8; g++) {
            bf16x8 x = f[g];
            #pragma unroll
            for (int j = 0; j < 8; j++)
                v[g * 8 + j] += bf2f((unsigned short)x[j]);
        }
    }
    float ss = 0.f;
    #pragma unroll
    for (int d = 0; d < DCH; d++) {
        v[d] *= (1.f / SHOT);
        ss = fmaf(v[d], v[d], ss);
    }
    float inv = 1.f / fmaxf(sqrtf(ss), EPS);
    bf16x8* o = (bf16x8*)(s_local + (size_t)idx * DCH);
    #pragma unroll
    for (int g = 0; g < 8; g++) {
        bf16x8 pk;
        #pragma unroll
        for (int j = 0; j < 8; j++) pk[j] = (short)f2bf(v[g * 8 + j] * inv);
        o[g] = pk;
    }
}

// ---------------- similarity via MFMA ----------------
#define SLDW 72
__global__ __launch_bounds__(256) void sim_mfma(
    const unsigned short* __restrict__ qloc,  // [150][441][64] bf16
    const unsigned short* __restrict__ sloc,  // [10][441][64] bf16
    float* __restrict__ out)
{
    int blk = blockIdx.x;
    int imgq = blk / WAY, way = blk % WAY;
    int b = imgq / NQ;
    const unsigned short* qp = qloc + (size_t)imgq * HW3 * DCH;
    const unsigned short* sp = sloc + (size_t)(b * WAY + way) * HW3 * DCH;

    __shared__ unsigned short slds[448 * SLDW];
    int tid = threadIdx.x;
    for (int i = tid; i < 448 * 8; i += 256) {
        int row = i >> 3, ch = (i & 7) << 3;
        bf16x8 v = (bf16x8)(short)0;
        if (row < HW3) v = *(const bf16x8*)(sp + (size_t)row * DCH + ch);
        *(bf16x8*)(&slds[row * SLDW + ch]) = v;
    }
    __syncthreads();

    int wv = tid >> 6, lane = tid & 63;
    int lc = lane & 15, kg = lane >> 4;
    int mt0 = wv * 7;

    bf16x8 qa0[7], qa1[7];
    #pragma unroll
    for (int i = 0; i < 7; i++) {
        const unsigned short* qrow = qp + (size_t)((mt0 + i) * 16 + lc) * DCH + (kg << 3);
        qa0[i] = *(const bf16x8*)(qrow);
        qa1[i] = *(const bf16x8*)(qrow + 32);
    }
    f32x4 rmax[7];
    #pragma unroll
    for (int i = 0; i < 7; i++)
        rmax[i] = (f32x4){-1e30f, -1e30f, -1e30f, -1e30f};

    for (int nt = 0; nt < 27; nt++) {
        const unsigned short* srow = &slds[(nt * 16 + lc) * SLDW + (kg << 3)];
        bf16x8 sb0 = *(const bf16x8*)(srow);
        bf16x8 sb1 = *(const bf16x8*)(srow + 32);
        #pragma unroll
        for (int i = 0; i < 7; i++) {
            f32x4 acc = (f32x4){0.f, 0.f, 0.f, 0.f};
            acc = __builtin_amdgcn_mfma_f32_16x16x32_bf16(qa0[i], sb0, acc, 0, 0, 0);
            acc = __builtin_amdgcn_mfma_f32_16x16x32_bf16(qa1[i], sb1, acc, 0, 0, 0);
            rmax[i][0] = fmaxf(rmax[i][0], acc[0]);
            rmax[i][1] = fmaxf(rmax[i][1], acc[1]);
            rmax[i][2] = fmaxf(rmax[i][2], acc[2]);
            rmax[i][3] = fmaxf(rmax[i][3], acc[3]);
        }
    }
    {   // last n-tile (cols 432..447): mask invalid cols
        const unsigned short* srow = &slds[(432 + lc) * SLDW + (kg << 3)];
        bf16x8 sb0 = *(const bf16x8*)(srow);
        bf16x8 sb1 = *(const bf16x8*)(srow + 32);
        bool nval = (432 + lc) < HW3;
        #pragma unroll
        for (int i = 0; i < 7; i++) {
            f32x4 acc = (f32x4){0.f, 0.f, 0.f, 0.f};
            acc = __builtin_amdgcn_mfma_f32_16x16x32_bf16(qa0[i], sb0, acc, 0, 0, 0);
            acc = __builtin_amdgcn_mfma_f32_16x16x32_bf16(qa1[i], sb1, acc, 0, 0, 0);
            #pragma unroll
            for (int r = 0; r < 4; r++)
                rmax[i][r] = fmaxf(rmax[i][r], nval ? acc[r] : -1e30f);
        }
    }

    float msum = 0.f;
    #pragma unroll
    for (int i = 0; i < 7; i++) {
        #pragma unroll
        for (int r = 0; r < 4; r++) {
            float v = rmax[i][r];
            v = fmaxf(v, __shfl_xor(v, 1, 64));
            v = fmaxf(v, __shfl_xor(v, 2, 64));
            v = fmaxf(v, __shfl_xor(v, 4, 64));
            v = fmaxf(v, __shfl_xor(v, 8, 64));
            int m = (mt0 + i) * 16 + (kg << 2) + r;
            if (lc == 0 && m < HW3) msum += v;
        }
    }
    #pragma unroll
    for (int off = 32; off > 0; off >>= 1)
        msum += __shfl_xor(msum, off, 64);
    __shared__ float red[4];
    if (lane == 0) red[wv] = msum;
    __syncthreads();
    if (tid == 0)
        out[(size_t)imgq * WAY + way] = (red[0] + red[1] + red[2] + red[3]) * (1.f / HW3);
}

extern "C" void kernel_launch(void* const* d_in, const int* in_sizes, int n_in,
                              void* d_out, int out_size, void* d_ws, size_t ws_size,
                              hipStream_t stream) {
    const float* query   = (const float*)d_in[0];
    const float* support = (const float*)d_in[1];
    const float* w1 = (const float*)d_in[2];
    const float* w2 = (const float*)d_in[3];
    const float* w3 = (const float*)d_in[4];
    const float* w4 = (const float*)d_in[5];
    const float* s1 = (const float*)d_in[6];
    const float* b1 = (const float*)d_in[7];
    const float* s2 = (const float*)d_in[8];
    const float* b2 = (const float*)d_in[9];
    const float* s3 = (const float*)d_in[10];
    const float* b3 = (const float*)d_in[11];
    const float* s4 = (const float*)d_in[12];
    const float* b4 = (const float*)d_in[13];
    float* out = (float*)d_out;

    char* ws = (char*)d_ws;
    unsigned short* A1  = (unsigned short*)(ws);              // 200*1764*64 bf16 = 45,158,400 B
    unsigned short* A2  = (unsigned short*)(ws + 45158400);   // 200*441*64 bf16 = 11,289,600 B
    unsigned short* A3  = (unsigned short*)(ws + 56448000);
    unsigned short* A4  = (unsigned short*)(ws + 67737600);
    unsigned short* QL  = (unsigned short*)(ws + 79027200);   // 150*441*64 bf16 = 8,467,200 B
    unsigned short* SL  = (unsigned short*)(ws + 87495296);   // 10*441*64 bf16 = 564,480 B
    unsigned short* WP2 = (unsigned short*)(ws + 88059776);   // 36864 bf16 = 73,728 B
    unsigned short* WP3 = (unsigned short*)(ws + 88133504);
    unsigned short* WP4 = (unsigned short*)(ws + 88207232);
    unsigned short* WP1 = (unsigned short*)(ws + 88280960);   // 2048 bf16 = 4,096 B
    unsigned short* PAD = (unsigned short*)(ws + 88285056);   // 200*3*7396 bf16 = 8,875,200 B

    pad_in<<<(NIMG * 3 * PSZ + 255) / 256, 256, 0, stream>>>(query, support, PAD);
    pack_w1<<<8, 256, 0, stream>>>(w1, s1, WP1);
    pack_w<<<(3 * 36864 + 255) / 256, 256, 0, stream>>>(w2, s2, w3, s3, w4, s4, WP2, WP3, WP4);

    conv1_mfma<<<NIMG * 7, 256, 0, stream>>>(PAD, WP1, b1, A1);
    conv2_mfma_pool<<<NIMG * 7, 256, 0, stream>>>(A1, WP2, b2, A2);
    conv34_mfma<<<NIMG, 256, 0, stream>>>(A2, WP3, b3, A3);
    conv34_mfma<<<NIMG, 256, 0, stream>>>(A3, WP4, b4, A4);

    q_norm<<<(NQIMG * HW3 + 255) / 256, 256, 0, stream>>>(A4, QL);
    s_mean_norm<<<(BDIM * WAY * HW3 + 255) / 256, 256, 0, stream>>>(A4, SL);

    sim_mfma<<<NQIMG * WAY, 256, 0, stream>>>(QL, SL, out);
}

// Round 9
// 153.558 us; speedup vs baseline: 36.7738x; 1.1342x over previous
//
#include <hip/hip_runtime.h>

#define EPS 1e-12f

// Problem constants
#define NIMG   200      // 150 query + 50 support
#define NQIMG  150
#define BDIM   2
#define NQ     75
#define WAY    5
#define SHOT   5
#define DCH    64
#define H1     84
#define H2     42
#define H3     21
#define HW2    1764     // 42*42
#define HW3    441      // 21*21
#define PH     86       // padded 84+2
#define PSZ    7396     // 86*86
#define SST    448      // padded support row stride

typedef __attribute__((ext_vector_type(8))) short bf16x8;
typedef __attribute__((ext_vector_type(4))) float f32x4;

__device__ __forceinline__ unsigned short f2bf(float f) {
    unsigned u = __float_as_uint(f);
    u += 0x7fffu + ((u >> 16) & 1u);
    return (unsigned short)(u >> 16);
}
__device__ __forceinline__ float bf2f(unsigned short h) {
    return __uint_as_float(((unsigned)h) << 16);
}
// LDS pixel-line swizzle for conv2/conv34: 128B line per pixel, chunk ^= (pix>>1)&7
__device__ __forceinline__ int swz(int pix, int c) {
    return pix * 128 + ((c ^ ((pix >> 1) & 7)) << 4);
}

// ---------------- input zero-pad: f32 NCHW 84x84 -> bf16 [img][3][86][86] ----------------
__global__ __launch_bounds__(256) void pad_in(
    const float* __restrict__ qin, const float* __restrict__ sin_,
    unsigned short* __restrict__ pad)
{
    int idx = blockIdx.x * 256 + threadIdx.x;
    if (idx >= NIMG * 3 * PSZ) return;
    int img = idx / (3 * PSZ);
    int rem = idx % (3 * PSZ);
    int ci = rem / PSZ, p = rem % PSZ;
    int iy = p / PH, ix = p % PH;
    float v = 0.f;
    if (iy >= 1 && iy <= H1 && ix >= 1 && ix <= H1) {
        const float* src = (img < NQIMG) ? (qin + (size_t)img * 3 * H1 * H1)
                                         : (sin_ + (size_t)(img - NQIMG) * 3 * H1 * H1);
        v = src[(size_t)ci * H1 * H1 + (iy - 1) * H1 + (ix - 1)];
    }
    pad[idx] = f2bf(v);
}

// ---------------- w1 pack: (64,3,3,3) f32 * scale -> MFMA A-fragments, K=27 pad 32 ----------------
__global__ __launch_bounds__(256) void pack_w1(
    const float* __restrict__ w1, const float* __restrict__ s1,
    unsigned short* __restrict__ p1)
{
    int idx = blockIdx.x * 256 + threadIdx.x;
    if (idx >= 2048) return;
    int j = idx & 7, lane = (idx >> 3) & 63, mt = idx >> 9;
    int co = (mt << 4) + (lane & 15);
    int k = ((lane >> 4) << 3) + j;
    float v = 0.f;
    if (k < 27) {
        int ci = k / 9, s = k % 9;
        v = w1[(co * 3 + ci) * 9 + s] * s1[co];
    }
    p1[idx] = f2bf(v);
}

// ---------------- weight pack: OIHW f32 * scale -> MFMA-fragment-ordered bf16 ----------------
__global__ __launch_bounds__(256) void pack_w(
    const float* __restrict__ w2, const float* __restrict__ s2,
    const float* __restrict__ w3, const float* __restrict__ s3,
    const float* __restrict__ w4, const float* __restrict__ s4,
    unsigned short* __restrict__ p2, unsigned short* __restrict__ p3,
    unsigned short* __restrict__ p4)
{
    int idx = blockIdx.x * 256 + threadIdx.x;
    if (idx >= 3 * 36864) return;
    int which = idx / 36864;
    int r = idx % 36864;
    int j = r & 7, lane = (r >> 3) & 63, mt = (r >> 9) & 3, t = (r >> 11) & 1, s = r >> 12;
    int co = (mt << 4) + (lane & 15);
    int ci = (t << 5) + ((lane >> 4) << 3) + j;
    const float* w = (which == 0) ? w2 : (which == 1) ? w3 : w4;
    const float* sc = (which == 0) ? s2 : (which == 1) ? s3 : s4;
    unsigned short* p = (which == 0) ? p2 : (which == 1) ? p3 : p4;
    p[r] = f2bf(w[(co * 64 + ci) * 9 + s] * sc[co]);
}

// ---------------- conv1: LDS strip stage + ds-gather im2col, 16 MFMA/iter, reg-max pool ----------------
// grid NIMG*7 (seg = 6 pooled rows), block 256. Strip: [3][14][86] bf16 = 7224 B.
__global__ __launch_bounds__(256) void conv1_mfma(
    const unsigned short* __restrict__ pad,   // [img][3][86][86] bf16
    const unsigned short* __restrict__ wp1,   // packed A fragments (scale folded)
    const float* __restrict__ bias,
    unsigned short* __restrict__ out)         // [img][1764][64] bf16
{
    int img = blockIdx.x / 7, seg = blockIdx.x % 7;
    int tid = threadIdx.x;
    __shared__ unsigned short strip[3 * 14 * 86];   // 7224 B

    // stage: per ci a contiguous 14-row block (602 dwords) starting at padded row 12*seg
    const unsigned* srcd = (const unsigned*)pad;
    size_t ibase = (size_t)img * 3 * (PSZ / 2);
    #pragma unroll
    for (int it = 0; it < 8; it++) {
        int i = it * 256 + tid;
        if (i < 1806) {
            int ci = i / 602, r = i % 602;
            ((unsigned*)strip)[i] = srcd[ibase + ci * (PSZ / 2) + 516 * seg + r];
        }
    }
    __syncthreads();

    int wv = tid >> 6, lane = tid & 63;
    int lc = lane & 15, kg = lane >> 4;

    const bf16x8* wvv = (const bf16x8*)wp1;
    bf16x8 a0 = wvv[lane];
    bf16x8 a1 = wvv[64 + lane];
    bf16x8 a2 = wvv[128 + lane];
    bf16x8 a3 = wvv[192 + lane];

    int off[8];
    #pragma unroll
    for (int j = 0; j < 8; j++) {
        int k = (kg << 3) + j;
        int kk = k < 27 ? k : 0;          // k>=27: A row is zero; finite B value irrelevant
        int ci = kk / 9, s = kk % 9;
        off[j] = ci * 1204 + (s / 3) * 86 + (s % 3);
    }

    f32x4 bini[4];
    #pragma unroll
    for (int mt = 0; mt < 4; mt++) {
        float4 bq = *reinterpret_cast<const float4*>(bias + (mt << 4) + (kg << 2));
        bini[mt] = (f32x4){bq.x, bq.y, bq.z, bq.w};
    }

    #pragma unroll
    for (int it = 0; it < 4; it++) {
        int pl = it * 64 + wv * 16 + lc;          // local pooled px 0..255 (252 valid)
        bool valid = pl < 252;
        int plc = valid ? pl : 251;
        int pyl = plc / 42, pxl = plc % 42;
        int base = pyl * 172 + 2 * pxl;           // (2*pyl)*86 + 2*pxl

        bf16x8 b[4];
        #pragma unroll
        for (int j = 0; j < 8; j++) {
            int a = base + off[j];
            b[0][j] = (short)strip[a];
            b[1][j] = (short)strip[a + 1];
            b[2][j] = (short)strip[a + 86];
            b[3][j] = (short)strip[a + 87];
        }

        f32x4 acc[4][4];
        #pragma unroll
        for (int mt = 0; mt < 4; mt++)
            #pragma unroll
            for (int sub = 0; sub < 4; sub++)
                acc[mt][sub] = bini[mt];
        #pragma unroll
        for (int sub = 0; sub < 4; sub++) {
            acc[0][sub] = __builtin_amdgcn_mfma_f32_16x16x32_bf16(a0, b[sub], acc[0][sub], 0, 0, 0);
            acc[1][sub] = __builtin_amdgcn_mfma_f32_16x16x32_bf16(a1, b[sub], acc[1][sub], 0, 0, 0);
            acc[2][sub] = __builtin_amdgcn_mfma_f32_16x16x32_bf16(a2, b[sub], acc[2][sub], 0, 0, 0);
            acc[3][sub] = __builtin_amdgcn_mfma_f32_16x16x32_bf16(a3, b[sub], acc[3][sub], 0, 0, 0);
        }

        if (valid) {
            int p = seg * 252 + pl;
            #pragma unroll
            for (int mt = 0; mt < 4; mt++) {
                unsigned short uo[4];
                #pragma unroll
                for (int r = 0; r < 4; r++) {
                    float m = fmaxf(fmaxf(acc[mt][0][r], acc[mt][1][r]),
                                    fmaxf(acc[mt][2][r], acc[mt][3][r]));
                    uo[r] = f2bf(fmaxf(m, 0.f));
                }
                uint2 pk;
                pk.x = (unsigned)uo[0] | ((unsigned)uo[1] << 16);
                pk.y = (unsigned)uo[2] | ((unsigned)uo[3] << 16);
                *reinterpret_cast<uint2*>(out + ((size_t)img * HW2 + p) * DCH + (mt << 4) + (kg << 2)) = pk;
            }
        }
    }
}

// ---------------- conv2: 64->64 MFMA + LDS strip staging, bias-init, pool, ReLU ----------------
__global__ __launch_bounds__(256) void conv2_mfma_pool(
    const unsigned short* __restrict__ act,   // [img][1764][64]
    const unsigned short* __restrict__ wp,    // packed fragments (scale folded)
    const float* __restrict__ bias,
    unsigned short* __restrict__ out)         // [img][441][64]
{
    int img = blockIdx.x / 7, tg = blockIdx.x % 7;
    int tid = threadIdx.x;
    __shared__ unsigned short lds[8 * 44 * DCH];   // 45,056 B

    const unsigned short* ab = act + (size_t)img * HW2 * DCH;
    int ybase = 6 * tg - 1;
    #pragma unroll
    for (int it = 0; it < 11; it++) {
        int idx = it * 256 + tid;
        int pix = idx >> 3, c = idx & 7;
        int r = pix / 44, xx = pix % 44;
        int y = ybase + r, x = xx - 1;
        bf16x8 v = (bf16x8)(short)0;
        if ((unsigned)y < (unsigned)H2 && (unsigned)x < (unsigned)H2)
            v = *(const bf16x8*)(ab + ((size_t)(y * H2 + x)) * DCH + (c << 3));
        *(bf16x8*)((char*)lds + swz(pix, c)) = v;
    }
    __syncthreads();

    int wv = tid >> 6, lane = tid & 63;
    int lc = lane & 15, kg = lane >> 4;
    int p_local = wv * 16 + lc;
    bool valid = p_local < 63;
    int pl = valid ? p_local : 62;
    int pyl = pl / 21, pxl = pl % 21;
    int pixc[4];
    #pragma unroll
    for (int sub = 0; sub < 4; sub++)
        pixc[sub] = (2 * pyl + (sub >> 1) + 1) * 44 + (2 * pxl + (sub & 1) + 1);

    f32x4 bini[4];
    #pragma unroll
    for (int mt = 0; mt < 4; mt++) {
        float4 bq = *reinterpret_cast<const float4*>(bias + (mt << 4) + (kg << 2));
        bini[mt] = (f32x4){bq.x, bq.y, bq.z, bq.w};
    }

    const bf16x8* wvv = (const bf16x8*)wp;
    f32x4 acc[4][4];
    #pragma unroll
    for (int i = 0; i < 4; i++)
        #pragma unroll
        for (int j = 0; j < 4; j++)
            acc[i][j] = bini[i];

    for (int s = 0; s < 9; s++) {
        int offs = (s / 3 - 1) * 44 + (s % 3 - 1);
        #pragma unroll
        for (int t = 0; t < 2; t++) {
            int fbase = ((s * 2 + t) * 4) << 6;
            bf16x8 a0 = wvv[fbase + lane];
            bf16x8 a1 = wvv[fbase + 64 + lane];
            bf16x8 a2 = wvv[fbase + 128 + lane];
            bf16x8 a3 = wvv[fbase + 192 + lane];
            int c = (t << 2) + kg;
            bf16x8 b[4];
            #pragma unroll
            for (int sub = 0; sub < 4; sub++) {
                int pix = pixc[sub] + offs;
                b[sub] = *(const bf16x8*)((const char*)lds + swz(pix, c));
            }
            #pragma unroll
            for (int sub = 0; sub < 4; sub++) {
                acc[0][sub] = __builtin_amdgcn_mfma_f32_16x16x32_bf16(a0, b[sub], acc[0][sub], 0, 0, 0);
                acc[1][sub] = __builtin_amdgcn_mfma_f32_16x16x32_bf16(a1, b[sub], acc[1][sub], 0, 0, 0);
                acc[2][sub] = __builtin_amdgcn_mfma_f32_16x16x32_bf16(a2, b[sub], acc[2][sub], 0, 0, 0);
                acc[3][sub] = __builtin_amdgcn_mfma_f32_16x16x32_bf16(a3, b[sub], acc[3][sub], 0, 0, 0);
            }
        }
    }

    if (!valid) return;
    int p = tg * 63 + p_local;
    #pragma unroll
    for (int mt = 0; mt < 4; mt++) {
        unsigned short uo[4];
        #pragma unroll
        for (int r = 0; r < 4; r++) {
            float m = fmaxf(fmaxf(acc[mt][0][r], acc[mt][1][r]),
                            fmaxf(acc[mt][2][r], acc[mt][3][r]));
            uo[r] = f2bf(fmaxf(m, 0.f));
        }
        uint2 pk;
        pk.x = (unsigned)uo[0] | ((unsigned)uo[1] << 16);
        pk.y = (unsigned)uo[2] | ((unsigned)uo[3] << 16);
        *reinterpret_cast<uint2*>(out + ((size_t)img * HW3 + p) * DCH + (mt << 4) + (kg << 2)) = pk;
    }
}

// ---------------- conv3/4: 64->64 MFMA, whole image in LDS, bias-init, ReLU ----------------
__global__ __launch_bounds__(256) void conv34_mfma(
    const unsigned short* __restrict__ act,   // [img][441][64]
    const unsigned short* __restrict__ wp,
    const float* __restrict__ bias,
    unsigned short* __restrict__ out)         // [img][441][64]
{
    int img = blockIdx.x;
    int tid = threadIdx.x;
    __shared__ unsigned short lds[529 * DCH];   // 67,712 B

    const unsigned short* ab = act + (size_t)img * HW3 * DCH;
    #pragma unroll
    for (int it = 0; it < 17; it++) {
        int idx = it * 256 + tid;
        if (idx < 529 * 8) {
            int pix = idx >> 3, c = idx & 7;
            int r = pix / 23, xx = pix % 23;
            int y = r - 1, x = xx - 1;
            bf16x8 v = (bf16x8)(short)0;
            if ((unsigned)y < (unsigned)H3 && (unsigned)x < (unsigned)H3)
                v = *(const bf16x8*)(ab + ((size_t)(y * H3 + x)) * DCH + (c << 3));
            *(bf16x8*)((char*)lds + swz(pix, c)) = v;
        }
    }
    __syncthreads();

    int wv = tid >> 6, lane = tid & 63;
    int lc = lane & 15, kg = lane >> 4;
    int pixBase[7];
    bool pv[7];
    #pragma unroll
    for (int i = 0; i < 7; i++) {
        int p = (wv * 7 + i) * 16 + lc;
        pv[i] = p < HW3;
        int pc = pv[i] ? p : HW3 - 1;
        pixBase[i] = (pc / 21) * 23 + (pc % 21);
    }

    f32x4 bini[4];
    #pragma unroll
    for (int mt = 0; mt < 4; mt++) {
        float4 bq = *reinterpret_cast<const float4*>(bias + (mt << 4) + (kg << 2));
        bini[mt] = (f32x4){bq.x, bq.y, bq.z, bq.w};
    }

    const bf16x8* wvv = (const bf16x8*)wp;
    f32x4 acc[7][4];
    #pragma unroll
    for (int i = 0; i < 7; i++)
        #pragma unroll
        for (int m = 0; m < 4; m++)
            acc[i][m] = bini[m];

    for (int s = 0; s < 9; s++) {
        int offs = (s / 3) * 23 + (s % 3);
        #pragma unroll
        for (int t = 0; t < 2; t++) {
            int fbase = ((s * 2 + t) * 4) << 6;
            bf16x8 a0 = wvv[fbase + lane];
            bf16x8 a1 = wvv[fbase + 64 + lane];
            bf16x8 a2 = wvv[fbase + 128 + lane];
            bf16x8 a3 = wvv[fbase + 192 + lane];
            int c = (t << 2) + kg;
            #pragma unroll
            for (int i = 0; i < 7; i++) {
                int pix = pixBase[i] + offs;
                bf16x8 bb = *(const bf16x8*)((const char*)lds + swz(pix, c));
                acc[i][0] = __builtin_amdgcn_mfma_f32_16x16x32_bf16(a0, bb, acc[i][0], 0, 0, 0);
                acc[i][1] = __builtin_amdgcn_mfma_f32_16x16x32_bf16(a1, bb, acc[i][1], 0, 0, 0);
                acc[i][2] = __builtin_amdgcn_mfma_f32_16x16x32_bf16(a2, bb, acc[i][2], 0, 0, 0);
                acc[i][3] = __builtin_amdgcn_mfma_f32_16x16x32_bf16(a3, bb, acc[i][3], 0, 0, 0);
            }
        }
    }

    #pragma unroll
    for (int mt = 0; mt < 4; mt++) {
        #pragma unroll
        for (int i = 0; i < 7; i++) {
            if (!pv[i]) continue;
            int p = (wv * 7 + i) * 16 + lc;
            unsigned short uo[4];
            #pragma unroll
            for (int r = 0; r < 4; r++)
                uo[r] = f2bf(fmaxf(acc[i][mt][r], 0.f));
            uint2 pk;
            pk.x = (unsigned)uo[0] | ((unsigned)uo[1] << 16);
            pk.y = (unsigned)uo[2] | ((unsigned)uo[3] << 16);
            *reinterpret_cast<uint2*>(out + ((size_t)img * HW3 + p) * DCH + (mt << 4) + (kg << 2)) = pk;
        }
    }
}

// ---------------- query L2-normalize: NHWC bf16 -> [img][hw][64] bf16 ----------------
__global__ __launch_bounds__(256) void q_norm(
    const unsigned short* __restrict__ feat, unsigned short* __restrict__ q_local)
{
    int idx = blockIdx.x * 256 + threadIdx.x;
    if (idx >= NQIMG * HW3) return;
    const bf16x8* f = (const bf16x8*)(feat + (size_t)idx * DCH);
    float v[DCH];
    float ss = 0.f;
    #pragma unroll
    for (int g = 0; g < 8; g++) {
        bf16x8 x = f[g];
        #pragma unroll
        for (int j = 0; j < 8; j++) {
            float vv = bf2f((unsigned short)x[j]);
            v[g * 8 + j] = vv;
            ss = fmaf(vv, vv, ss);
        }
    }
    float inv = 1.f / fmaxf(sqrtf(ss), EPS);
    bf16x8* o = (bf16x8*)(q_local + (size_t)idx * DCH);
    #pragma unroll
    for (int g = 0; g < 8; g++) {
        bf16x8 pk;
        #pragma unroll
        for (int j = 0; j < 8; j++) pk[j] = (short)f2bf(v[g * 8 + j] * inv);
        o[g] = pk;
    }
}

// ---------------- support: mean over shots + L2-norm -> [bc][448][64] bf16, zero tail ----------------
__global__ __launch_bounds__(256) void s_mean_norm(
    const unsigned short* __restrict__ feat, unsigned short* __restrict__ s_local)
{
    int idx = blockIdx.x * 256 + threadIdx.x;
    if (idx >= BDIM * WAY * SST) return;
    int hw = idx % SST;
    int bc = idx / SST;
    bf16x8* o = (bf16x8*)(s_local + (size_t)idx * DCH);
    if (hw >= HW3) {
        #pragma unroll
        for (int g = 0; g < 8; g++) o[g] = (bf16x8)(short)0;
        return;
    }
    int img0 = NQIMG + bc * SHOT;
    float v[DCH];
    #pragma unroll
    for (int d = 0; d < DCH; d++) v[d] = 0.f;
    for (int sh = 0; sh < SHOT; sh++) {
        const bf16x8* f = (const bf16x8*)(feat + ((size_t)(img0 + sh) * HW3 + hw) * DCH);
        #pragma unroll
        for (int g = 0; g < 8; g++) {
            bf16x8 x = f[g];
            #pragma unroll
            for (int j = 0; j < 8; j++)
                v[g * 8 + j] += bf2f((unsigned short)x[j]);
        }
    }
    float ss = 0.f;
    #pragma unroll
    for (int d = 0; d < DCH; d++) {
        v[d] *= (1.f / SHOT);
        ss = fmaf(v[d], v[d], ss);
    }
    float inv = 1.f / fmaxf(sqrtf(ss), EPS);
    #pragma unroll
    for (int g = 0; g < 8; g++) {
        bf16x8 pk;
        #pragma unroll
        for (int j = 0; j < 8; j++) pk[j] = (short)f2bf(v[g * 8 + j] * inv);
        o[g] = pk;
    }
}

// ---------------- similarity via MFMA, s read from L2, 2 n-tiles/iter + max3 ----------------
__global__ __launch_bounds__(256) void sim_mfma(
    const unsigned short* __restrict__ qloc,  // [150][441][64] bf16
    const unsigned short* __restrict__ sloc,  // [10][448][64] bf16 (tail zeroed)
    float* __restrict__ out)
{
    int blk = blockIdx.x;
    int imgq = blk / WAY, way = blk % WAY;
    int b = imgq / NQ;
    const unsigned short* qp = qloc + (size_t)imgq * HW3 * DCH;
    const unsigned short* sp = sloc + (size_t)(b * WAY + way) * SST * DCH;

    int tid = threadIdx.x;
    int wv = tid >> 6, lane = tid & 63;
    int lc = lane & 15, kg = lane >> 4;
    int mt0 = wv * 7;

    bf16x8 qa0[7], qa1[7];
    #pragma unroll
    for (int i = 0; i < 7; i++) {
        const unsigned short* qrow = qp + (size_t)((mt0 + i) * 16 + lc) * DCH + (kg << 3);
        qa0[i] = *(const bf16x8*)(qrow);
        qa1[i] = *(const bf16x8*)(qrow + 32);
    }
    f32x4 rmax[7];
    #pragma unroll
    for (int i = 0; i < 7; i++)
        rmax[i] = (f32x4){-1e30f, -1e30f, -1e30f, -1e30f};

    const f32x4 z4 = (f32x4){0.f, 0.f, 0.f, 0.f};
    const unsigned short* sbase = sp + (size_t)lc * DCH + (kg << 3);

    for (int t = 0; t < 13; t++) {
        const unsigned short* r0 = sbase + (size_t)(2 * t) * 16 * DCH;
        const unsigned short* r1 = r0 + 16 * DCH;
        bf16x8 sA0 = *(const bf16x8*)(r0);
        bf16x8 sA1 = *(const bf16x8*)(r0 + 32);
        bf16x8 sB0 = *(const bf16x8*)(r1);
        bf16x8 sB1 = *(const bf16x8*)(r1 + 32);
        #pragma unroll
        for (int i = 0; i < 7; i++) {
            f32x4 aA = __builtin_amdgcn_mfma_f32_16x16x32_bf16(qa0[i], sA0, z4, 0, 0, 0);
            aA = __builtin_amdgcn_mfma_f32_16x16x32_bf16(qa1[i], sA1, aA, 0, 0, 0);
            f32x4 aB = __builtin_amdgcn_mfma_f32_16x16x32_bf16(qa0[i], sB0, z4, 0, 0, 0);
            aB = __builtin_amdgcn_mfma_f32_16x16x32_bf16(qa1[i], sB1, aB, 0, 0, 0);
            #pragma unroll
            for (int r = 0; r < 4; r++)
                rmax[i][r] = fmaxf(rmax[i][r], fmaxf(aA[r], aB[r]));   // v_max3
        }
    }
    {   // nt 26 (all cols valid) + nt 27 (cols 432..447, mask >=441)
        const unsigned short* r0 = sbase + (size_t)26 * 16 * DCH;
        const unsigned short* r1 = r0 + 16 * DCH;
        bf16x8 sA0 = *(const bf16x8*)(r0);
        bf16x8 sA1 = *(const bf16x8*)(r0 + 32);
        bf16x8 sB0 = *(const bf16x8*)(r1);
        bf16x8 sB1 = *(const bf16x8*)(r1 + 32);
        bool nval = (432 + lc) < HW3;
        #pragma unroll
        for (int i = 0; i < 7; i++) {
            f32x4 aA = __builtin_amdgcn_mfma_f32_16x16x32_bf16(qa0[i], sA0, z4, 0, 0, 0);
            aA = __builtin_amdgcn_mfma_f32_16x16x32_bf16(qa1[i], sA1, aA, 0, 0, 0);
            f32x4 aB = __builtin_amdgcn_mfma_f32_16x16x32_bf16(qa0[i], sB0, z4, 0, 0, 0);
            aB = __builtin_amdgcn_mfma_f32_16x16x32_bf16(qa1[i], sB1, aB, 0, 0, 0);
            #pragma unroll
            for (int r = 0; r < 4; r++)
                rmax[i][r] = fmaxf(rmax[i][r], fmaxf(aA[r], nval ? aB[r] : -1e30f));
        }
    }

    float msum = 0.f;
    #pragma unroll
    for (int i = 0; i < 7; i++) {
        #pragma unroll
        for (int r = 0; r < 4; r++) {
            float v = rmax[i][r];
            v = fmaxf(v, __shfl_xor(v, 1, 64));
            v = fmaxf(v, __shfl_xor(v, 2, 64));
            v = fmaxf(v, __shfl_xor(v, 4, 64));
            v = fmaxf(v, __shfl_xor(v, 8, 64));
            int m = (mt0 + i) * 16 + (kg << 2) + r;
            if (lc == 0 && m < HW3) msum += v;
        }
    }
    #pragma unroll
    for (int off = 32; off > 0; off >>= 1)
        msum += __shfl_xor(msum, off, 64);
    __shared__ float red[4];
    if (lane == 0) red[wv] = msum;
    __syncthreads();
    if (tid == 0)
        out[(size_t)imgq * WAY + way] = (red[0] + red[1] + red[2] + red[3]) * (1.f / HW3);
}

extern "C" void kernel_launch(void* const* d_in, const int* in_sizes, int n_in,
                              void* d_out, int out_size, void* d_ws, size_t ws_size,
                              hipStream_t stream) {
    const float* query   = (const float*)d_in[0];
    const float* support = (const float*)d_in[1];
    const float* w1 = (const float*)d_in[2];
    const float* w2 = (const float*)d_in[3];
    const float* w3 = (const float*)d_in[4];
    const float* w4 = (const float*)d_in[5];
    const float* s1 = (const float*)d_in[6];
    const float* b1 = (const float*)d_in[7];
    const float* s2 = (const float*)d_in[8];
    const float* b2 = (const float*)d_in[9];
    const float* s3 = (const float*)d_in[10];
    const float* b3 = (const float*)d_in[11];
    const float* s4 = (const float*)d_in[12];
    const float* b4 = (const float*)d_in[13];
    float* out = (float*)d_out;

    char* ws = (char*)d_ws;
    unsigned short* A1  = (unsigned short*)(ws);              // 200*1764*64 bf16 = 45,158,400 B
    unsigned short* A2  = (unsigned short*)(ws + 45158400);   // 200*441*64 bf16 = 11,289,600 B
    unsigned short* A3  = (unsigned short*)(ws + 56448000);
    unsigned short* A4  = (unsigned short*)(ws + 67737600);
    unsigned short* QL  = (unsigned short*)(ws + 79027200);   // 150*441*64 bf16 = 8,467,200 B
    unsigned short* SL  = (unsigned short*)(ws + 87494400);   // 10*448*64 bf16 = 573,440 B
    unsigned short* WP2 = (unsigned short*)(ws + 88067840);   // 36864 bf16 = 73,728 B
    unsigned short* WP3 = (unsigned short*)(ws + 88141568);
    unsigned short* WP4 = (unsigned short*)(ws + 88215296);
    unsigned short* WP1 = (unsigned short*)(ws + 88289024);   // 2048 bf16 = 4,096 B
    unsigned short* PAD = (unsigned short*)(ws + 88293120);   // 200*3*7396 bf16 = 8,875,200 B

    pad_in<<<(NIMG * 3 * PSZ + 255) / 256, 256, 0, stream>>>(query, support, PAD);
    pack_w1<<<8, 256, 0, stream>>>(w1, s1, WP1);
    pack_w<<<(3 * 36864 + 255) / 256, 256, 0, stream>>>(w2, s2, w3, s3, w4, s4, WP2, WP3, WP4);

    conv1_mfma<<<NIMG * 7, 256, 0, stream>>>(PAD, WP1, b1, A1);
    conv2_mfma_pool<<<NIMG * 7, 256, 0, stream>>>(A1, WP2, b2, A2);
    conv34_mfma<<<NIMG, 256, 0, stream>>>(A2, WP3, b3, A3);
    conv34_mfma<<<NIMG, 256, 0, stream>>>(A3, WP4, b4, A4);

    q_norm<<<(NQIMG * HW3 + 255) / 256, 256, 0, stream>>>(A4, QL);
    s_mean_norm<<<(BDIM * WAY * SST + 255) / 256, 256, 0, stream>>>(A4, SL);

    sim_mfma<<<NQIMG * WAY, 256, 0, stream>>>(QL, SL, out);
}

// Round 10
// 136.728 us; speedup vs baseline: 41.3005x; 1.1231x over previous
//
#include <hip/hip_runtime.h>

#define EPS 1e-12f

// Problem constants
#define NIMG   200      // 150 query + 50 support
#define NQIMG  150
#define BDIM   2
#define NQ     75
#define WAY    5
#define SHOT   5
#define DCH    64
#define H1     84
#define H2     42
#define H3     21
#define HW2    1764     // 42*42
#define HW3    441      // 21*21
#define PH     86       // padded 84+2
#define PSZ    7396     // 86*86
#define SST    448      // padded support row stride

// prep kernel grid sections
#define PAD_BLKS  17335     // ceil(200*3*7396 / 256)
#define W1_BLKS   8
#define W_BLKS    432       // 3*36864/256

typedef __attribute__((ext_vector_type(8))) short bf16x8;
typedef __attribute__((ext_vector_type(4))) float f32x4;

__device__ __forceinline__ unsigned short f2bf(float f) {
    unsigned u = __float_as_uint(f);
    u += 0x7fffu + ((u >> 16) & 1u);
    return (unsigned short)(u >> 16);
}
__device__ __forceinline__ float bf2f(unsigned short h) {
    return __uint_as_float(((unsigned)h) << 16);
}
// LDS pixel-line swizzle: 128B line per pixel, chunk ^= (pix>>1)&7
__device__ __forceinline__ int swz(int pix, int c) {
    return pix * 128 + ((c ^ ((pix >> 1) & 7)) << 4);
}

// ---------------- prep: pad input + pack all weights (fused) ----------------
__global__ __launch_bounds__(256) void prep(
    const float* __restrict__ qin, const float* __restrict__ sin_,
    const float* __restrict__ w1, const float* __restrict__ s1,
    const float* __restrict__ w2, const float* __restrict__ s2,
    const float* __restrict__ w3, const float* __restrict__ s3,
    const float* __restrict__ w4, const float* __restrict__ s4,
    unsigned short* __restrict__ pad, unsigned short* __restrict__ p1,
    unsigned short* __restrict__ p2, unsigned short* __restrict__ p3,
    unsigned short* __restrict__ p4)
{
    int blk = blockIdx.x;
    if (blk < PAD_BLKS) {
        int idx = blk * 256 + threadIdx.x;
        if (idx >= NIMG * 3 * PSZ) return;
        int img = idx / (3 * PSZ);
        int rem = idx % (3 * PSZ);
        int ci = rem / PSZ, p = rem % PSZ;
        int iy = p / PH, ix = p % PH;
        float v = 0.f;
        if (iy >= 1 && iy <= H1 && ix >= 1 && ix <= H1) {
            const float* src = (img < NQIMG) ? (qin + (size_t)img * 3 * H1 * H1)
                                             : (sin_ + (size_t)(img - NQIMG) * 3 * H1 * H1);
            v = src[(size_t)ci * H1 * H1 + (iy - 1) * H1 + (ix - 1)];
        }
        pad[idx] = f2bf(v);
    } else if (blk < PAD_BLKS + W1_BLKS) {
        int idx = (blk - PAD_BLKS) * 256 + threadIdx.x;
        int j = idx & 7, lane = (idx >> 3) & 63, mt = idx >> 9;
        int co = (mt << 4) + (lane & 15);
        int k = ((lane >> 4) << 3) + j;
        float v = 0.f;
        if (k < 27) {
            int ci = k / 9, s = k % 9;
            v = w1[(co * 3 + ci) * 9 + s] * s1[co];
        }
        p1[idx] = f2bf(v);
    } else {
        int idx = (blk - PAD_BLKS - W1_BLKS) * 256 + threadIdx.x;
        int which = idx / 36864;
        int r = idx % 36864;
        int j = r & 7, lane = (r >> 3) & 63, mt = (r >> 9) & 3, t = (r >> 11) & 1, s = r >> 12;
        int co = (mt << 4) + (lane & 15);
        int ci = (t << 5) + ((lane >> 4) << 3) + j;
        const float* w = (which == 0) ? w2 : (which == 1) ? w3 : w4;
        const float* sc = (which == 0) ? s2 : (which == 1) ? s3 : s4;
        unsigned short* p = (which == 0) ? p2 : (which == 1) ? p3 : p4;
        p[r] = f2bf(w[(co * 64 + ci) * 9 + s] * sc[co]);
    }
}

// ---------------- conv1: LDS strip stage + ds-gather im2col, reg-max pool ----------------
__global__ __launch_bounds__(256) void conv1_mfma(
    const unsigned short* __restrict__ pad,   // [img][3][86][86] bf16
    const unsigned short* __restrict__ wp1,
    const float* __restrict__ bias,
    unsigned short* __restrict__ out)         // [img][1764][64] bf16
{
    int img = blockIdx.x / 7, seg = blockIdx.x % 7;
    int tid = threadIdx.x;
    __shared__ unsigned short strip[3 * 14 * 86];   // 7224 B

    const unsigned* srcd = (const unsigned*)pad;
    size_t ibase = (size_t)img * 3 * (PSZ / 2);
    #pragma unroll
    for (int it = 0; it < 8; it++) {
        int i = it * 256 + tid;
        if (i < 1806) {
            int ci = i / 602, r = i % 602;
            ((unsigned*)strip)[i] = srcd[ibase + ci * (PSZ / 2) + 516 * seg + r];
        }
    }
    __syncthreads();

    int wv = tid >> 6, lane = tid & 63;
    int lc = lane & 15, kg = lane >> 4;

    const bf16x8* wvv = (const bf16x8*)wp1;
    bf16x8 a0 = wvv[lane];
    bf16x8 a1 = wvv[64 + lane];
    bf16x8 a2 = wvv[128 + lane];
    bf16x8 a3 = wvv[192 + lane];

    int off[8];
    #pragma unroll
    for (int j = 0; j < 8; j++) {
        int k = (kg << 3) + j;
        int kk = k < 27 ? k : 0;
        int ci = kk / 9, s = kk % 9;
        off[j] = ci * 1204 + (s / 3) * 86 + (s % 3);
    }

    f32x4 bini[4];
    #pragma unroll
    for (int mt = 0; mt < 4; mt++) {
        float4 bq = *reinterpret_cast<const float4*>(bias + (mt << 4) + (kg << 2));
        bini[mt] = (f32x4){bq.x, bq.y, bq.z, bq.w};
    }

    #pragma unroll
    for (int it = 0; it < 4; it++) {
        int pl = it * 64 + wv * 16 + lc;
        bool valid = pl < 252;
        int plc = valid ? pl : 251;
        int pyl = plc / 42, pxl = plc % 42;
        int base = pyl * 172 + 2 * pxl;

        bf16x8 b[4];
        #pragma unroll
        for (int j = 0; j < 8; j++) {
            int a = base + off[j];
            b[0][j] = (short)strip[a];
            b[1][j] = (short)strip[a + 1];
            b[2][j] = (short)strip[a + 86];
            b[3][j] = (short)strip[a + 87];
        }

        f32x4 acc[4][4];
        #pragma unroll
        for (int mt = 0; mt < 4; mt++)
            #pragma unroll
            for (int sub = 0; sub < 4; sub++)
                acc[mt][sub] = bini[mt];
        #pragma unroll
        for (int sub = 0; sub < 4; sub++) {
            acc[0][sub] = __builtin_amdgcn_mfma_f32_16x16x32_bf16(a0, b[sub], acc[0][sub], 0, 0, 0);
            acc[1][sub] = __builtin_amdgcn_mfma_f32_16x16x32_bf16(a1, b[sub], acc[1][sub], 0, 0, 0);
            acc[2][sub] = __builtin_amdgcn_mfma_f32_16x16x32_bf16(a2, b[sub], acc[2][sub], 0, 0, 0);
            acc[3][sub] = __builtin_amdgcn_mfma_f32_16x16x32_bf16(a3, b[sub], acc[3][sub], 0, 0, 0);
        }

        if (valid) {
            int p = seg * 252 + pl;
            #pragma unroll
            for (int mt = 0; mt < 4; mt++) {
                unsigned short uo[4];
                #pragma unroll
                for (int r = 0; r < 4; r++) {
                    float m = fmaxf(fmaxf(acc[mt][0][r], acc[mt][1][r]),
                                    fmaxf(acc[mt][2][r], acc[mt][3][r]));
                    uo[r] = f2bf(fmaxf(m, 0.f));
                }
                uint2 pk;
                pk.x = (unsigned)uo[0] | ((unsigned)uo[1] << 16);
                pk.y = (unsigned)uo[2] | ((unsigned)uo[3] << 16);
                *reinterpret_cast<uint2*>(out + ((size_t)img * HW2 + p) * DCH + (mt << 4) + (kg << 2)) = pk;
            }
        }
    }
}

// ---------------- conv2: 64->64 MFMA + LDS strip staging, bias-init, pool, ReLU ----------------
__global__ __launch_bounds__(256) void conv2_mfma_pool(
    const unsigned short* __restrict__ act,   // [img][1764][64]
    const unsigned short* __restrict__ wp,
    const float* __restrict__ bias,
    unsigned short* __restrict__ out)         // [img][441][64]
{
    int img = blockIdx.x / 7, tg = blockIdx.x % 7;
    int tid = threadIdx.x;
    __shared__ unsigned short lds[8 * 44 * DCH];   // 45,056 B

    const unsigned short* ab = act + (size_t)img * HW2 * DCH;
    int ybase = 6 * tg - 1;
    #pragma unroll
    for (int it = 0; it < 11; it++) {
        int idx = it * 256 + tid;
        int pix = idx >> 3, c = idx & 7;
        int r = pix / 44, xx = pix % 44;
        int y = ybase + r, x = xx - 1;
        bf16x8 v = (bf16x8)(short)0;
        if ((unsigned)y < (unsigned)H2 && (unsigned)x < (unsigned)H2)
            v = *(const bf16x8*)(ab + ((size_t)(y * H2 + x)) * DCH + (c << 3));
        *(bf16x8*)((char*)lds + swz(pix, c)) = v;
    }
    __syncthreads();

    int wv = tid >> 6, lane = tid & 63;
    int lc = lane & 15, kg = lane >> 4;
    int p_local = wv * 16 + lc;
    bool valid = p_local < 63;
    int pl = valid ? p_local : 62;
    int pyl = pl / 21, pxl = pl % 21;
    int pixc[4];
    #pragma unroll
    for (int sub = 0; sub < 4; sub++)
        pixc[sub] = (2 * pyl + (sub >> 1) + 1) * 44 + (2 * pxl + (sub & 1) + 1);

    f32x4 bini[4];
    #pragma unroll
    for (int mt = 0; mt < 4; mt++) {
        float4 bq = *reinterpret_cast<const float4*>(bias + (mt << 4) + (kg << 2));
        bini[mt] = (f32x4){bq.x, bq.y, bq.z, bq.w};
    }

    const bf16x8* wvv = (const bf16x8*)wp;
    f32x4 acc[4][4];
    #pragma unroll
    for (int i = 0; i < 4; i++)
        #pragma unroll
        for (int j = 0; j < 4; j++)
            acc[i][j] = bini[i];

    for (int s = 0; s < 9; s++) {
        int offs = (s / 3 - 1) * 44 + (s % 3 - 1);
        #pragma unroll
        for (int t = 0; t < 2; t++) {
            int fbase = ((s * 2 + t) * 4) << 6;
            bf16x8 a0 = wvv[fbase + lane];
            bf16x8 a1 = wvv[fbase + 64 + lane];
            bf16x8 a2 = wvv[fbase + 128 + lane];
            bf16x8 a3 = wvv[fbase + 192 + lane];
            int c = (t << 2) + kg;
            bf16x8 b[4];
            #pragma unroll
            for (int sub = 0; sub < 4; sub++) {
                int pix = pixc[sub] + offs;
                b[sub] = *(const bf16x8*)((const char*)lds + swz(pix, c));
            }
            #pragma unroll
            for (int sub = 0; sub < 4; sub++) {
                acc[0][sub] = __builtin_amdgcn_mfma_f32_16x16x32_bf16(a0, b[sub], acc[0][sub], 0, 0, 0);
                acc[1][sub] = __builtin_amdgcn_mfma_f32_16x16x32_bf16(a1, b[sub], acc[1][sub], 0, 0, 0);
                acc[2][sub] = __builtin_amdgcn_mfma_f32_16x16x32_bf16(a2, b[sub], acc[2][sub], 0, 0, 0);
                acc[3][sub] = __builtin_amdgcn_mfma_f32_16x16x32_bf16(a3, b[sub], acc[3][sub], 0, 0, 0);
            }
        }
    }

    if (!valid) return;
    int p = tg * 63 + p_local;
    #pragma unroll
    for (int mt = 0; mt < 4; mt++) {
        unsigned short uo[4];
        #pragma unroll
        for (int r = 0; r < 4; r++) {
            float m = fmaxf(fmaxf(acc[mt][0][r], acc[mt][1][r]),
                            fmaxf(acc[mt][2][r], acc[mt][3][r]));
            uo[r] = f2bf(fmaxf(m, 0.f));
        }
        uint2 pk;
        pk.x = (unsigned)uo[0] | ((unsigned)uo[1] << 16);
        pk.y = (unsigned)uo[2] | ((unsigned)uo[3] << 16);
        *reinterpret_cast<uint2*>(out + ((size_t)img * HW3 + p) * DCH + (mt << 4) + (kg << 2)) = pk;
    }
}

// ---------------- conv3+conv4 fused (+q_norm for query imgs) ----------------
// grid NIMG, block 256. One whole image per block. LDS (67.7KB) holds conv2-out
// padded image; conv3 output is written back into the SAME LDS (interior; halo
// zeroed), then conv4 runs from LDS. Query imgs: epilogue L2-normalizes in-register
// (ssq reduced across the 4 kg-lanes via shfl_xor 16/32) and writes QL; support
// imgs write raw relu to A4 for s_mean_norm.
__global__ __launch_bounds__(256) void conv34_fused(
    const unsigned short* __restrict__ act,   // [img][441][64] (conv2 out)
    const unsigned short* __restrict__ wp3, const unsigned short* __restrict__ wp4,
    const float* __restrict__ b3, const float* __restrict__ b4,
    unsigned short* __restrict__ a4out,       // support: [img][441][64]
    unsigned short* __restrict__ qlout)       // query:   [img][441][64] normalized
{
    int img = blockIdx.x;
    int tid = threadIdx.x;
    __shared__ unsigned short lds[529 * DCH];   // 67,712 B

    const unsigned short* ab = act + (size_t)img * HW3 * DCH;
    #pragma unroll
    for (int it = 0; it < 17; it++) {
        int idx = it * 256 + tid;
        if (idx < 529 * 8) {
            int pix = idx >> 3, c = idx & 7;
            int r = pix / 23, xx = pix % 23;
            int y = r - 1, x = xx - 1;
            bf16x8 v = (bf16x8)(short)0;
            if ((unsigned)y < (unsigned)H3 && (unsigned)x < (unsigned)H3)
                v = *(const bf16x8*)(ab + ((size_t)(y * H3 + x)) * DCH + (c << 3));
            *(bf16x8*)((char*)lds + swz(pix, c)) = v;
        }
    }
    __syncthreads();

    int wv = tid >> 6, lane = tid & 63;
    int lc = lane & 15, kg = lane >> 4;
    int pixBase[7];
    bool pv[7];
    #pragma unroll
    for (int i = 0; i < 7; i++) {
        int p = (wv * 7 + i) * 16 + lc;
        pv[i] = p < HW3;
        int pc = pv[i] ? p : HW3 - 1;
        pixBase[i] = (pc / 21) * 23 + (pc % 21);
    }

    // ---- conv3 ----
    f32x4 bini[4];
    #pragma unroll
    for (int mt = 0; mt < 4; mt++) {
        float4 bq = *reinterpret_cast<const float4*>(b3 + (mt << 4) + (kg << 2));
        bini[mt] = (f32x4){bq.x, bq.y, bq.z, bq.w};
    }

    f32x4 acc[7][4];
    #pragma unroll
    for (int i = 0; i < 7; i++)
        #pragma unroll
        for (int m = 0; m < 4; m++)
            acc[i][m] = bini[m];

    const bf16x8* wv3 = (const bf16x8*)wp3;
    for (int s = 0; s < 9; s++) {
        int offs = (s / 3) * 23 + (s % 3);
        #pragma unroll
        for (int t = 0; t < 2; t++) {
            int fbase = ((s * 2 + t) * 4) << 6;
            bf16x8 a0 = wv3[fbase + lane];
            bf16x8 a1 = wv3[fbase + 64 + lane];
            bf16x8 a2 = wv3[fbase + 128 + lane];
            bf16x8 a3 = wv3[fbase + 192 + lane];
            int c = (t << 2) + kg;
            #pragma unroll
            for (int i = 0; i < 7; i++) {
                int pix = pixBase[i] + offs;
                bf16x8 bb = *(const bf16x8*)((const char*)lds + swz(pix, c));
                acc[i][0] = __builtin_amdgcn_mfma_f32_16x16x32_bf16(a0, bb, acc[i][0], 0, 0, 0);
                acc[i][1] = __builtin_amdgcn_mfma_f32_16x16x32_bf16(a1, bb, acc[i][1], 0, 0, 0);
                acc[i][2] = __builtin_amdgcn_mfma_f32_16x16x32_bf16(a2, bb, acc[i][2], 0, 0, 0);
                acc[i][3] = __builtin_amdgcn_mfma_f32_16x16x32_bf16(a3, bb, acc[i][3], 0, 0, 0);
            }
        }
    }

    __syncthreads();   // all conv3 LDS reads done before overwrite

    // write conv3 relu output into LDS interior (each lane: 8B piece per mt)
    #pragma unroll
    for (int i = 0; i < 7; i++) {
        if (!pv[i]) continue;
        int pix = pixBase[i] + 24;   // interior: (py+1)*23 + (px+1)
        #pragma unroll
        for (int mt = 0; mt < 4; mt++) {
            unsigned short uo[4];
            #pragma unroll
            for (int r = 0; r < 4; r++)
                uo[r] = f2bf(fmaxf(acc[i][mt][r], 0.f));
            uint2 pk;
            pk.x = (unsigned)uo[0] | ((unsigned)uo[1] << 16);
            pk.y = (unsigned)uo[2] | ((unsigned)uo[3] << 16);
            int c = (mt << 1) + (kg >> 1);
            *(uint2*)((char*)lds + swz(pix, c) + ((kg & 1) << 3)) = pk;
        }
    }
    // zero the 88 halo lines (704 16B chunks)
    #pragma unroll
    for (int it = 0; it < 3; it++) {
        int idx = it * 256 + tid;
        if (idx < 704) {
            int j = idx >> 3, c = idx & 7;
            int pix;
            if (j < 23)      pix = j;
            else if (j < 46) pix = 506 + (j - 23);
            else { int k = j - 46; pix = (1 + (k >> 1)) * 23 + (k & 1) * 22; }
            *(bf16x8*)((char*)lds + swz(pix, c)) = (bf16x8)(short)0;
        }
    }
    __syncthreads();

    // ---- conv4 ----
    #pragma unroll
    for (int mt = 0; mt < 4; mt++) {
        float4 bq = *reinterpret_cast<const float4*>(b4 + (mt << 4) + (kg << 2));
        bini[mt] = (f32x4){bq.x, bq.y, bq.z, bq.w};
    }
    #pragma unroll
    for (int i = 0; i < 7; i++)
        #pragma unroll
        for (int m = 0; m < 4; m++)
            acc[i][m] = bini[m];

    const bf16x8* wv4 = (const bf16x8*)wp4;
    for (int s = 0; s < 9; s++) {
        int offs = (s / 3) * 23 + (s % 3);
        #pragma unroll
        for (int t = 0; t < 2; t++) {
            int fbase = ((s * 2 + t) * 4) << 6;
            bf16x8 a0 = wv4[fbase + lane];
            bf16x8 a1 = wv4[fbase + 64 + lane];
            bf16x8 a2 = wv4[fbase + 128 + lane];
            bf16x8 a3 = wv4[fbase + 192 + lane];
            int c = (t << 2) + kg;
            #pragma unroll
            for (int i = 0; i < 7; i++) {
                int pix = pixBase[i] + offs;
                bf16x8 bb = *(const bf16x8*)((const char*)lds + swz(pix, c));
                acc[i][0] = __builtin_amdgcn_mfma_f32_16x16x32_bf16(a0, bb, acc[i][0], 0, 0, 0);
                acc[i][1] = __builtin_amdgcn_mfma_f32_16x16x32_bf16(a1, bb, acc[i][1], 0, 0, 0);
                acc[i][2] = __builtin_amdgcn_mfma_f32_16x16x32_bf16(a2, bb, acc[i][2], 0, 0, 0);
                acc[i][3] = __builtin_amdgcn_mfma_f32_16x16x32_bf16(a3, bb, acc[i][3], 0, 0, 0);
            }
        }
    }

    // ---- epilogue ----
    if (img < NQIMG) {
        // relu + in-register L2-norm across the 4 kg-lanes, write normalized QL
        #pragma unroll
        for (int i = 0; i < 7; i++) {
            float v[4][4];
            float ssq = 0.f;
            #pragma unroll
            for (int mt = 0; mt < 4; mt++)
                #pragma unroll
                for (int r = 0; r < 4; r++) {
                    float x = fmaxf(acc[i][mt][r], 0.f);
                    v[mt][r] = x;
                    ssq = fmaf(x, x, ssq);
                }
            ssq += __shfl_xor(ssq, 16, 64);
            ssq += __shfl_xor(ssq, 32, 64);
            float inv = 1.f / fmaxf(sqrtf(ssq), EPS);
            if (!pv[i]) continue;
            int p = (wv * 7 + i) * 16 + lc;
            #pragma unroll
            for (int mt = 0; mt < 4; mt++) {
                unsigned short uo[4];
                #pragma unroll
                for (int r = 0; r < 4; r++)
                    uo[r] = f2bf(v[mt][r] * inv);
                uint2 pk;
                pk.x = (unsigned)uo[0] | ((unsigned)uo[1] << 16);
                pk.y = (unsigned)uo[2] | ((unsigned)uo[3] << 16);
                *reinterpret_cast<uint2*>(qlout + ((size_t)img * HW3 + p) * DCH + (mt << 4) + (kg << 2)) = pk;
            }
        }
    } else {
        #pragma unroll
        for (int mt = 0; mt < 4; mt++) {
            #pragma unroll
            for (int i = 0; i < 7; i++) {
                if (!pv[i]) continue;
                int p = (wv * 7 + i) * 16 + lc;
                unsigned short uo[4];
                #pragma unroll
                for (int r = 0; r < 4; r++)
                    uo[r] = f2bf(fmaxf(acc[i][mt][r], 0.f));
                uint2 pk;
                pk.x = (unsigned)uo[0] | ((unsigned)uo[1] << 16);
                pk.y = (unsigned)uo[2] | ((unsigned)uo[3] << 16);
                *reinterpret_cast<uint2*>(a4out + ((size_t)img * HW3 + p) * DCH + (mt << 4) + (kg << 2)) = pk;
            }
        }
    }
}

// ---------------- support: mean over shots + L2-norm -> [bc][448][64] bf16, zero tail ----------------
__global__ __launch_bounds__(256) void s_mean_norm(
    const unsigned short* __restrict__ feat, unsigned short* __restrict__ s_local)
{
    int idx = blockIdx.x * 256 + threadIdx.x;
    if (idx >= BDIM * WAY * SST) return;
    int hw = idx % SST;
    int bc = idx / SST;
    bf16x8* o = (bf16x8*)(s_local + (size_t)idx * DCH);
    if (hw >= HW3) {
        #pragma unroll
        for (int g = 0; g < 8; g++) o[g] = (bf16x8)(short)0;
        return;
    }
    int img0 = NQIMG + bc * SHOT;
    float v[DCH];
    #pragma unroll
    for (int d = 0; d < DCH; d++) v[d] = 0.f;
    for (int sh = 0; sh < SHOT; sh++) {
        const bf16x8* f = (const bf16x8*)(feat + ((size_t)(img0 + sh) * HW3 + hw) * DCH);
        #pragma unroll
        for (int g = 0; g < 8; g++) {
            bf16x8 x = f[g];
            #pragma unroll
            for (int j = 0; j < 8; j++)
                v[g * 8 + j] += bf2f((unsigned short)x[j]);
        }
    }
    float ss = 0.f;
    #pragma unroll
    for (int d = 0; d < DCH; d++) {
        v[d] *= (1.f / SHOT);
        ss = fmaf(v[d], v[d], ss);
    }
    float inv = 1.f / fmaxf(sqrtf(ss), EPS);
    #pragma unroll
    for (int g = 0; g < 8; g++) {
        bf16x8 pk;
        #pragma unroll
        for (int j = 0; j < 8; j++) pk[j] = (short)f2bf(v[g * 8 + j] * inv);
        o[g] = pk;
    }
}

// ---------------- similarity via MFMA, s read from L2, 2 n-tiles/iter + max3 ----------------
__global__ __launch_bounds__(256) void sim_mfma(
    const unsigned short* __restrict__ qloc,  // [150][441][64] bf16
    const unsigned short* __restrict__ sloc,  // [10][448][64] bf16 (tail zeroed)
    float* __restrict__ out)
{
    int blk = blockIdx.x;
    int imgq = blk / WAY, way = blk % WAY;
    int b = imgq / NQ;
    const unsigned short* qp = qloc + (size_t)imgq * HW3 * DCH;
    const unsigned short* sp = sloc + (size_t)(b * WAY + way) * SST * DCH;

    int tid = threadIdx.x;
    int wv = tid >> 6, lane = tid & 63;
    int lc = lane & 15, kg = lane >> 4;
    int mt0 = wv * 7;

    bf16x8 qa0[7], qa1[7];
    #pragma unroll
    for (int i = 0; i < 7; i++) {
        const unsigned short* qrow = qp + (size_t)((mt0 + i) * 16 + lc) * DCH + (kg << 3);
        qa0[i] = *(const bf16x8*)(qrow);
        qa1[i] = *(const bf16x8*)(qrow + 32);
    }
    f32x4 rmax[7];
    #pragma unroll
    for (int i = 0; i < 7; i++)
        rmax[i] = (f32x4){-1e30f, -1e30f, -1e30f, -1e30f};

    const f32x4 z4 = (f32x4){0.f, 0.f, 0.f, 0.f};
    const unsigned short* sbase = sp + (size_t)lc * DCH + (kg << 3);

    for (int t = 0; t < 13; t++) {
        const unsigned short* r0 = sbase + (size_t)(2 * t) * 16 * DCH;
        const unsigned short* r1 = r0 + 16 * DCH;
        bf16x8 sA0 = *(const bf16x8*)(r0);
        bf16x8 sA1 = *(const bf16x8*)(r0 + 32);
        bf16x8 sB0 = *(const bf16x8*)(r1);
        bf16x8 sB1 = *(const bf16x8*)(r1 + 32);
        #pragma unroll
        for (int i = 0; i < 7; i++) {
            f32x4 aA = __builtin_amdgcn_mfma_f32_16x16x32_bf16(qa0[i], sA0, z4, 0, 0, 0);
            aA = __builtin_amdgcn_mfma_f32_16x16x32_bf16(qa1[i], sA1, aA, 0, 0, 0);
            f32x4 aB = __builtin_amdgcn_mfma_f32_16x16x32_bf16(qa0[i], sB0, z4, 0, 0, 0);
            aB = __builtin_amdgcn_mfma_f32_16x16x32_bf16(qa1[i], sB1, aB, 0, 0, 0);
            #pragma unroll
            for (int r = 0; r < 4; r++)
                rmax[i][r] = fmaxf(rmax[i][r], fmaxf(aA[r], aB[r]));   // v_max3
        }
    }
    {   // nt 26 (all cols valid) + nt 27 (cols 432..447, mask >=441)
        const unsigned short* r0 = sbase + (size_t)26 * 16 * DCH;
        const unsigned short* r1 = r0 + 16 * DCH;
        bf16x8 sA0 = *(const bf16x8*)(r0);
        bf16x8 sA1 = *(const bf16x8*)(r0 + 32);
        bf16x8 sB0 = *(const bf16x8*)(r1);
        bf16x8 sB1 = *(const bf16x8*)(r1 + 32);
        bool nval = (432 + lc) < HW3;
        #pragma unroll
        for (int i = 0; i < 7; i++) {
            f32x4 aA = __builtin_amdgcn_mfma_f32_16x16x32_bf16(qa0[i], sA0, z4, 0, 0, 0);
            aA = __builtin_amdgcn_mfma_f32_16x16x32_bf16(qa1[i], sA1, aA, 0, 0, 0);
            f32x4 aB = __builtin_amdgcn_mfma_f32_16x16x32_bf16(qa0[i], sB0, z4, 0, 0, 0);
            aB = __builtin_amdgcn_mfma_f32_16x16x32_bf16(qa1[i], sB1, aB, 0, 0, 0);
            #pragma unroll
            for (int r = 0; r < 4; r++)
                rmax[i][r] = fmaxf(rmax[i][r], fmaxf(aA[r], nval ? aB[r] : -1e30f));
        }
    }

    float msum = 0.f;
    #pragma unroll
    for (int i = 0; i < 7; i++) {
        #pragma unroll
        for (int r = 0; r < 4; r++) {
            float v = rmax[i][r];
            v = fmaxf(v, __shfl_xor(v, 1, 64));
            v = fmaxf(v, __shfl_xor(v, 2, 64));
            v = fmaxf(v, __shfl_xor(v, 4, 64));
            v = fmaxf(v, __shfl_xor(v, 8, 64));
            int m = (mt0 + i) * 16 + (kg << 2) + r;
            if (lc == 0 && m < HW3) msum += v;
        }
    }
    #pragma unroll
    for (int off = 32; off > 0; off >>= 1)
        msum += __shfl_xor(msum, off, 64);
    __shared__ float red[4];
    if (lane == 0) red[wv] = msum;
    __syncthreads();
    if (tid == 0)
        out[(size_t)imgq * WAY + way] = (red[0] + red[1] + red[2] + red[3]) * (1.f / HW3);
}

extern "C" void kernel_launch(void* const* d_in, const int* in_sizes, int n_in,
                              void* d_out, int out_size, void* d_ws, size_t ws_size,
                              hipStream_t stream) {
    const float* query   = (const float*)d_in[0];
    const float* support = (const float*)d_in[1];
    const float* w1 = (const float*)d_in[2];
    const float* w2 = (const float*)d_in[3];
    const float* w3 = (const float*)d_in[4];
    const float* w4 = (const float*)d_in[5];
    const float* s1 = (const float*)d_in[6];
    const float* b1 = (const float*)d_in[7];
    const float* s2 = (const float*)d_in[8];
    const float* b2 = (const float*)d_in[9];
    const float* s3 = (const float*)d_in[10];
    const float* b3 = (const float*)d_in[11];
    const float* s4 = (const float*)d_in[12];
    const float* b4 = (const float*)d_in[13];
    float* out = (float*)d_out;

    char* ws = (char*)d_ws;
    unsigned short* A1  = (unsigned short*)(ws);              // 200*1764*64 bf16 = 45,158,400 B
    unsigned short* A2  = (unsigned short*)(ws + 45158400);   // 200*441*64 bf16 = 11,289,600 B
    unsigned short* A4  = (unsigned short*)(ws + 56448000);   // support feat (only >=150 written)
    unsigned short* QL  = (unsigned short*)(ws + 67737600);   // 150*441*64 bf16 = 8,467,200 B
    unsigned short* SL  = (unsigned short*)(ws + 76204800);   // 10*448*64 bf16 = 573,440 B
    unsigned short* WP2 = (unsigned short*)(ws + 76778240);   // 36864 bf16 = 73,728 B
    unsigned short* WP3 = (unsigned short*)(ws + 76851968);
    unsigned short* WP4 = (unsigned short*)(ws + 76925696);
    unsigned short* WP1 = (unsigned short*)(ws + 76999424);   // 2048 bf16 = 4,096 B
    unsigned short* PAD = (unsigned short*)(ws + 77003520);   // 200*3*7396 bf16 = 8,875,200 B

    prep<<<PAD_BLKS + W1_BLKS + W_BLKS, 256, 0, stream>>>(
        query, support, w1, s1, w2, s2, w3, s3, w4, s4, PAD, WP1, WP2, WP3, WP4);

    conv1_mfma<<<NIMG * 7, 256, 0, stream>>>(PAD, WP1, b1, A1);
    conv2_mfma_pool<<<NIMG * 7, 256, 0, stream>>>(A1, WP2, b2, A2);
    conv34_fused<<<NIMG, 256, 0, stream>>>(A2, WP3, WP4, b3, b4, A4, QL);

    s_mean_norm<<<(BDIM * WAY * SST + 255) / 256, 256, 0, stream>>>(A4, SL);

    sim_mfma<<<NQIMG * WAY, 256, 0, stream>>>(QL, SL, out);
}